// Round 1
// baseline (3146.405 us; speedup 1.0000x reference)
//
#include <hip/hip_runtime.h>

#define R_REL 3

static inline size_t align_up(size_t x, size_t a) { return (x + a - 1) & ~(a - 1); }

__device__ __forceinline__ unsigned enc_f(float f) {
    unsigned u = __float_as_uint(f);
    return (u & 0x80000000u) ? ~u : (u | 0x80000000u);
}
__device__ __forceinline__ float dec_f(unsigned k) {
    unsigned u = (k & 0x80000000u) ? (k & 0x7FFFFFFFu) : ~k;
    return __uint_as_float(u);
}
__device__ __forceinline__ float eluf(float x) {
    return x > 0.f ? x : (__expf(x) - 1.f);
}

// ---------------- tiny weight-prep kernels ----------------

// v[r][i] = sum_j W_gat[r][i][j] * attn_r[r][j]
__global__ void v_kernel(const float* __restrict__ W_gat, const float* __restrict__ attn_r,
                         float* __restrict__ v) {
    int r = blockIdx.x;
    __shared__ float ar[128];
    if (threadIdx.x < 128) ar[threadIdx.x] = attn_r[r * 128 + threadIdx.x];
    __syncthreads();
    if (threadIdx.x < 128) {
        const float* W = W_gat + (size_t)r * 128 * 128 + (size_t)threadIdx.x * 128;
        float s = 0.f;
        for (int j = 0; j < 128; ++j) s += W[j] * ar[j];
        v[r * 128 + threadIdx.x] = s;
    }
}

// u[r][k] = sum_i WT_dst[k][i] * v[r][i];  cc[r] = sum_i bT_dst[i]*v[r][i]
__global__ void u_kernel(const float* __restrict__ WT_dst, const float* __restrict__ bT_dst,
                         const float* __restrict__ v, float* __restrict__ u,
                         float* __restrict__ cc) {
    int r = blockIdx.x;
    __shared__ float vs[128];
    if (threadIdx.x < 128) vs[threadIdx.x] = v[r * 128 + threadIdx.x];
    __syncthreads();
    const float* W = WT_dst + (size_t)threadIdx.x * 128;
    float s = 0.f;
    for (int i = 0; i < 128; ++i) s += W[i] * vs[i];
    u[r * 256 + threadIdx.x] = s;
    if (threadIdx.x == 0) {
        float c = 0.f;
        for (int i = 0; i < 128; ++i) c += bT_dst[i] * vs[i];
        cc[r] = c;
    }
}

// Wc[r][k][j] = sum_i WT_src[r][k][i] * W_gat[r][i][j]   (k==256 row computes bc from bT_src)
__global__ void wc_kernel(const float* __restrict__ WT_src, const float* __restrict__ bT_src,
                          const float* __restrict__ W_gat, float* __restrict__ Wc,
                          float* __restrict__ bc) {
    int r = blockIdx.y;
    int k = blockIdx.x;  // 0..256
    int j = threadIdx.x; // 0..127
    __shared__ float as[128];
    const float* arow = (k < 256) ? (WT_src + ((size_t)r * 256 + k) * 128)
                                  : (bT_src + (size_t)r * 128);
    as[j] = arow[j];
    __syncthreads();
    const float* W = W_gat + (size_t)r * 128 * 128;
    float s = 0.f;
    for (int i = 0; i < 128; ++i) s += as[i] * W[(size_t)i * 128 + j];
    if (k < 256) Wc[((size_t)r * 256 + k) * 128 + j] = s;
    else         bc[(size_t)r * 128 + j] = s;
}

// ---------------- hs GEMM: hs[r] = src[r] @ Wc[r] + bc[r]; el = hs . attn_l ----------------

__global__ __launch_bounds__(256) void gemm_hs(
    const float* __restrict__ src, const float* __restrict__ Wc,
    const float* __restrict__ bc, const float* __restrict__ attn_l,
    float* __restrict__ hs, float* __restrict__ el, int N) {
    const int r = blockIdx.y;
    const int n0 = blockIdx.x * 32;
    const int t = threadIdx.x;
    const int colg = t & 31, rowg = t >> 5;
    __shared__ float As[32][68];
    __shared__ float Bs[64][128];
    const float* A = src + (size_t)r * N * 256;
    const float* B = Wc + (size_t)r * 256 * 128;
    float acc[4][4] = {};
    for (int k0 = 0; k0 < 256; k0 += 64) {
#pragma unroll
        for (int i = 0; i < 2; ++i) {
            int idx = t + 256 * i;
            int rr = idx >> 4, c4 = idx & 15;
            int row = n0 + rr;
            float4 val = make_float4(0.f, 0.f, 0.f, 0.f);
            if (row < N) val = *(const float4*)(A + (size_t)row * 256 + k0 + c4 * 4);
            *(float4*)&As[rr][c4 * 4] = val;
        }
#pragma unroll
        for (int i = 0; i < 8; ++i) {
            int idx = t + 256 * i;
            int kr = idx >> 5, c4 = idx & 31;
            *(float4*)&Bs[kr][c4 * 4] = *(const float4*)(B + (size_t)(k0 + kr) * 128 + c4 * 4);
        }
        __syncthreads();
#pragma unroll 4
        for (int kk = 0; kk < 64; ++kk) {
            float4 bv = *(float4*)&Bs[kk][colg * 4];
#pragma unroll
            for (int i = 0; i < 4; ++i) {
                float a = As[rowg * 4 + i][kk];
                acc[i][0] += a * bv.x; acc[i][1] += a * bv.y;
                acc[i][2] += a * bv.z; acc[i][3] += a * bv.w;
            }
        }
        __syncthreads();
    }
    float4 bcv = *(const float4*)(bc + r * 128 + colg * 4);
    float4 alv = *(const float4*)(attn_l + r * 128 + colg * 4);
#pragma unroll
    for (int i = 0; i < 4; ++i) {
        int row = n0 + rowg * 4 + i;
        float4 h;
        h.x = acc[i][0] + bcv.x; h.y = acc[i][1] + bcv.y;
        h.z = acc[i][2] + bcv.z; h.w = acc[i][3] + bcv.w;
        float p = h.x * alv.x + h.y * alv.y + h.z * alv.z + h.w * alv.w;
#pragma unroll
        for (int off = 16; off >= 1; off >>= 1) p += __shfl_xor(p, off, 64);
        if (row < N) {
            *(float4*)(hs + ((size_t)r * N + row) * 128 + colg * 4) = h;
            if (colg == 0) el[(size_t)r * N + row] = p;
        }
    }
}

// ---------------- er: er[r][n] = dst_feat[n] . u[r] + cc[r] ----------------

__global__ void er_kernel(const float* __restrict__ dst_feat, const float* __restrict__ u,
                          const float* __restrict__ cc, float* __restrict__ er, int N) {
    __shared__ float us[3][256];
    for (int i = threadIdx.x; i < 3 * 256; i += 256) us[i / 256][i & 255] = u[i];
    __syncthreads();
    int wave = threadIdx.x >> 6, lane = threadIdx.x & 63;
    int n = blockIdx.x * 4 + wave;
    if (n >= N) return;
    float4 f = *(const float4*)(dst_feat + (size_t)n * 256 + lane * 4);
#pragma unroll
    for (int r = 0; r < R_REL; ++r) {
        float4 uv = *(float4*)&us[r][lane * 4];
        float s = f.x * uv.x + f.y * uv.y + f.z * uv.z + f.w * uv.w;
#pragma unroll
        for (int off = 32; off >= 1; off >>= 1) s += __shfl_xor(s, off, 64);
        if (lane == 0) er[(size_t)r * N + n] = s + cc[r];
    }
}

// ---------------- edge passes ----------------

__global__ void edge_a(const int* __restrict__ si, const int* __restrict__ di,
                       const float* __restrict__ el, const float* __restrict__ er,
                       float* __restrict__ ebuf, unsigned* __restrict__ menc, int N, int E) {
    int r = blockIdx.y;
    int i = blockIdx.x * 256 + threadIdx.x;
    if (i >= E) return;
    int g = r * E + i;
    float e = el[(size_t)r * N + si[g]] + er[(size_t)r * N + di[g]];
    e = e > 0.f ? e : 0.2f * e;
    ebuf[g] = e;
    atomicMax(&menc[(size_t)r * N + di[g]], enc_f(e));
}

__global__ void edge_b(const int* __restrict__ di, float* __restrict__ ebuf,
                       const unsigned* __restrict__ menc, float* __restrict__ ssum,
                       int N, int E) {
    int r = blockIdx.y;
    int i = blockIdx.x * 256 + threadIdx.x;
    if (i >= E) return;
    int g = r * E + i;
    int d = di[g];
    float ex = __expf(ebuf[g] - dec_f(menc[(size_t)r * N + d]));
    ebuf[g] = ex;
    atomicAdd(&ssum[(size_t)r * N + d], ex);
}

__global__ void edge_c(const int* __restrict__ si, const int* __restrict__ di,
                       const float* __restrict__ ebuf, const float* __restrict__ ssum,
                       const float* __restrict__ hs, float* __restrict__ gout, int N, int E) {
    int r = blockIdx.y;
    int i = blockIdx.x * 8 + (threadIdx.x >> 5);
    int lane = threadIdx.x & 31;
    if (i >= E) return;
    int g = r * E + i;
    int s = si[g], d = di[g];
    float alpha = ebuf[g] / ssum[(size_t)r * N + d];
    float4 h = *(const float4*)(hs + ((size_t)r * N + s) * 128 + lane * 4);
    float* o = gout + ((size_t)r * N + d) * 128 + lane * 4;
    atomicAdd(o + 0, alpha * h.x);
    atomicAdd(o + 1, alpha * h.y);
    atomicAdd(o + 2, alpha * h.z);
    atomicAdd(o + 3, alpha * h.w);
}

// ---------------- semantic attention GEMM ----------------

__global__ __launch_bounds__(256) void gemm_sem(
    const float* __restrict__ gout, const float* __restrict__ b_gat,
    const float* __restrict__ W1, const float* __restrict__ b1,
    const float* __restrict__ w2, float* __restrict__ wsum, int N) {
    const int r = blockIdx.y;
    const int n0 = blockIdx.x * 32;
    const int t = threadIdx.x;
    const int colg = t & 31, rowg = t >> 5;
    __shared__ float As[32][68];
    __shared__ float Bs[64][128];
    const float* A = gout + (size_t)r * N * 128;
    const float* bg = b_gat + (size_t)r * 128;
    float acc[4][4] = {};
    for (int k0 = 0; k0 < 128; k0 += 64) {
#pragma unroll
        for (int i = 0; i < 2; ++i) {
            int idx = t + 256 * i;
            int rr = idx >> 4, c4 = idx & 15;
            int row = n0 + rr;
            float4 val = make_float4(0.f, 0.f, 0.f, 0.f);
            if (row < N) {
                val = *(const float4*)(A + (size_t)row * 128 + k0 + c4 * 4);
                float4 b = *(const float4*)(bg + k0 + c4 * 4);
                val.x = eluf(val.x + b.x); val.y = eluf(val.y + b.y);
                val.z = eluf(val.z + b.z); val.w = eluf(val.w + b.w);
            }
            *(float4*)&As[rr][c4 * 4] = val;
        }
#pragma unroll
        for (int i = 0; i < 8; ++i) {
            int idx = t + 256 * i;
            int kr = idx >> 5, c4 = idx & 31;
            *(float4*)&Bs[kr][c4 * 4] = *(const float4*)(W1 + (size_t)(k0 + kr) * 128 + c4 * 4);
        }
        __syncthreads();
#pragma unroll 4
        for (int kk = 0; kk < 64; ++kk) {
            float4 bv = *(float4*)&Bs[kk][colg * 4];
#pragma unroll
            for (int i = 0; i < 4; ++i) {
                float a = As[rowg * 4 + i][kk];
                acc[i][0] += a * bv.x; acc[i][1] += a * bv.y;
                acc[i][2] += a * bv.z; acc[i][3] += a * bv.w;
            }
        }
        __syncthreads();
    }
    float4 b1v = *(const float4*)(b1 + colg * 4);
    float4 w2v = *(const float4*)(w2 + colg * 4);
    float wloc = 0.f;
#pragma unroll
    for (int i = 0; i < 4; ++i) {
        int row = n0 + rowg * 4 + i;
        float p = tanhf(acc[i][0] + b1v.x) * w2v.x
                + tanhf(acc[i][1] + b1v.y) * w2v.y
                + tanhf(acc[i][2] + b1v.z) * w2v.z
                + tanhf(acc[i][3] + b1v.w) * w2v.w;
#pragma unroll
        for (int off = 16; off >= 1; off >>= 1) p += __shfl_xor(p, off, 64);
        if (colg == 0 && row < N) wloc += p;
    }
    if (colg == 0) atomicAdd(&wsum[r], wloc);
}

__global__ void softmax_a(const float* __restrict__ wsum, float* __restrict__ aw, int N) {
    if (threadIdx.x == 0) {
        float w0 = wsum[0] / (float)N, w1 = wsum[1] / (float)N, w2 = wsum[2] / (float)N;
        float m = fmaxf(w0, fmaxf(w1, w2));
        float e0 = __expf(w0 - m), e1 = __expf(w1 - m), e2 = __expf(w2 - m);
        float s = e0 + e1 + e2;
        aw[0] = e0 / s; aw[1] = e1 / s; aw[2] = e2 / s;
    }
}

__global__ void combine(const float* __restrict__ gout, const float* __restrict__ b_gat,
                        const float* __restrict__ aw, float* __restrict__ out, int N) {
    int idx = blockIdx.x * 256 + threadIdx.x;
    if (idx >= N * 32) return;
    int n = idx >> 5, c4 = idx & 31;
    float a0 = aw[0], a1 = aw[1], a2 = aw[2];
    float4 o = make_float4(0.f, 0.f, 0.f, 0.f);
    {
        float4 g = *(const float4*)(gout + ((size_t)0 * N + n) * 128 + c4 * 4);
        float4 b = *(const float4*)(b_gat + 0 * 128 + c4 * 4);
        o.x += a0 * eluf(g.x + b.x); o.y += a0 * eluf(g.y + b.y);
        o.z += a0 * eluf(g.z + b.z); o.w += a0 * eluf(g.w + b.w);
    }
    {
        float4 g = *(const float4*)(gout + ((size_t)1 * N + n) * 128 + c4 * 4);
        float4 b = *(const float4*)(b_gat + 1 * 128 + c4 * 4);
        o.x += a1 * eluf(g.x + b.x); o.y += a1 * eluf(g.y + b.y);
        o.z += a1 * eluf(g.z + b.z); o.w += a1 * eluf(g.w + b.w);
    }
    {
        float4 g = *(const float4*)(gout + ((size_t)2 * N + n) * 128 + c4 * 4);
        float4 b = *(const float4*)(b_gat + 2 * 128 + c4 * 4);
        o.x += a2 * eluf(g.x + b.x); o.y += a2 * eluf(g.y + b.y);
        o.z += a2 * eluf(g.z + b.z); o.w += a2 * eluf(g.w + b.w);
    }
    *(float4*)(out + (size_t)idx * 4) = o;
}

// ---------------- launch ----------------

extern "C" void kernel_launch(void* const* d_in, const int* in_sizes, int n_in,
                              void* d_out, int out_size, void* d_ws, size_t ws_size,
                              hipStream_t stream) {
    const float* dst_feat = (const float*)d_in[0];
    const float* src_feats = (const float*)d_in[1];
    const int*   src_idx  = (const int*)d_in[2];
    const int*   dst_idx  = (const int*)d_in[3];
    const float* WT_dst   = (const float*)d_in[4];
    const float* bT_dst   = (const float*)d_in[5];
    const float* WT_src   = (const float*)d_in[6];
    const float* bT_src   = (const float*)d_in[7];
    const float* W_gat    = (const float*)d_in[8];
    const float* attn_l   = (const float*)d_in[9];
    const float* attn_r   = (const float*)d_in[10];
    const float* b_gat    = (const float*)d_in[11];
    const float* W1_sem   = (const float*)d_in[12];
    const float* b1_sem   = (const float*)d_in[13];
    const float* w2_sem   = (const float*)d_in[14];

    const int N = in_sizes[0] / 256;
    const int E = in_sizes[2] / R_REL;
    float* out = (float*)d_out;

    char* ws = (char*)d_ws;
    size_t off = 0;
    auto alloc = [&](size_t bytes) { char* p = ws + off; off = align_up(off + bytes, 256); return p; };
    float*    hs   = (float*)alloc((size_t)R_REL * N * 128 * 4);
    float*    gout = (float*)alloc((size_t)R_REL * N * 128 * 4);
    float*    ebuf = (float*)alloc((size_t)R_REL * E * 4);
    float*    Wc   = (float*)alloc((size_t)R_REL * 256 * 128 * 4);
    float*    bc   = (float*)alloc(R_REL * 128 * 4);
    float*    u    = (float*)alloc(R_REL * 256 * 4);
    float*    vv   = (float*)alloc(R_REL * 128 * 4);
    float*    cc   = (float*)alloc(R_REL * 4);
    float*    el   = (float*)alloc((size_t)R_REL * N * 4);
    float*    er   = (float*)alloc((size_t)R_REL * N * 4);
    unsigned* menc = (unsigned*)alloc((size_t)R_REL * N * 4);
    float*    ssum = (float*)alloc((size_t)R_REL * N * 4);
    float*    wsum = (float*)alloc(R_REL * 4);
    float*    aw   = (float*)alloc(R_REL * 4);

    hipMemsetAsync(gout, 0, (size_t)R_REL * N * 128 * 4, stream);
    hipMemsetAsync(menc, 0, (size_t)R_REL * N * 4, stream);
    hipMemsetAsync(ssum, 0, (size_t)R_REL * N * 4, stream);
    hipMemsetAsync(wsum, 0, R_REL * 4, stream);

    v_kernel<<<R_REL, 128, 0, stream>>>(W_gat, attn_r, vv);
    u_kernel<<<R_REL, 256, 0, stream>>>(WT_dst, bT_dst, vv, u, cc);
    wc_kernel<<<dim3(257, R_REL), 128, 0, stream>>>(WT_src, bT_src, W_gat, Wc, bc);

    dim3 g1((N + 31) / 32, R_REL);
    gemm_hs<<<g1, 256, 0, stream>>>(src_feats, Wc, bc, attn_l, hs, el, N);
    er_kernel<<<(N + 3) / 4, 256, 0, stream>>>(dst_feat, u, cc, er, N);

    edge_a<<<dim3((E + 255) / 256, R_REL), 256, 0, stream>>>(src_idx, dst_idx, el, er, ebuf, menc, N, E);
    edge_b<<<dim3((E + 255) / 256, R_REL), 256, 0, stream>>>(dst_idx, ebuf, menc, ssum, N, E);
    edge_c<<<dim3((E + 7) / 8, R_REL), 256, 0, stream>>>(src_idx, dst_idx, ebuf, ssum, hs, gout, N, E);

    gemm_sem<<<g1, 256, 0, stream>>>(gout, b_gat, W1_sem, b1_sem, w2_sem, wsum, N);
    softmax_a<<<1, 64, 0, stream>>>(wsum, aw, N);
    combine<<<(N * 32 + 255) / 256, 256, 0, stream>>>(gout, b_gat, aw, out, N);
}

// Round 2
// 817.455 us; speedup vs baseline: 3.8490x; 3.8490x over previous
//
#include <hip/hip_runtime.h>

#define R_REL 3

static inline size_t align_up(size_t x, size_t a) { return (x + a - 1) & ~(a - 1); }

__device__ __forceinline__ float eluf(float x) {
    return x > 0.f ? x : (__expf(x) - 1.f);
}

// ---------------- tiny weight-prep kernels ----------------

// v[r][i] = sum_j W_gat[r][i][j] * attn_r[r][j]
__global__ void v_kernel(const float* __restrict__ W_gat, const float* __restrict__ attn_r,
                         float* __restrict__ v) {
    int r = blockIdx.x;
    __shared__ float ar[128];
    if (threadIdx.x < 128) ar[threadIdx.x] = attn_r[r * 128 + threadIdx.x];
    __syncthreads();
    if (threadIdx.x < 128) {
        const float* W = W_gat + (size_t)r * 128 * 128 + (size_t)threadIdx.x * 128;
        float s = 0.f;
        for (int j = 0; j < 128; ++j) s += W[j] * ar[j];
        v[r * 128 + threadIdx.x] = s;
    }
}

// u[r][k] = sum_i WT_dst[k][i] * v[r][i];  cc[r] = sum_i bT_dst[i]*v[r][i]
__global__ void u_kernel(const float* __restrict__ WT_dst, const float* __restrict__ bT_dst,
                         const float* __restrict__ v, float* __restrict__ u,
                         float* __restrict__ cc) {
    int r = blockIdx.x;
    __shared__ float vs[128];
    if (threadIdx.x < 128) vs[threadIdx.x] = v[r * 128 + threadIdx.x];
    __syncthreads();
    const float* W = WT_dst + (size_t)threadIdx.x * 128;
    float s = 0.f;
    for (int i = 0; i < 128; ++i) s += W[i] * vs[i];
    u[r * 256 + threadIdx.x] = s;
    if (threadIdx.x == 0) {
        float c = 0.f;
        for (int i = 0; i < 128; ++i) c += bT_dst[i] * vs[i];
        cc[r] = c;
    }
}

// Wc[r][k][j] = sum_i WT_src[r][k][i] * W_gat[r][i][j]   (k==256 row computes bc from bT_src)
__global__ void wc_kernel(const float* __restrict__ WT_src, const float* __restrict__ bT_src,
                          const float* __restrict__ W_gat, float* __restrict__ Wc,
                          float* __restrict__ bc) {
    int r = blockIdx.y;
    int k = blockIdx.x;  // 0..256
    int j = threadIdx.x; // 0..127
    __shared__ float as[128];
    const float* arow = (k < 256) ? (WT_src + ((size_t)r * 256 + k) * 128)
                                  : (bT_src + (size_t)r * 128);
    as[j] = arow[j];
    __syncthreads();
    const float* W = W_gat + (size_t)r * 128 * 128;
    float s = 0.f;
    for (int i = 0; i < 128; ++i) s += as[i] * W[(size_t)i * 128 + j];
    if (k < 256) Wc[((size_t)r * 256 + k) * 128 + j] = s;
    else         bc[(size_t)r * 128 + j] = s;
}

// ---------------- hs GEMM: hs[r] = src[r] @ Wc[r] + bc[r]; el = hs . attn_l ----------------

__global__ __launch_bounds__(256) void gemm_hs(
    const float* __restrict__ src, const float* __restrict__ Wc,
    const float* __restrict__ bc, const float* __restrict__ attn_l,
    float* __restrict__ hs, float* __restrict__ el, int N) {
    const int r = blockIdx.y;
    const int n0 = blockIdx.x * 32;
    const int t = threadIdx.x;
    const int colg = t & 31, rowg = t >> 5;
    __shared__ float As[32][68];
    __shared__ float Bs[64][128];
    const float* A = src + (size_t)r * N * 256;
    const float* B = Wc + (size_t)r * 256 * 128;
    float acc[4][4] = {};
    for (int k0 = 0; k0 < 256; k0 += 64) {
#pragma unroll
        for (int i = 0; i < 2; ++i) {
            int idx = t + 256 * i;
            int rr = idx >> 4, c4 = idx & 15;
            int row = n0 + rr;
            float4 val = make_float4(0.f, 0.f, 0.f, 0.f);
            if (row < N) val = *(const float4*)(A + (size_t)row * 256 + k0 + c4 * 4);
            *(float4*)&As[rr][c4 * 4] = val;
        }
#pragma unroll
        for (int i = 0; i < 8; ++i) {
            int idx = t + 256 * i;
            int kr = idx >> 5, c4 = idx & 31;
            *(float4*)&Bs[kr][c4 * 4] = *(const float4*)(B + (size_t)(k0 + kr) * 128 + c4 * 4);
        }
        __syncthreads();
#pragma unroll 4
        for (int kk = 0; kk < 64; ++kk) {
            float4 bv = *(float4*)&Bs[kk][colg * 4];
#pragma unroll
            for (int i = 0; i < 4; ++i) {
                float a = As[rowg * 4 + i][kk];
                acc[i][0] += a * bv.x; acc[i][1] += a * bv.y;
                acc[i][2] += a * bv.z; acc[i][3] += a * bv.w;
            }
        }
        __syncthreads();
    }
    float4 bcv = *(const float4*)(bc + r * 128 + colg * 4);
    float4 alv = *(const float4*)(attn_l + r * 128 + colg * 4);
#pragma unroll
    for (int i = 0; i < 4; ++i) {
        int row = n0 + rowg * 4 + i;
        float4 h;
        h.x = acc[i][0] + bcv.x; h.y = acc[i][1] + bcv.y;
        h.z = acc[i][2] + bcv.z; h.w = acc[i][3] + bcv.w;
        float p = h.x * alv.x + h.y * alv.y + h.z * alv.z + h.w * alv.w;
#pragma unroll
        for (int off = 16; off >= 1; off >>= 1) p += __shfl_xor(p, off, 64);
        if (row < N) {
            *(float4*)(hs + ((size_t)r * N + row) * 128 + colg * 4) = h;
            if (colg == 0) el[(size_t)r * N + row] = p;
        }
    }
}

// ---------------- er: er[r][n] = dst_feat[n] . u[r] + cc[r] ----------------

__global__ void er_kernel(const float* __restrict__ dst_feat, const float* __restrict__ u,
                          const float* __restrict__ cc, float* __restrict__ er, int N) {
    __shared__ float us[3][256];
    for (int i = threadIdx.x; i < 3 * 256; i += 256) us[i / 256][i & 255] = u[i];
    __syncthreads();
    int wave = threadIdx.x >> 6, lane = threadIdx.x & 63;
    int n = blockIdx.x * 4 + wave;
    if (n >= N) return;
    float4 f = *(const float4*)(dst_feat + (size_t)n * 256 + lane * 4);
#pragma unroll
    for (int r = 0; r < R_REL; ++r) {
        float4 uv = *(float4*)&us[r][lane * 4];
        float s = f.x * uv.x + f.y * uv.y + f.z * uv.z + f.w * uv.w;
#pragma unroll
        for (int off = 32; off >= 1; off >>= 1) s += __shfl_xor(s, off, 64);
        if (lane == 0) er[(size_t)r * N + n] = s + cc[r];
    }
}

// ---------------- CSR build (dst-sorted) ----------------

__global__ void deg_kernel(const int* __restrict__ di, int* __restrict__ deg, int N, int E) {
    int r = blockIdx.y;
    int i = blockIdx.x * 256 + threadIdx.x;
    if (i >= E) return;
    atomicAdd(&deg[(size_t)r * N + di[(size_t)r * E + i]], 1);
}

// exclusive scan of deg per relation; writes offs and cur (= offs copy)
__global__ __launch_bounds__(1024) void scan_kernel(const int* __restrict__ deg,
                                                    int* __restrict__ offs,
                                                    int* __restrict__ cur, int N) {
    const int r = blockIdx.x;
    const int t = threadIdx.x;
    const int lane = t & 63, wave = t >> 6;
    const int NW = 16;  // 1024/64
    __shared__ int wsum[NW];
    __shared__ int carry_s;
    if (t == 0) carry_s = 0;
    __syncthreads();
    for (int base = 0; base < N; base += 1024) {
        int idx = base + t;
        int v = (idx < N) ? deg[(size_t)r * N + idx] : 0;
        int x = v;
#pragma unroll
        for (int off = 1; off < 64; off <<= 1) {
            int y = __shfl_up(x, off, 64);
            if (lane >= off) x += y;
        }
        if (lane == 63) wsum[wave] = x;
        __syncthreads();
        if (wave == 0 && lane < NW) {
            int y = wsum[lane];
#pragma unroll
            for (int off = 1; off < NW; off <<= 1) {
                int z = __shfl_up(y, off, 64);
                if (lane >= off) y += z;
            }
            wsum[lane] = y;
        }
        __syncthreads();
        int waveoff = (wave > 0) ? wsum[wave - 1] : 0;
        int excl = carry_s + waveoff + x - v;
        if (idx < N) {
            offs[(size_t)r * N + idx] = excl;
            cur[(size_t)r * N + idx] = excl;
        }
        __syncthreads();
        if (t == 0) carry_s += wsum[NW - 1];
        __syncthreads();
    }
}

__global__ void fill_kernel(const int* __restrict__ si, const int* __restrict__ di,
                            int* __restrict__ cur, int* __restrict__ csr, int N, int E) {
    int r = blockIdx.y;
    int i = blockIdx.x * 256 + threadIdx.x;
    if (i >= E) return;
    size_t g = (size_t)r * E + i;
    int d = di[g];
    int pos = atomicAdd(&cur[(size_t)r * N + d], 1);
    csr[(size_t)r * E + pos] = si[g];
}

// ---------------- fused per-dst softmax + aggregation (gather) ----------------

__global__ __launch_bounds__(256) void gather_kernel(
    const int* __restrict__ csr, const int* __restrict__ offs, const int* __restrict__ deg,
    const float* __restrict__ el, const float* __restrict__ er,
    const float* __restrict__ hs, float* __restrict__ gout, int N, int E) {
    const int r = blockIdx.y;
    const int wave = threadIdx.x >> 6, lane = threadIdx.x & 63;
    const int d = blockIdx.x * 4 + wave;
    if (d >= N) return;
    float* op = gout + ((size_t)r * N + d) * 128 + lane * 2;
    const int beg = offs[(size_t)r * N + d];
    const int dg = deg[(size_t)r * N + d];
    if (dg == 0) { *(float2*)op = make_float2(0.f, 0.f); return; }
    const float erd = er[(size_t)r * N + d];
    const float* elr = el + (size_t)r * N;
    const int* csrr = csr + (size_t)r * E;
    const float* hsr = hs + (size_t)r * N * 128;

    // pass 1: max over edges (lanes strided)
    float m = -3.0e38f;
    for (int i = beg + lane; i < beg + dg; i += 64) {
        float e = elr[csrr[i]] + erd;
        e = e > 0.f ? e : 0.2f * e;
        m = fmaxf(m, e);
    }
#pragma unroll
    for (int off = 32; off >= 1; off >>= 1) m = fmaxf(m, __shfl_xor(m, off, 64));

    // pass 2: exp/sum + broadcast-accumulate
    float ssum = 0.f;
    float2 acc = make_float2(0.f, 0.f);
    for (int c = beg; c < beg + dg; c += 64) {
        int nn = min(64, beg + dg - c);
        int src = 0; float p = 0.f;
        if (lane < nn) {
            src = csrr[c + lane];
            float e = elr[src] + erd;
            e = e > 0.f ? e : 0.2f * e;
            p = __expf(e - m);
            ssum += p;
        }
        for (int j = 0; j < nn; ++j) {
            float pj = __shfl(p, j, 64);
            int sj = __shfl(src, j, 64);
            float2 h = *(const float2*)(hsr + (size_t)sj * 128 + lane * 2);
            acc.x += pj * h.x;
            acc.y += pj * h.y;
        }
    }
#pragma unroll
    for (int off = 32; off >= 1; off >>= 1) ssum += __shfl_xor(ssum, off, 64);
    float inv = 1.f / ssum;
    acc.x *= inv; acc.y *= inv;
    *(float2*)op = acc;
}

// ---------------- semantic attention GEMM ----------------

__global__ __launch_bounds__(256) void gemm_sem(
    const float* __restrict__ gout, const float* __restrict__ b_gat,
    const float* __restrict__ W1, const float* __restrict__ b1,
    const float* __restrict__ w2, float* __restrict__ wsum, int N) {
    const int r = blockIdx.y;
    const int n0 = blockIdx.x * 32;
    const int t = threadIdx.x;
    const int colg = t & 31, rowg = t >> 5;
    __shared__ float As[32][68];
    __shared__ float Bs[64][128];
    const float* A = gout + (size_t)r * N * 128;
    const float* bg = b_gat + (size_t)r * 128;
    float acc[4][4] = {};
    for (int k0 = 0; k0 < 128; k0 += 64) {
#pragma unroll
        for (int i = 0; i < 2; ++i) {
            int idx = t + 256 * i;
            int rr = idx >> 4, c4 = idx & 15;
            int row = n0 + rr;
            float4 val = make_float4(0.f, 0.f, 0.f, 0.f);
            if (row < N) {
                val = *(const float4*)(A + (size_t)row * 128 + k0 + c4 * 4);
                float4 b = *(const float4*)(bg + k0 + c4 * 4);
                val.x = eluf(val.x + b.x); val.y = eluf(val.y + b.y);
                val.z = eluf(val.z + b.z); val.w = eluf(val.w + b.w);
            }
            *(float4*)&As[rr][c4 * 4] = val;
        }
#pragma unroll
        for (int i = 0; i < 8; ++i) {
            int idx = t + 256 * i;
            int kr = idx >> 5, c4 = idx & 31;
            *(float4*)&Bs[kr][c4 * 4] = *(const float4*)(W1 + (size_t)(k0 + kr) * 128 + c4 * 4);
        }
        __syncthreads();
#pragma unroll 4
        for (int kk = 0; kk < 64; ++kk) {
            float4 bv = *(float4*)&Bs[kk][colg * 4];
#pragma unroll
            for (int i = 0; i < 4; ++i) {
                float a = As[rowg * 4 + i][kk];
                acc[i][0] += a * bv.x; acc[i][1] += a * bv.y;
                acc[i][2] += a * bv.z; acc[i][3] += a * bv.w;
            }
        }
        __syncthreads();
    }
    float4 b1v = *(const float4*)(b1 + colg * 4);
    float4 w2v = *(const float4*)(w2 + colg * 4);
    float wloc = 0.f;
#pragma unroll
    for (int i = 0; i < 4; ++i) {
        int row = n0 + rowg * 4 + i;
        float p = tanhf(acc[i][0] + b1v.x) * w2v.x
                + tanhf(acc[i][1] + b1v.y) * w2v.y
                + tanhf(acc[i][2] + b1v.z) * w2v.z
                + tanhf(acc[i][3] + b1v.w) * w2v.w;
#pragma unroll
        for (int off = 16; off >= 1; off >>= 1) p += __shfl_xor(p, off, 64);
        if (colg == 0 && row < N) wloc += p;
    }
    if (colg == 0) atomicAdd(&wsum[r], wloc);
}

__global__ void softmax_a(const float* __restrict__ wsum, float* __restrict__ aw, int N) {
    if (threadIdx.x == 0) {
        float w0 = wsum[0] / (float)N, w1 = wsum[1] / (float)N, w2 = wsum[2] / (float)N;
        float m = fmaxf(w0, fmaxf(w1, w2));
        float e0 = __expf(w0 - m), e1 = __expf(w1 - m), e2 = __expf(w2 - m);
        float s = e0 + e1 + e2;
        aw[0] = e0 / s; aw[1] = e1 / s; aw[2] = e2 / s;
    }
}

__global__ void combine(const float* __restrict__ gout, const float* __restrict__ b_gat,
                        const float* __restrict__ aw, float* __restrict__ out, int N) {
    int idx = blockIdx.x * 256 + threadIdx.x;
    if (idx >= N * 32) return;
    int n = idx >> 5, c4 = idx & 31;
    float a0 = aw[0], a1 = aw[1], a2 = aw[2];
    float4 o = make_float4(0.f, 0.f, 0.f, 0.f);
    {
        float4 g = *(const float4*)(gout + ((size_t)0 * N + n) * 128 + c4 * 4);
        float4 b = *(const float4*)(b_gat + 0 * 128 + c4 * 4);
        o.x += a0 * eluf(g.x + b.x); o.y += a0 * eluf(g.y + b.y);
        o.z += a0 * eluf(g.z + b.z); o.w += a0 * eluf(g.w + b.w);
    }
    {
        float4 g = *(const float4*)(gout + ((size_t)1 * N + n) * 128 + c4 * 4);
        float4 b = *(const float4*)(b_gat + 1 * 128 + c4 * 4);
        o.x += a1 * eluf(g.x + b.x); o.y += a1 * eluf(g.y + b.y);
        o.z += a1 * eluf(g.z + b.z); o.w += a1 * eluf(g.w + b.w);
    }
    {
        float4 g = *(const float4*)(gout + ((size_t)2 * N + n) * 128 + c4 * 4);
        float4 b = *(const float4*)(b_gat + 2 * 128 + c4 * 4);
        o.x += a2 * eluf(g.x + b.x); o.y += a2 * eluf(g.y + b.y);
        o.z += a2 * eluf(g.z + b.z); o.w += a2 * eluf(g.w + b.w);
    }
    *(float4*)(out + (size_t)idx * 4) = o;
}

// ---------------- launch ----------------

extern "C" void kernel_launch(void* const* d_in, const int* in_sizes, int n_in,
                              void* d_out, int out_size, void* d_ws, size_t ws_size,
                              hipStream_t stream) {
    const float* dst_feat = (const float*)d_in[0];
    const float* src_feats = (const float*)d_in[1];
    const int*   src_idx  = (const int*)d_in[2];
    const int*   dst_idx  = (const int*)d_in[3];
    const float* WT_dst   = (const float*)d_in[4];
    const float* bT_dst   = (const float*)d_in[5];
    const float* WT_src   = (const float*)d_in[6];
    const float* bT_src   = (const float*)d_in[7];
    const float* W_gat    = (const float*)d_in[8];
    const float* attn_l   = (const float*)d_in[9];
    const float* attn_r   = (const float*)d_in[10];
    const float* b_gat    = (const float*)d_in[11];
    const float* W1_sem   = (const float*)d_in[12];
    const float* b1_sem   = (const float*)d_in[13];
    const float* w2_sem   = (const float*)d_in[14];

    const int N = in_sizes[0] / 256;
    const int E = in_sizes[2] / R_REL;
    float* out = (float*)d_out;

    char* ws = (char*)d_ws;
    size_t off = 0;
    auto alloc = [&](size_t bytes) { char* p = ws + off; off = align_up(off + bytes, 256); return p; };
    float*    hs   = (float*)alloc((size_t)R_REL * N * 128 * 4);
    float*    gout = (float*)alloc((size_t)R_REL * N * 128 * 4);
    float*    Wc   = (float*)alloc((size_t)R_REL * 256 * 128 * 4);
    float*    bc   = (float*)alloc(R_REL * 128 * 4);
    float*    u    = (float*)alloc(R_REL * 256 * 4);
    float*    vv   = (float*)alloc(R_REL * 128 * 4);
    float*    cc   = (float*)alloc(R_REL * 4);
    float*    el   = (float*)alloc((size_t)R_REL * N * 4);
    float*    er   = (float*)alloc((size_t)R_REL * N * 4);
    int*      deg  = (int*)alloc((size_t)R_REL * N * 4);
    int*      offs = (int*)alloc((size_t)R_REL * N * 4);
    int*      cur  = (int*)alloc((size_t)R_REL * N * 4);
    int*      csr  = (int*)alloc((size_t)R_REL * E * 4);
    float*    wsum = (float*)alloc(R_REL * 4);
    float*    aw   = (float*)alloc(R_REL * 4);

    hipMemsetAsync(deg, 0, (size_t)R_REL * N * 4, stream);
    hipMemsetAsync(wsum, 0, R_REL * 4, stream);

    // weight prep
    v_kernel<<<R_REL, 128, 0, stream>>>(W_gat, attn_r, vv);
    u_kernel<<<R_REL, 256, 0, stream>>>(WT_dst, bT_dst, vv, u, cc);
    wc_kernel<<<dim3(257, R_REL), 128, 0, stream>>>(WT_src, bT_src, W_gat, Wc, bc);

    // CSR build (independent of GEMMs)
    deg_kernel<<<dim3((E + 255) / 256, R_REL), 256, 0, stream>>>(dst_idx, deg, N, E);
    scan_kernel<<<R_REL, 1024, 0, stream>>>(deg, offs, cur, N);
    fill_kernel<<<dim3((E + 255) / 256, R_REL), 256, 0, stream>>>(src_idx, dst_idx, cur, csr, N, E);

    // node projections
    dim3 g1((N + 31) / 32, R_REL);
    gemm_hs<<<g1, 256, 0, stream>>>(src_feats, Wc, bc, attn_l, hs, el, N);
    er_kernel<<<(N + 3) / 4, 256, 0, stream>>>(dst_feat, u, cc, er, N);

    // fused edge softmax + aggregation
    gather_kernel<<<dim3((N + 3) / 4, R_REL), 256, 0, stream>>>(csr, offs, deg, el, er, hs, gout, N, E);

    // semantic attention + combine
    gemm_sem<<<g1, 256, 0, stream>>>(gout, b_gat, W1_sem, b1_sem, w2_sem, wsum, N);
    softmax_a<<<1, 64, 0, stream>>>(wsum, aw, N);
    combine<<<(N * 32 + 255) / 256, 256, 0, stream>>>(gout, b_gat, aw, out, N);
}

// Round 3
// 611.319 us; speedup vs baseline: 5.1469x; 1.3372x over previous
//
#include <hip/hip_runtime.h>

#define R_REL 3

typedef __attribute__((ext_vector_type(8))) short bf16x8;
typedef __attribute__((ext_vector_type(4))) float f32x4;

static inline size_t align_up(size_t x, size_t a) { return (x + a - 1) & ~(a - 1); }

__device__ __forceinline__ float eluf(float x) {
    return x > 0.f ? x : (__expf(x) - 1.f);
}
__device__ __forceinline__ unsigned short f2bf(float f) {
    unsigned u = __float_as_uint(f);
    u += 0x7fffu + ((u >> 16) & 1u);
    return (unsigned short)(u >> 16);
}
__device__ __forceinline__ float bf2f(unsigned short h) {
    return __uint_as_float((unsigned)h << 16);
}

// ---------------- tiny weight-prep kernels ----------------

// v[r][i] = sum_j W_gat[r][i][j] * attn_r[r][j]
__global__ void v_kernel(const float* __restrict__ W_gat, const float* __restrict__ attn_r,
                         float* __restrict__ v) {
    int r = blockIdx.x;
    __shared__ float ar[128];
    if (threadIdx.x < 128) ar[threadIdx.x] = attn_r[r * 128 + threadIdx.x];
    __syncthreads();
    if (threadIdx.x < 128) {
        const float* W = W_gat + (size_t)r * 128 * 128 + (size_t)threadIdx.x * 128;
        float s = 0.f;
        for (int j = 0; j < 128; ++j) s += W[j] * ar[j];
        v[r * 128 + threadIdx.x] = s;
    }
}

// u[r][k] = sum_i WT_dst[k][i] * v[r][i];  cc[r] = sum_i bT_dst[i]*v[r][i]
__global__ void u_kernel(const float* __restrict__ WT_dst, const float* __restrict__ bT_dst,
                         const float* __restrict__ v, float* __restrict__ u,
                         float* __restrict__ cc) {
    int r = blockIdx.x;
    __shared__ float vs[128];
    if (threadIdx.x < 128) vs[threadIdx.x] = v[r * 128 + threadIdx.x];
    __syncthreads();
    const float* W = WT_dst + (size_t)threadIdx.x * 128;
    float s = 0.f;
    for (int i = 0; i < 128; ++i) s += W[i] * vs[i];
    u[r * 256 + threadIdx.x] = s;
    if (threadIdx.x == 0) {
        float c = 0.f;
        for (int i = 0; i < 128; ++i) c += bT_dst[i] * vs[i];
        cc[r] = c;
    }
}

// Wc[r][k][j] = sum_i WT_src[r][k][i] * W_gat[r][i][j]   (k==256 row computes bc from bT_src)
__global__ void wc_kernel(const float* __restrict__ WT_src, const float* __restrict__ bT_src,
                          const float* __restrict__ W_gat, float* __restrict__ Wc,
                          float* __restrict__ bc) {
    int r = blockIdx.y;
    int k = blockIdx.x;  // 0..256
    int j = threadIdx.x; // 0..127
    __shared__ float as[128];
    const float* arow = (k < 256) ? (WT_src + ((size_t)r * 256 + k) * 128)
                                  : (bT_src + (size_t)r * 128);
    as[j] = arow[j];
    __syncthreads();
    const float* W = W_gat + (size_t)r * 128 * 128;
    float s = 0.f;
    for (int i = 0; i < 128; ++i) s += as[i] * W[(size_t)i * 128 + j];
    if (k < 256) Wc[((size_t)r * 256 + k) * 128 + j] = s;
    else         bc[(size_t)r * 128 + j] = s;
}

// pack fp32 [relstride rows...][K][128] matrix into per-lane MFMA B-fragment order:
// P[((r*KS + ks)*8 + cb)*64 + lane][8] = S[r][ks*32 + (lane>>4)*8 + j][cb*16 + (lane&15)]
__global__ void pack_kernel(const float* __restrict__ S, unsigned short* __restrict__ P,
                            int relstride, int KS) {
    int r = blockIdx.y;
    int ks = blockIdx.x >> 3, cb = blockIdx.x & 7;
    int l = threadIdx.x;
    const float* Sr = S + (size_t)r * relstride;
    int col = cb * 16 + (l & 15);
    int kb = ks * 32 + (l >> 4) * 8;
    unsigned short v[8];
#pragma unroll
    for (int j = 0; j < 8; ++j) v[j] = f2bf(Sr[(size_t)(kb + j) * 128 + col]);
    unsigned short* dst = P + ((((size_t)r * KS + ks) * 8 + cb) * 64 + l) * 8;
    *(uint4*)dst = *(uint4*)v;
}

// ---------------- hs GEMM (MFMA): hs[r] = bf16(src[r] @ Wc[r] + bc[r]); el = hs . attn_l ----------------

__global__ __launch_bounds__(256) void gemm_hs(
    const float* __restrict__ src, const unsigned short* __restrict__ Bpack,
    const float* __restrict__ bc, const float* __restrict__ attn_l,
    unsigned short* __restrict__ hsb, float* __restrict__ el, int N) {
    const int r = blockIdx.y;
    const int n0 = blockIdx.x * 64;
    const int t = threadIdx.x;
    const int w = t >> 6, l = t & 63;
    __shared__ unsigned short Alds[64 * 256];  // 32KB, 512B rows, XOR-swizzled
    const float* A = src + (size_t)r * N * 256;
    // stage A tile fp32 -> bf16 (64 rows x 256 k)
#pragma unroll
    for (int i = 0; i < 16; ++i) {
        int cid = t + 256 * i;        // 4096 float4 chunks
        int row = cid >> 6, kq = cid & 63;
        float4 v = make_float4(0.f, 0.f, 0.f, 0.f);
        if (n0 + row < N) v = *(const float4*)(A + (size_t)(n0 + row) * 256 + kq * 4);
        unsigned lo = (unsigned)f2bf(v.x) | ((unsigned)f2bf(v.y) << 16);
        unsigned hi = (unsigned)f2bf(v.z) | ((unsigned)f2bf(v.w) << 16);
        int off = ((row * 512) + kq * 8) ^ ((row & 7) << 4);
        *(uint2*)((char*)Alds + off) = make_uint2(lo, hi);
    }
    __syncthreads();

    const bf16x8* bp = (const bf16x8*)(Bpack + (size_t)r * 256 * 128);
    f32x4 acc[8] = {};
    const int arow = w * 16 + (l & 15);
#pragma unroll
    for (int ks = 0; ks < 8; ++ks) {
        int aoff = ((arow * 512) + ks * 64 + (l >> 4) * 16) ^ ((arow & 7) << 4);
        bf16x8 av = *(const bf16x8*)((char*)Alds + aoff);
#pragma unroll
        for (int cf = 0; cf < 8; ++cf) {
            bf16x8 bv = bp[(ks * 8 + cf) * 64 + l];
            acc[cf] = __builtin_amdgcn_mfma_f32_16x16x32_bf16(av, bv, acc[cf], 0, 0, 0);
        }
    }

    float bcv[8], alv[8];
#pragma unroll
    for (int cf = 0; cf < 8; ++cf) {
        int col = cf * 16 + (l & 15);
        bcv[cf] = bc[r * 128 + col];
        alv[cf] = attn_l[r * 128 + col];
    }
#pragma unroll
    for (int i = 0; i < 4; ++i) {
        int row = n0 + w * 16 + (l >> 4) * 4 + i;
        float pe = 0.f;
        unsigned short hv[8];
#pragma unroll
        for (int cf = 0; cf < 8; ++cf) {
            float v = acc[cf][i] + bcv[cf];
            pe += v * alv[cf];
            hv[cf] = f2bf(v);
        }
        if (row < N) {
            unsigned short* hp = hsb + ((size_t)r * N + row) * 128 + (l & 15);
#pragma unroll
            for (int cf = 0; cf < 8; ++cf) hp[cf * 16] = hv[cf];
        }
        pe += __shfl_xor(pe, 1, 64);
        pe += __shfl_xor(pe, 2, 64);
        pe += __shfl_xor(pe, 4, 64);
        pe += __shfl_xor(pe, 8, 64);
        if ((l & 15) == 0 && row < N) el[(size_t)r * N + row] = pe;
    }
}

// ---------------- er: er[r][n] = dst_feat[n] . u[r] + cc[r] ----------------

__global__ void er_kernel(const float* __restrict__ dst_feat, const float* __restrict__ u,
                          const float* __restrict__ cc, float* __restrict__ er, int N) {
    __shared__ float us[3][256];
    for (int i = threadIdx.x; i < 3 * 256; i += 256) us[i / 256][i & 255] = u[i];
    __syncthreads();
    int wave = threadIdx.x >> 6, lane = threadIdx.x & 63;
    int n = blockIdx.x * 4 + wave;
    if (n >= N) return;
    float4 f = *(const float4*)(dst_feat + (size_t)n * 256 + lane * 4);
#pragma unroll
    for (int r = 0; r < R_REL; ++r) {
        float4 uv = *(float4*)&us[r][lane * 4];
        float s = f.x * uv.x + f.y * uv.y + f.z * uv.z + f.w * uv.w;
#pragma unroll
        for (int off = 32; off >= 1; off >>= 1) s += __shfl_xor(s, off, 64);
        if (lane == 0) er[(size_t)r * N + n] = s + cc[r];
    }
}

// ---------------- CSR build (dst-sorted) ----------------

__global__ void deg_kernel(const int* __restrict__ di, int* __restrict__ deg, int N, int E) {
    int r = blockIdx.y;
    int i = blockIdx.x * 256 + threadIdx.x;
    if (i >= E) return;
    atomicAdd(&deg[(size_t)r * N + di[(size_t)r * E + i]], 1);
}

__global__ __launch_bounds__(1024) void scan_kernel(const int* __restrict__ deg,
                                                    int* __restrict__ offs,
                                                    int* __restrict__ cur, int N) {
    const int r = blockIdx.x;
    const int t = threadIdx.x;
    const int lane = t & 63, wave = t >> 6;
    const int NW = 16;  // 1024/64
    __shared__ int wsum[NW];
    __shared__ int carry_s;
    if (t == 0) carry_s = 0;
    __syncthreads();
    for (int base = 0; base < N; base += 1024) {
        int idx = base + t;
        int v = (idx < N) ? deg[(size_t)r * N + idx] : 0;
        int x = v;
#pragma unroll
        for (int off = 1; off < 64; off <<= 1) {
            int y = __shfl_up(x, off, 64);
            if (lane >= off) x += y;
        }
        if (lane == 63) wsum[wave] = x;
        __syncthreads();
        if (wave == 0 && lane < NW) {
            int y = wsum[lane];
#pragma unroll
            for (int off = 1; off < NW; off <<= 1) {
                int z = __shfl_up(y, off, 64);
                if (lane >= off) y += z;
            }
            wsum[lane] = y;
        }
        __syncthreads();
        int waveoff = (wave > 0) ? wsum[wave - 1] : 0;
        int excl = carry_s + waveoff + x - v;
        if (idx < N) {
            offs[(size_t)r * N + idx] = excl;
            cur[(size_t)r * N + idx] = excl;
        }
        __syncthreads();
        if (t == 0) carry_s += wsum[NW - 1];
        __syncthreads();
    }
}

__global__ void fill_kernel(const int* __restrict__ si, const int* __restrict__ di,
                            int* __restrict__ cur, int* __restrict__ csr, int N, int E) {
    int r = blockIdx.y;
    int i = blockIdx.x * 256 + threadIdx.x;
    if (i >= E) return;
    size_t g = (size_t)r * E + i;
    int d = di[g];
    int pos = atomicAdd(&cur[(size_t)r * N + d], 1);
    csr[(size_t)r * E + pos] = si[g];
}

// ---------------- fused per-dst softmax + aggregation + bias + ELU -> z (bf16) ----------------

__global__ __launch_bounds__(256) void gather_kernel(
    const int* __restrict__ csr, const int* __restrict__ offs, const int* __restrict__ deg,
    const float* __restrict__ el, const float* __restrict__ er,
    const unsigned short* __restrict__ hsb, const float* __restrict__ b_gat,
    unsigned short* __restrict__ z, int N, int E) {
    const int r = blockIdx.y;
    const int wave = threadIdx.x >> 6, lane = threadIdx.x & 63;
    const int d = blockIdx.x * 4 + wave;
    if (d >= N) return;
    const float bg0 = b_gat[r * 128 + lane * 2];
    const float bg1 = b_gat[r * 128 + lane * 2 + 1];
    const int beg = offs[(size_t)r * N + d];
    const int dg = deg[(size_t)r * N + d];
    float2 acc = make_float2(0.f, 0.f);
    if (dg > 0) {
        const float erd = er[(size_t)r * N + d];
        const float* elr = el + (size_t)r * N;
        const int* csrr = csr + (size_t)r * E;
        const unsigned short* hsr = hsb + (size_t)r * N * 128;

        float m = -3.0e38f;
        for (int i = beg + lane; i < beg + dg; i += 64) {
            float e = elr[csrr[i]] + erd;
            e = e > 0.f ? e : 0.2f * e;
            m = fmaxf(m, e);
        }
#pragma unroll
        for (int off = 32; off >= 1; off >>= 1) m = fmaxf(m, __shfl_xor(m, off, 64));

        float ssum = 0.f;
        for (int c = beg; c < beg + dg; c += 64) {
            int nn = min(64, beg + dg - c);
            int src = 0; float p = 0.f;
            if (lane < nn) {
                src = csrr[c + lane];
                float e = elr[src] + erd;
                e = e > 0.f ? e : 0.2f * e;
                p = __expf(e - m);
                ssum += p;
            }
            for (int j = 0; j < nn; ++j) {
                float pj = __shfl(p, j, 64);
                int sj = __shfl(src, j, 64);
                unsigned hw = *(const unsigned*)(hsr + (size_t)sj * 128 + lane * 2);
                acc.x += pj * bf2f((unsigned short)(hw & 0xffffu));
                acc.y += pj * bf2f((unsigned short)(hw >> 16));
            }
        }
#pragma unroll
        for (int off = 32; off >= 1; off >>= 1) ssum += __shfl_xor(ssum, off, 64);
        float inv = 1.f / ssum;
        acc.x *= inv; acc.y *= inv;
    }
    float z0 = eluf(acc.x + bg0);
    float z1 = eluf(acc.y + bg1);
    unsigned* op = (unsigned*)(z + ((size_t)r * N + d) * 128 + lane * 2);
    *op = (unsigned)f2bf(z0) | ((unsigned)f2bf(z1) << 16);
}

// ---------------- semantic attention GEMM (MFMA) ----------------

__global__ __launch_bounds__(256) void gemm_sem(
    const unsigned short* __restrict__ z, const unsigned short* __restrict__ W1p,
    const float* __restrict__ b1, const float* __restrict__ w2,
    float* __restrict__ wsum, int N) {
    const int r = blockIdx.y;
    const int n0 = blockIdx.x * 64;
    const int t = threadIdx.x;
    const int w = t >> 6, l = t & 63;
    __shared__ unsigned short Alds[64 * 128];  // 16KB, 256B rows, XOR-swizzled
    const unsigned short* A = z + (size_t)r * N * 128;
#pragma unroll
    for (int i = 0; i < 4; ++i) {
        int cid = t + 256 * i;         // 1024 16B chunks
        int row = cid >> 4, kc = cid & 15;
        uint4 v = make_uint4(0, 0, 0, 0);
        if (n0 + row < N) v = *(const uint4*)(A + (size_t)(n0 + row) * 128 + kc * 8);
        int off = ((row * 256) + kc * 16) ^ ((row & 7) << 4);
        *(uint4*)((char*)Alds + off) = v;
    }
    __syncthreads();

    const bf16x8* bp = (const bf16x8*)W1p;
    f32x4 acc[8] = {};
    const int arow = w * 16 + (l & 15);
#pragma unroll
    for (int ks = 0; ks < 4; ++ks) {
        int aoff = ((arow * 256) + ks * 64 + (l >> 4) * 16) ^ ((arow & 7) << 4);
        bf16x8 av = *(const bf16x8*)((char*)Alds + aoff);
#pragma unroll
        for (int cf = 0; cf < 8; ++cf) {
            bf16x8 bv = bp[(ks * 8 + cf) * 64 + l];
            acc[cf] = __builtin_amdgcn_mfma_f32_16x16x32_bf16(av, bv, acc[cf], 0, 0, 0);
        }
    }
    float b1v[8], w2v[8];
#pragma unroll
    for (int cf = 0; cf < 8; ++cf) {
        int col = cf * 16 + (l & 15);
        b1v[cf] = b1[col];
        w2v[cf] = w2[col];
    }
    float wloc = 0.f;
#pragma unroll
    for (int i = 0; i < 4; ++i) {
        int row = n0 + w * 16 + (l >> 4) * 4 + i;
        float s = 0.f;
#pragma unroll
        for (int cf = 0; cf < 8; ++cf) s += tanhf(acc[cf][i] + b1v[cf]) * w2v[cf];
        s += __shfl_xor(s, 1, 64);
        s += __shfl_xor(s, 2, 64);
        s += __shfl_xor(s, 4, 64);
        s += __shfl_xor(s, 8, 64);
        if ((l & 15) == 0 && row < N) wloc += s;
    }
    wloc += __shfl_xor(wloc, 16, 64);
    wloc += __shfl_xor(wloc, 32, 64);
    if (l == 0) atomicAdd(&wsum[r], wloc);
}

__global__ void softmax_a(const float* __restrict__ wsum, float* __restrict__ aw, int N) {
    if (threadIdx.x == 0) {
        float w0 = wsum[0] / (float)N, w1 = wsum[1] / (float)N, w2 = wsum[2] / (float)N;
        float m = fmaxf(w0, fmaxf(w1, w2));
        float e0 = __expf(w0 - m), e1 = __expf(w1 - m), e2 = __expf(w2 - m);
        float s = e0 + e1 + e2;
        aw[0] = e0 / s; aw[1] = e1 / s; aw[2] = e2 / s;
    }
}

__global__ void combine(const unsigned short* __restrict__ z, const float* __restrict__ aw,
                        float* __restrict__ out, int N) {
    int idx = blockIdx.x * 256 + threadIdx.x;
    if (idx >= N * 32) return;
    int n = idx >> 5, c4 = idx & 31;
    float a0 = aw[0], a1 = aw[1], a2 = aw[2];
    uint2 z0 = *(const uint2*)(z + ((size_t)0 * N + n) * 128 + c4 * 4);
    uint2 z1 = *(const uint2*)(z + ((size_t)1 * N + n) * 128 + c4 * 4);
    uint2 z2 = *(const uint2*)(z + ((size_t)2 * N + n) * 128 + c4 * 4);
    float4 o;
    o.x = a0 * bf2f((unsigned short)(z0.x & 0xffffu)) + a1 * bf2f((unsigned short)(z1.x & 0xffffu)) + a2 * bf2f((unsigned short)(z2.x & 0xffffu));
    o.y = a0 * bf2f((unsigned short)(z0.x >> 16))     + a1 * bf2f((unsigned short)(z1.x >> 16))     + a2 * bf2f((unsigned short)(z2.x >> 16));
    o.z = a0 * bf2f((unsigned short)(z0.y & 0xffffu)) + a1 * bf2f((unsigned short)(z1.y & 0xffffu)) + a2 * bf2f((unsigned short)(z2.y & 0xffffu));
    o.w = a0 * bf2f((unsigned short)(z0.y >> 16))     + a1 * bf2f((unsigned short)(z1.y >> 16))     + a2 * bf2f((unsigned short)(z2.y >> 16));
    *(float4*)(out + (size_t)idx * 4) = o;
}

// ---------------- launch ----------------

extern "C" void kernel_launch(void* const* d_in, const int* in_sizes, int n_in,
                              void* d_out, int out_size, void* d_ws, size_t ws_size,
                              hipStream_t stream) {
    const float* dst_feat = (const float*)d_in[0];
    const float* src_feats = (const float*)d_in[1];
    const int*   src_idx  = (const int*)d_in[2];
    const int*   dst_idx  = (const int*)d_in[3];
    const float* WT_dst   = (const float*)d_in[4];
    const float* bT_dst   = (const float*)d_in[5];
    const float* WT_src   = (const float*)d_in[6];
    const float* bT_src   = (const float*)d_in[7];
    const float* W_gat    = (const float*)d_in[8];
    const float* attn_l   = (const float*)d_in[9];
    const float* attn_r   = (const float*)d_in[10];
    const float* b_gat    = (const float*)d_in[11];
    const float* W1_sem   = (const float*)d_in[12];
    const float* b1_sem   = (const float*)d_in[13];
    const float* w2_sem   = (const float*)d_in[14];

    const int N = in_sizes[0] / 256;
    const int E = in_sizes[2] / R_REL;
    float* out = (float*)d_out;

    char* ws = (char*)d_ws;
    size_t off = 0;
    auto alloc = [&](size_t bytes) { char* p = ws + off; off = align_up(off + bytes, 256); return p; };
    unsigned short* hsb   = (unsigned short*)alloc((size_t)R_REL * N * 128 * 2);
    unsigned short* zbuf  = (unsigned short*)alloc((size_t)R_REL * N * 128 * 2);
    float*    Wc    = (float*)alloc((size_t)R_REL * 256 * 128 * 4);
    unsigned short* Wcp   = (unsigned short*)alloc((size_t)R_REL * 256 * 128 * 2);
    unsigned short* W1p   = (unsigned short*)alloc((size_t)128 * 128 * 2);
    float*    bc    = (float*)alloc(R_REL * 128 * 4);
    float*    u     = (float*)alloc(R_REL * 256 * 4);
    float*    vv    = (float*)alloc(R_REL * 128 * 4);
    float*    cc    = (float*)alloc(R_REL * 4);
    float*    el    = (float*)alloc((size_t)R_REL * N * 4);
    float*    er    = (float*)alloc((size_t)R_REL * N * 4);
    int*      deg   = (int*)alloc((size_t)R_REL * N * 4);
    int*      offs  = (int*)alloc((size_t)R_REL * N * 4);
    int*      cur   = (int*)alloc((size_t)R_REL * N * 4);
    int*      csr   = (int*)alloc((size_t)R_REL * E * 4);
    float*    wsum  = (float*)alloc(R_REL * 4);
    float*    aw    = (float*)alloc(R_REL * 4);

    hipMemsetAsync(deg, 0, (size_t)R_REL * N * 4, stream);
    hipMemsetAsync(wsum, 0, R_REL * 4, stream);

    // weight prep
    v_kernel<<<R_REL, 128, 0, stream>>>(W_gat, attn_r, vv);
    u_kernel<<<R_REL, 256, 0, stream>>>(WT_dst, bT_dst, vv, u, cc);
    wc_kernel<<<dim3(257, R_REL), 128, 0, stream>>>(WT_src, bT_src, W_gat, Wc, bc);
    pack_kernel<<<dim3(64, R_REL), 64, 0, stream>>>(Wc, Wcp, 256 * 128, 8);
    pack_kernel<<<dim3(32, 1), 64, 0, stream>>>(W1_sem, W1p, 0, 4);

    // CSR build (independent of GEMMs)
    deg_kernel<<<dim3((E + 255) / 256, R_REL), 256, 0, stream>>>(dst_idx, deg, N, E);
    scan_kernel<<<R_REL, 1024, 0, stream>>>(deg, offs, cur, N);
    fill_kernel<<<dim3((E + 255) / 256, R_REL), 256, 0, stream>>>(src_idx, dst_idx, cur, csr, N, E);

    // node projections
    dim3 g1((N + 63) / 64, R_REL);
    gemm_hs<<<g1, 256, 0, stream>>>(src_feats, Wcp, bc, attn_l, hsb, el, N);
    er_kernel<<<(N + 3) / 4, 256, 0, stream>>>(dst_feat, u, cc, er, N);

    // fused edge softmax + aggregation -> z
    gather_kernel<<<dim3((N + 3) / 4, R_REL), 256, 0, stream>>>(csr, offs, deg, el, er, hsb, b_gat, zbuf, N, E);

    // semantic attention + combine
    gemm_sem<<<g1, 256, 0, stream>>>(zbuf, W1p, b1_sem, w2_sem, wsum, N);
    softmax_a<<<1, 64, 0, stream>>>(wsum, aw, N);
    combine<<<(N * 32 + 255) / 256, 256, 0, stream>>>(zbuf, aw, out, N);
}

// Round 4
// 567.054 us; speedup vs baseline: 5.5487x; 1.0781x over previous
//
#include <hip/hip_runtime.h>
#include <hip/hip_bf16.h>

#define R_REL 3

typedef __attribute__((ext_vector_type(8))) short bf16x8;
typedef __attribute__((ext_vector_type(4))) float f32x4;

static inline size_t align_up(size_t x, size_t a) { return (x + a - 1) & ~(a - 1); }

__device__ __forceinline__ float eluf(float x) {
    return x > 0.f ? x : (__expf(x) - 1.f);
}
__device__ __forceinline__ unsigned short f2bf(float f) {
    __hip_bfloat16 h = __float2bfloat16(f);
    return *reinterpret_cast<unsigned short*>(&h);
}
__device__ __forceinline__ unsigned pk2bf(float lo, float hi) {
    __hip_bfloat162 h = __float22bfloat162_rn(make_float2(lo, hi));
    return *reinterpret_cast<unsigned*>(&h);
}
__device__ __forceinline__ float bf2f(unsigned short h) {
    return __uint_as_float((unsigned)h << 16);
}

// ---------------- tiny weight-prep kernels ----------------

__global__ void v_kernel(const float* __restrict__ W_gat, const float* __restrict__ attn_r,
                         float* __restrict__ v) {
    int r = blockIdx.x;
    __shared__ float ar[128];
    if (threadIdx.x < 128) ar[threadIdx.x] = attn_r[r * 128 + threadIdx.x];
    __syncthreads();
    if (threadIdx.x < 128) {
        const float* W = W_gat + (size_t)r * 128 * 128 + (size_t)threadIdx.x * 128;
        float s = 0.f;
        for (int j = 0; j < 128; ++j) s += W[j] * ar[j];
        v[r * 128 + threadIdx.x] = s;
    }
}

__global__ void u_kernel(const float* __restrict__ WT_dst, const float* __restrict__ bT_dst,
                         const float* __restrict__ v, float* __restrict__ u,
                         float* __restrict__ cc) {
    int r = blockIdx.x;
    __shared__ float vs[128];
    if (threadIdx.x < 128) vs[threadIdx.x] = v[r * 128 + threadIdx.x];
    __syncthreads();
    const float* W = WT_dst + (size_t)threadIdx.x * 128;
    float s = 0.f;
    for (int i = 0; i < 128; ++i) s += W[i] * vs[i];
    u[r * 256 + threadIdx.x] = s;
    if (threadIdx.x == 0) {
        float c = 0.f;
        for (int i = 0; i < 128; ++i) c += bT_dst[i] * vs[i];
        cc[r] = c;
    }
}

__global__ void wc_kernel(const float* __restrict__ WT_src, const float* __restrict__ bT_src,
                          const float* __restrict__ W_gat, float* __restrict__ Wc,
                          float* __restrict__ bc) {
    int r = blockIdx.y;
    int k = blockIdx.x;  // 0..256
    int j = threadIdx.x; // 0..127
    __shared__ float as[128];
    const float* arow = (k < 256) ? (WT_src + ((size_t)r * 256 + k) * 128)
                                  : (bT_src + (size_t)r * 128);
    as[j] = arow[j];
    __syncthreads();
    const float* W = W_gat + (size_t)r * 128 * 128;
    float s = 0.f;
    for (int i = 0; i < 128; ++i) s += as[i] * W[(size_t)i * 128 + j];
    if (k < 256) Wc[((size_t)r * 256 + k) * 128 + j] = s;
    else         bc[(size_t)r * 128 + j] = s;
}

// pack fp32 [relstride rows...][K][128] matrix into per-lane MFMA B-fragment order
__global__ void pack_kernel(const float* __restrict__ S, unsigned short* __restrict__ P,
                            int relstride, int KS) {
    int r = blockIdx.y;
    int ks = blockIdx.x >> 3, cb = blockIdx.x & 7;
    int l = threadIdx.x;
    const float* Sr = S + (size_t)r * relstride;
    int col = cb * 16 + (l & 15);
    int kb = ks * 32 + (l >> 4) * 8;
    unsigned short v[8];
#pragma unroll
    for (int j = 0; j < 8; ++j) v[j] = f2bf(Sr[(size_t)(kb + j) * 128 + col]);
    unsigned short* dst = P + ((((size_t)r * KS + ks) * 8 + cb) * 64 + l) * 8;
    *(uint4*)dst = *(uint4*)v;
}

// ---------------- hs GEMM (MFMA, A direct from global): hs = bf16(src@Wc + bc); el = hs.attn_l ----

__global__ __launch_bounds__(256) void gemm_hs(
    const float* __restrict__ src, const unsigned short* __restrict__ Bpack,
    const float* __restrict__ bc, const float* __restrict__ attn_l,
    unsigned short* __restrict__ hsb, float* __restrict__ el, int N) {
    const int r = blockIdx.y;
    const int t = threadIdx.x;
    const int w = t >> 6, l = t & 63;
    const int rowbase = blockIdx.x * 64 + w * 16;
    const int arow_i = rowbase + (l & 15);
    const int kg = l >> 4;
    const float* A = src + (size_t)r * N * 256;
    const float* arow = A + (size_t)(arow_i < N ? arow_i : N - 1) * 256;
    const bf16x8* bp = (const bf16x8*)(Bpack + (size_t)r * 256 * 128);
    f32x4 acc[8] = {};
#pragma unroll
    for (int ks = 0; ks < 8; ++ks) {
        float4 a0 = *(const float4*)(arow + ks * 32 + kg * 8);
        float4 a1 = *(const float4*)(arow + ks * 32 + kg * 8 + 4);
        uint4 uv;
        uv.x = pk2bf(a0.x, a0.y);
        uv.y = pk2bf(a0.z, a0.w);
        uv.z = pk2bf(a1.x, a1.y);
        uv.w = pk2bf(a1.z, a1.w);
        bf16x8 av = *(bf16x8*)&uv;
#pragma unroll
        for (int cf = 0; cf < 8; ++cf) {
            bf16x8 bv = bp[(ks * 8 + cf) * 64 + l];
            acc[cf] = __builtin_amdgcn_mfma_f32_16x16x32_bf16(av, bv, acc[cf], 0, 0, 0);
        }
    }
    float bcv[8], alv[8];
#pragma unroll
    for (int cf = 0; cf < 8; ++cf) {
        int col = cf * 16 + (l & 15);
        bcv[cf] = bc[r * 128 + col];
        alv[cf] = attn_l[r * 128 + col];
    }
#pragma unroll
    for (int i = 0; i < 4; ++i) {
        int row = rowbase + (l >> 4) * 4 + i;
        float pe = 0.f;
        unsigned short hv[8];
#pragma unroll
        for (int cf = 0; cf < 8; ++cf) {
            float v = acc[cf][i] + bcv[cf];
            pe += v * alv[cf];
            hv[cf] = f2bf(v);
        }
        if (row < N) {
            unsigned short* hp = hsb + ((size_t)r * N + row) * 128 + (l & 15);
#pragma unroll
            for (int cf = 0; cf < 8; ++cf) hp[cf * 16] = hv[cf];
        }
        pe += __shfl_xor(pe, 1, 64);
        pe += __shfl_xor(pe, 2, 64);
        pe += __shfl_xor(pe, 4, 64);
        pe += __shfl_xor(pe, 8, 64);
        if ((l & 15) == 0 && row < N) el[(size_t)r * N + row] = pe;
    }
}

// ---------------- er: er[r][n] = dst_feat[n] . u[r] + cc[r] ----------------

__global__ void er_kernel(const float* __restrict__ dst_feat, const float* __restrict__ u,
                          const float* __restrict__ cc, float* __restrict__ er, int N) {
    __shared__ float us[3][256];
    for (int i = threadIdx.x; i < 3 * 256; i += 256) us[i / 256][i & 255] = u[i];
    __syncthreads();
    int wave = threadIdx.x >> 6, lane = threadIdx.x & 63;
    int n = blockIdx.x * 4 + wave;
    if (n >= N) return;
    float4 f = *(const float4*)(dst_feat + (size_t)n * 256 + lane * 4);
#pragma unroll
    for (int r = 0; r < R_REL; ++r) {
        float4 uv = *(float4*)&us[r][lane * 4];
        float s = f.x * uv.x + f.y * uv.y + f.z * uv.z + f.w * uv.w;
#pragma unroll
        for (int off = 32; off >= 1; off >>= 1) s += __shfl_xor(s, off, 64);
        if (lane == 0) er[(size_t)r * N + n] = s + cc[r];
    }
}

// ---------------- CSR build (dst-sorted) ----------------

__global__ void deg_kernel(const int* __restrict__ di, int* __restrict__ deg, int N, int E) {
    int r = blockIdx.y;
    int i = blockIdx.x * 256 + threadIdx.x;
    if (i >= E) return;
    atomicAdd(&deg[(size_t)r * N + di[(size_t)r * E + i]], 1);
}

__global__ __launch_bounds__(1024) void scan_kernel(const int* __restrict__ deg,
                                                    int* __restrict__ offs,
                                                    int* __restrict__ cur, int N) {
    const int r = blockIdx.x;
    const int t = threadIdx.x;
    const int lane = t & 63, wave = t >> 6;
    const int NW = 16;
    __shared__ int wsum[NW];
    __shared__ int carry_s;
    if (t == 0) carry_s = 0;
    __syncthreads();
    for (int base = 0; base < N; base += 1024) {
        int idx = base + t;
        int v = (idx < N) ? deg[(size_t)r * N + idx] : 0;
        int x = v;
#pragma unroll
        for (int off = 1; off < 64; off <<= 1) {
            int y = __shfl_up(x, off, 64);
            if (lane >= off) x += y;
        }
        if (lane == 63) wsum[wave] = x;
        __syncthreads();
        if (wave == 0 && lane < NW) {
            int y = wsum[lane];
#pragma unroll
            for (int off = 1; off < NW; off <<= 1) {
                int z = __shfl_up(y, off, 64);
                if (lane >= off) y += z;
            }
            wsum[lane] = y;
        }
        __syncthreads();
        int waveoff = (wave > 0) ? wsum[wave - 1] : 0;
        int excl = carry_s + waveoff + x - v;
        if (idx < N) {
            offs[(size_t)r * N + idx] = excl;
            cur[(size_t)r * N + idx] = excl;
        }
        __syncthreads();
        if (t == 0) carry_s += wsum[NW - 1];
        __syncthreads();
    }
}

__global__ void fill_kernel(const int* __restrict__ si, const int* __restrict__ di,
                            int* __restrict__ cur, int* __restrict__ csr, int N, int E) {
    int r = blockIdx.y;
    int i = blockIdx.x * 256 + threadIdx.x;
    if (i >= E) return;
    size_t g = (size_t)r * E + i;
    int d = di[g];
    int pos = atomicAdd(&cur[(size_t)r * N + d], 1);
    csr[(size_t)r * E + pos] = si[g];
}

// ---------------- fused per-dst softmax + aggregation + bias + ELU -> z (bf16) ----------------
// 4x16-lane groups per wave: 4 src rows in flight per load instruction.

__global__ __launch_bounds__(256) void gather_kernel(
    const int* __restrict__ csr, const int* __restrict__ offs, const int* __restrict__ deg,
    const float* __restrict__ el, const float* __restrict__ er,
    const unsigned short* __restrict__ hsb, const float* __restrict__ b_gat,
    unsigned short* __restrict__ z, int N, int E) {
    const int r = blockIdx.y;
    const int wid = threadIdx.x >> 6;
    const int l = threadIdx.x & 63;
    const int grp = l >> 4, gl = l & 15;
    const int d = blockIdx.x * 4 + wid;
    if (d >= N) return;
    const int beg = offs[(size_t)r * N + d];
    const int dg = deg[(size_t)r * N + d];
    float ac[8] = {0.f, 0.f, 0.f, 0.f, 0.f, 0.f, 0.f, 0.f};
    if (dg > 0) {
        const float erd = er[(size_t)r * N + d];
        const float* elr = el + (size_t)r * N;
        const int* csrr = csr + (size_t)r * E;
        const unsigned short* hsr = hsb + (size_t)r * N * 128;

        // pass 1: max over edges (64-lane strided)
        float m = -3.0e38f;
        for (int i = beg + l; i < beg + dg; i += 64) {
            float e = elr[csrr[i]] + erd;
            e = e > 0.f ? e : 0.2f * e;
            m = fmaxf(m, e);
        }
#pragma unroll
        for (int off = 32; off >= 1; off >>= 1) m = fmaxf(m, __shfl_xor(m, off, 64));

        // pass 2: group-parallel exp + broadcast-accumulate
        float ssum = 0.f;
        for (int c = beg; c < beg + dg; c += 64) {
            int nn = min(64, beg + dg - c);
            int pos = grp + gl * 4;  // this lane's edge slot in chunk
            int src = 0; float p = 0.f;
            if (pos < nn) {
                src = csrr[c + pos];
                float e = elr[src] + erd;
                e = e > 0.f ? e : 0.2f * e;
                p = __expf(e - m);
                ssum += p;
            }
            int ng = (nn - grp + 3) >> 2;  // edges owned by this group (group-uniform)
            for (int j = 0; j < ng; ++j) {
                float pj = __shfl(p, (l & 48) + j, 64);
                int sj = __shfl(src, (l & 48) + j, 64);
                uint4 hw = *(const uint4*)(hsr + (size_t)sj * 128 + gl * 8);
                ac[0] += pj * bf2f((unsigned short)(hw.x & 0xffffu));
                ac[1] += pj * bf2f((unsigned short)(hw.x >> 16));
                ac[2] += pj * bf2f((unsigned short)(hw.y & 0xffffu));
                ac[3] += pj * bf2f((unsigned short)(hw.y >> 16));
                ac[4] += pj * bf2f((unsigned short)(hw.z & 0xffffu));
                ac[5] += pj * bf2f((unsigned short)(hw.z >> 16));
                ac[6] += pj * bf2f((unsigned short)(hw.w & 0xffffu));
                ac[7] += pj * bf2f((unsigned short)(hw.w >> 16));
            }
        }
#pragma unroll
        for (int off = 1; off <= 32; off <<= 1) ssum += __shfl_xor(ssum, off, 64);
#pragma unroll
        for (int k = 0; k < 8; ++k) {
            ac[k] += __shfl_xor(ac[k], 16, 64);
            ac[k] += __shfl_xor(ac[k], 32, 64);
        }
        float inv = 1.f / ssum;
#pragma unroll
        for (int k = 0; k < 8; ++k) ac[k] *= inv;
    }
    if (grp == 0) {
        const float* bg = b_gat + r * 128 + gl * 8;
        uint4 ow;
        ow.x = pk2bf(eluf(ac[0] + bg[0]), eluf(ac[1] + bg[1]));
        ow.y = pk2bf(eluf(ac[2] + bg[2]), eluf(ac[3] + bg[3]));
        ow.z = pk2bf(eluf(ac[4] + bg[4]), eluf(ac[5] + bg[5]));
        ow.w = pk2bf(eluf(ac[6] + bg[6]), eluf(ac[7] + bg[7]));
        *(uint4*)(z + ((size_t)r * N + d) * 128 + gl * 8) = ow;
    }
}

// ---------------- semantic attention GEMM (MFMA) ----------------

__global__ __launch_bounds__(256) void gemm_sem(
    const unsigned short* __restrict__ z, const unsigned short* __restrict__ W1p,
    const float* __restrict__ b1, const float* __restrict__ w2,
    float* __restrict__ wsum, int N) {
    const int r = blockIdx.y;
    const int n0 = blockIdx.x * 64;
    const int t = threadIdx.x;
    const int w = t >> 6, l = t & 63;
    __shared__ unsigned short Alds[64 * 128];
    const unsigned short* A = z + (size_t)r * N * 128;
#pragma unroll
    for (int i = 0; i < 4; ++i) {
        int cid = t + 256 * i;
        int row = cid >> 4, kc = cid & 15;
        uint4 v = make_uint4(0, 0, 0, 0);
        if (n0 + row < N) v = *(const uint4*)(A + (size_t)(n0 + row) * 128 + kc * 8);
        int off = ((row * 256) + kc * 16) ^ ((row & 7) << 4);
        *(uint4*)((char*)Alds + off) = v;
    }
    __syncthreads();

    const bf16x8* bp = (const bf16x8*)W1p;
    f32x4 acc[8] = {};
    const int arow = w * 16 + (l & 15);
#pragma unroll
    for (int ks = 0; ks < 4; ++ks) {
        int aoff = ((arow * 256) + ks * 64 + (l >> 4) * 16) ^ ((arow & 7) << 4);
        bf16x8 av = *(const bf16x8*)((char*)Alds + aoff);
#pragma unroll
        for (int cf = 0; cf < 8; ++cf) {
            bf16x8 bv = bp[(ks * 8 + cf) * 64 + l];
            acc[cf] = __builtin_amdgcn_mfma_f32_16x16x32_bf16(av, bv, acc[cf], 0, 0, 0);
        }
    }
    float b1v[8], w2v[8];
#pragma unroll
    for (int cf = 0; cf < 8; ++cf) {
        int col = cf * 16 + (l & 15);
        b1v[cf] = b1[col];
        w2v[cf] = w2[col];
    }
    float wloc = 0.f;
#pragma unroll
    for (int i = 0; i < 4; ++i) {
        int row = n0 + w * 16 + (l >> 4) * 4 + i;
        float s = 0.f;
#pragma unroll
        for (int cf = 0; cf < 8; ++cf) s += tanhf(acc[cf][i] + b1v[cf]) * w2v[cf];
        s += __shfl_xor(s, 1, 64);
        s += __shfl_xor(s, 2, 64);
        s += __shfl_xor(s, 4, 64);
        s += __shfl_xor(s, 8, 64);
        if ((l & 15) == 0 && row < N) wloc += s;
    }
    wloc += __shfl_xor(wloc, 16, 64);
    wloc += __shfl_xor(wloc, 32, 64);
    if (l == 0) atomicAdd(&wsum[r], wloc);
}

__global__ void softmax_a(const float* __restrict__ wsum, float* __restrict__ aw, int N) {
    if (threadIdx.x == 0) {
        float w0 = wsum[0] / (float)N, w1 = wsum[1] / (float)N, w2 = wsum[2] / (float)N;
        float m = fmaxf(w0, fmaxf(w1, w2));
        float e0 = __expf(w0 - m), e1 = __expf(w1 - m), e2 = __expf(w2 - m);
        float s = e0 + e1 + e2;
        aw[0] = e0 / s; aw[1] = e1 / s; aw[2] = e2 / s;
    }
}

__global__ void combine(const unsigned short* __restrict__ z, const float* __restrict__ aw,
                        float* __restrict__ out, int N) {
    int idx = blockIdx.x * 256 + threadIdx.x;
    if (idx >= N * 32) return;
    int n = idx >> 5, c4 = idx & 31;
    float a0 = aw[0], a1 = aw[1], a2 = aw[2];
    uint2 z0 = *(const uint2*)(z + ((size_t)0 * N + n) * 128 + c4 * 4);
    uint2 z1 = *(const uint2*)(z + ((size_t)1 * N + n) * 128 + c4 * 4);
    uint2 z2 = *(const uint2*)(z + ((size_t)2 * N + n) * 128 + c4 * 4);
    float4 o;
    o.x = a0 * bf2f((unsigned short)(z0.x & 0xffffu)) + a1 * bf2f((unsigned short)(z1.x & 0xffffu)) + a2 * bf2f((unsigned short)(z2.x & 0xffffu));
    o.y = a0 * bf2f((unsigned short)(z0.x >> 16))     + a1 * bf2f((unsigned short)(z1.x >> 16))     + a2 * bf2f((unsigned short)(z2.x >> 16));
    o.z = a0 * bf2f((unsigned short)(z0.y & 0xffffu)) + a1 * bf2f((unsigned short)(z1.y & 0xffffu)) + a2 * bf2f((unsigned short)(z2.y & 0xffffu));
    o.w = a0 * bf2f((unsigned short)(z0.y >> 16))     + a1 * bf2f((unsigned short)(z1.y >> 16))     + a2 * bf2f((unsigned short)(z2.y >> 16));
    *(float4*)(out + (size_t)idx * 4) = o;
}

// ---------------- launch ----------------

extern "C" void kernel_launch(void* const* d_in, const int* in_sizes, int n_in,
                              void* d_out, int out_size, void* d_ws, size_t ws_size,
                              hipStream_t stream) {
    const float* dst_feat = (const float*)d_in[0];
    const float* src_feats = (const float*)d_in[1];
    const int*   src_idx  = (const int*)d_in[2];
    const int*   dst_idx  = (const int*)d_in[3];
    const float* WT_dst   = (const float*)d_in[4];
    const float* bT_dst   = (const float*)d_in[5];
    const float* WT_src   = (const float*)d_in[6];
    const float* bT_src   = (const float*)d_in[7];
    const float* W_gat    = (const float*)d_in[8];
    const float* attn_l   = (const float*)d_in[9];
    const float* attn_r   = (const float*)d_in[10];
    const float* b_gat    = (const float*)d_in[11];
    const float* W1_sem   = (const float*)d_in[12];
    const float* b1_sem   = (const float*)d_in[13];
    const float* w2_sem   = (const float*)d_in[14];

    const int N = in_sizes[0] / 256;
    const int E = in_sizes[2] / R_REL;
    float* out = (float*)d_out;

    char* ws = (char*)d_ws;
    size_t off = 0;
    auto alloc = [&](size_t bytes) { char* p = ws + off; off = align_up(off + bytes, 256); return p; };
    unsigned short* hsb   = (unsigned short*)alloc((size_t)R_REL * N * 128 * 2);
    unsigned short* zbuf  = (unsigned short*)alloc((size_t)R_REL * N * 128 * 2);
    float*    Wc    = (float*)alloc((size_t)R_REL * 256 * 128 * 4);
    unsigned short* Wcp   = (unsigned short*)alloc((size_t)R_REL * 256 * 128 * 2);
    unsigned short* W1p   = (unsigned short*)alloc((size_t)128 * 128 * 2);
    float*    bc    = (float*)alloc(R_REL * 128 * 4);
    float*    u     = (float*)alloc(R_REL * 256 * 4);
    float*    vv    = (float*)alloc(R_REL * 128 * 4);
    float*    cc    = (float*)alloc(R_REL * 4);
    float*    el    = (float*)alloc((size_t)R_REL * N * 4);
    float*    er    = (float*)alloc((size_t)R_REL * N * 4);
    int*      deg   = (int*)alloc((size_t)R_REL * N * 4);
    int*      offs  = (int*)alloc((size_t)R_REL * N * 4);
    int*      cur   = (int*)alloc((size_t)R_REL * N * 4);
    int*      csr   = (int*)alloc((size_t)R_REL * E * 4);
    float*    wsum  = (float*)alloc(R_REL * 4);
    float*    aw    = (float*)alloc(R_REL * 4);

    hipMemsetAsync(deg, 0, (size_t)R_REL * N * 4, stream);
    hipMemsetAsync(wsum, 0, R_REL * 4, stream);

    // weight prep
    v_kernel<<<R_REL, 128, 0, stream>>>(W_gat, attn_r, vv);
    u_kernel<<<R_REL, 256, 0, stream>>>(WT_dst, bT_dst, vv, u, cc);
    wc_kernel<<<dim3(257, R_REL), 128, 0, stream>>>(WT_src, bT_src, W_gat, Wc, bc);
    pack_kernel<<<dim3(64, R_REL), 64, 0, stream>>>(Wc, Wcp, 256 * 128, 8);
    pack_kernel<<<dim3(32, 1), 64, 0, stream>>>(W1_sem, W1p, 0, 4);

    // CSR build
    deg_kernel<<<dim3((E + 255) / 256, R_REL), 256, 0, stream>>>(dst_idx, deg, N, E);
    scan_kernel<<<R_REL, 1024, 0, stream>>>(deg, offs, cur, N);
    fill_kernel<<<dim3((E + 255) / 256, R_REL), 256, 0, stream>>>(src_idx, dst_idx, cur, csr, N, E);

    // node projections
    dim3 g1((N + 63) / 64, R_REL);
    gemm_hs<<<g1, 256, 0, stream>>>(src_feats, Wcp, bc, attn_l, hsb, el, N);
    er_kernel<<<(N + 3) / 4, 256, 0, stream>>>(dst_feat, u, cc, er, N);

    // fused edge softmax + aggregation -> z
    gather_kernel<<<dim3((N + 3) / 4, R_REL), 256, 0, stream>>>(csr, offs, deg, el, er, hsb, b_gat, zbuf, N, E);

    // semantic attention + combine
    gemm_sem<<<g1, 256, 0, stream>>>(zbuf, W1p, b1_sem, w2_sem, wsum, N);
    softmax_a<<<1, 64, 0, stream>>>(wsum, aw, N);
    combine<<<(N * 32 + 255) / 256, 256, 0, stream>>>(zbuf, aw, out, N);
}

// Round 5
// 464.840 us; speedup vs baseline: 6.7688x; 1.2199x over previous
//
#include <hip/hip_runtime.h>
#include <hip/hip_bf16.h>

#define R_REL 3

typedef __attribute__((ext_vector_type(8))) short bf16x8;
typedef __attribute__((ext_vector_type(4))) float f32x4;

static inline size_t align_up(size_t x, size_t a) { return (x + a - 1) & ~(a - 1); }

__device__ __forceinline__ float eluf(float x) {
    return x > 0.f ? x : (__expf(x) - 1.f);
}
__device__ __forceinline__ unsigned short f2bf(float f) {
    __hip_bfloat16 h = __float2bfloat16(f);
    return *reinterpret_cast<unsigned short*>(&h);
}
__device__ __forceinline__ unsigned pk2bf(float lo, float hi) {
    __hip_bfloat162 h = __float22bfloat162_rn(make_float2(lo, hi));
    return *reinterpret_cast<unsigned*>(&h);
}
__device__ __forceinline__ float bf2f(unsigned short h) {
    return __uint_as_float((unsigned)h << 16);
}

// ---------------- tiny weight-prep kernels ----------------

__global__ void v_kernel(const float* __restrict__ W_gat, const float* __restrict__ attn_r,
                         float* __restrict__ v) {
    int r = blockIdx.x;
    __shared__ float ar[128];
    if (threadIdx.x < 128) ar[threadIdx.x] = attn_r[r * 128 + threadIdx.x];
    __syncthreads();
    if (threadIdx.x < 128) {
        const float* W = W_gat + (size_t)r * 128 * 128 + (size_t)threadIdx.x * 128;
        float s = 0.f;
        for (int j = 0; j < 128; ++j) s += W[j] * ar[j];
        v[r * 128 + threadIdx.x] = s;
    }
}

__global__ void u_kernel(const float* __restrict__ WT_dst, const float* __restrict__ bT_dst,
                         const float* __restrict__ v, float* __restrict__ u,
                         float* __restrict__ cc) {
    int r = blockIdx.x;
    __shared__ float vs[128];
    if (threadIdx.x < 128) vs[threadIdx.x] = v[r * 128 + threadIdx.x];
    __syncthreads();
    const float* W = WT_dst + (size_t)threadIdx.x * 128;
    float s = 0.f;
    for (int i = 0; i < 128; ++i) s += W[i] * vs[i];
    u[r * 256 + threadIdx.x] = s;
    if (threadIdx.x == 0) {
        float c = 0.f;
        for (int i = 0; i < 128; ++i) c += bT_dst[i] * vs[i];
        cc[r] = c;
    }
}

__global__ void wc_kernel(const float* __restrict__ WT_src, const float* __restrict__ bT_src,
                          const float* __restrict__ W_gat, float* __restrict__ Wc,
                          float* __restrict__ bc) {
    int r = blockIdx.y;
    int k = blockIdx.x;  // 0..256
    int j = threadIdx.x; // 0..127
    __shared__ float as[128];
    const float* arow = (k < 256) ? (WT_src + ((size_t)r * 256 + k) * 128)
                                  : (bT_src + (size_t)r * 128);
    as[j] = arow[j];
    __syncthreads();
    const float* W = W_gat + (size_t)r * 128 * 128;
    float s = 0.f;
    for (int i = 0; i < 128; ++i) s += as[i] * W[(size_t)i * 128 + j];
    if (k < 256) Wc[((size_t)r * 256 + k) * 128 + j] = s;
    else         bc[(size_t)r * 128 + j] = s;
}

// pack fp32 [relstride rows...][K][128] matrix into per-lane MFMA B-fragment order
__global__ void pack_kernel(const float* __restrict__ S, unsigned short* __restrict__ P,
                            int relstride, int KS) {
    int r = blockIdx.y;
    int ks = blockIdx.x >> 3, cb = blockIdx.x & 7;
    int l = threadIdx.x;
    const float* Sr = S + (size_t)r * relstride;
    int col = cb * 16 + (l & 15);
    int kb = ks * 32 + (l >> 4) * 8;
    unsigned short v[8];
#pragma unroll
    for (int j = 0; j < 8; ++j) v[j] = f2bf(Sr[(size_t)(kb + j) * 128 + col]);
    unsigned short* dst = P + ((((size_t)r * KS + ks) * 8 + cb) * 64 + l) * 8;
    *(uint4*)dst = *(uint4*)v;
}

// ---------------- hs GEMM (MFMA, A direct from global): hs = bf16(src@Wc + bc); el = hs.attn_l ----

__global__ __launch_bounds__(256) void gemm_hs(
    const float* __restrict__ src, const unsigned short* __restrict__ Bpack,
    const float* __restrict__ bc, const float* __restrict__ attn_l,
    unsigned short* __restrict__ hsb, float* __restrict__ el, int N) {
    const int r = blockIdx.y;
    const int t = threadIdx.x;
    const int w = t >> 6, l = t & 63;
    const int rowbase = blockIdx.x * 64 + w * 16;
    const int arow_i = rowbase + (l & 15);
    const int kg = l >> 4;
    const float* A = src + (size_t)r * N * 256;
    const float* arow = A + (size_t)(arow_i < N ? arow_i : N - 1) * 256;
    const bf16x8* bp = (const bf16x8*)(Bpack + (size_t)r * 256 * 128);
    f32x4 acc[8] = {};
#pragma unroll
    for (int ks = 0; ks < 8; ++ks) {
        float4 a0 = *(const float4*)(arow + ks * 32 + kg * 8);
        float4 a1 = *(const float4*)(arow + ks * 32 + kg * 8 + 4);
        uint4 uv;
        uv.x = pk2bf(a0.x, a0.y);
        uv.y = pk2bf(a0.z, a0.w);
        uv.z = pk2bf(a1.x, a1.y);
        uv.w = pk2bf(a1.z, a1.w);
        bf16x8 av = *(bf16x8*)&uv;
#pragma unroll
        for (int cf = 0; cf < 8; ++cf) {
            bf16x8 bv = bp[(ks * 8 + cf) * 64 + l];
            acc[cf] = __builtin_amdgcn_mfma_f32_16x16x32_bf16(av, bv, acc[cf], 0, 0, 0);
        }
    }
    float bcv[8], alv[8];
#pragma unroll
    for (int cf = 0; cf < 8; ++cf) {
        int col = cf * 16 + (l & 15);
        bcv[cf] = bc[r * 128 + col];
        alv[cf] = attn_l[r * 128 + col];
    }
#pragma unroll
    for (int i = 0; i < 4; ++i) {
        int row = rowbase + (l >> 4) * 4 + i;
        float pe = 0.f;
        unsigned short hv[8];
#pragma unroll
        for (int cf = 0; cf < 8; ++cf) {
            float v = acc[cf][i] + bcv[cf];
            pe += v * alv[cf];
            hv[cf] = f2bf(v);
        }
        if (row < N) {
            unsigned short* hp = hsb + ((size_t)r * N + row) * 128 + (l & 15);
#pragma unroll
            for (int cf = 0; cf < 8; ++cf) hp[cf * 16] = hv[cf];
        }
        pe += __shfl_xor(pe, 1, 64);
        pe += __shfl_xor(pe, 2, 64);
        pe += __shfl_xor(pe, 4, 64);
        pe += __shfl_xor(pe, 8, 64);
        if ((l & 15) == 0 && row < N) el[(size_t)r * N + row] = pe;
    }
}

// ---------------- er: er[r][n] = dst_feat[n] . u[r] + cc[r] ----------------

__global__ void er_kernel(const float* __restrict__ dst_feat, const float* __restrict__ u,
                          const float* __restrict__ cc, float* __restrict__ er, int N) {
    __shared__ float us[3][256];
    for (int i = threadIdx.x; i < 3 * 256; i += 256) us[i / 256][i & 255] = u[i];
    __syncthreads();
    int wave = threadIdx.x >> 6, lane = threadIdx.x & 63;
    int n = blockIdx.x * 4 + wave;
    if (n >= N) return;
    float4 f = *(const float4*)(dst_feat + (size_t)n * 256 + lane * 4);
#pragma unroll
    for (int r = 0; r < R_REL; ++r) {
        float4 uv = *(float4*)&us[r][lane * 4];
        float s = f.x * uv.x + f.y * uv.y + f.z * uv.z + f.w * uv.w;
#pragma unroll
        for (int off = 32; off >= 1; off >>= 1) s += __shfl_xor(s, off, 64);
        if (lane == 0) er[(size_t)r * N + n] = s + cc[r];
    }
}

// ---------------- CSR build (dst-sorted) ----------------

__global__ void deg_kernel(const int* __restrict__ di, int* __restrict__ deg, int N, int E) {
    int r = blockIdx.y;
    int i = blockIdx.x * 256 + threadIdx.x;
    if (i >= E) return;
    atomicAdd(&deg[(size_t)r * N + di[(size_t)r * E + i]], 1);
}

__global__ __launch_bounds__(1024) void scan_kernel(const int* __restrict__ deg,
                                                    int* __restrict__ offs,
                                                    int* __restrict__ cur, int N) {
    const int r = blockIdx.x;
    const int t = threadIdx.x;
    const int lane = t & 63, wave = t >> 6;
    const int NW = 16;
    __shared__ int wsum[NW];
    __shared__ int carry_s;
    if (t == 0) carry_s = 0;
    __syncthreads();
    for (int base = 0; base < N; base += 1024) {
        int idx = base + t;
        int v = (idx < N) ? deg[(size_t)r * N + idx] : 0;
        int x = v;
#pragma unroll
        for (int off = 1; off < 64; off <<= 1) {
            int y = __shfl_up(x, off, 64);
            if (lane >= off) x += y;
        }
        if (lane == 63) wsum[wave] = x;
        __syncthreads();
        if (wave == 0 && lane < NW) {
            int y = wsum[lane];
#pragma unroll
            for (int off = 1; off < NW; off <<= 1) {
                int z = __shfl_up(y, off, 64);
                if (lane >= off) y += z;
            }
            wsum[lane] = y;
        }
        __syncthreads();
        int waveoff = (wave > 0) ? wsum[wave - 1] : 0;
        int excl = carry_s + waveoff + x - v;
        if (idx < N) {
            offs[(size_t)r * N + idx] = excl;
            cur[(size_t)r * N + idx] = excl;
        }
        __syncthreads();
        if (t == 0) carry_s += wsum[NW - 1];
        __syncthreads();
    }
}

__global__ void fill_kernel(const int* __restrict__ si, const int* __restrict__ di,
                            int* __restrict__ cur, int* __restrict__ csr, int N, int E) {
    int r = blockIdx.y;
    int i = blockIdx.x * 256 + threadIdx.x;
    if (i >= E) return;
    size_t g = (size_t)r * E + i;
    int d = di[g];
    int pos = atomicAdd(&cur[(size_t)r * N + d], 1);
    csr[(size_t)r * E + pos] = si[g];
}

// ---------------- fused per-dst softmax + aggregation + bias + ELU -> z (bf16) ----------------
// 4x16-lane groups per wave: 4 src rows in flight per load instruction.

__global__ __launch_bounds__(256) void gather_kernel(
    const int* __restrict__ csr, const int* __restrict__ offs, const int* __restrict__ deg,
    const float* __restrict__ el, const float* __restrict__ er,
    const unsigned short* __restrict__ hsb, const float* __restrict__ b_gat,
    unsigned short* __restrict__ z, int N, int E) {
    const int r = blockIdx.y;
    const int wid = threadIdx.x >> 6;
    const int l = threadIdx.x & 63;
    const int grp = l >> 4, gl = l & 15;
    const int d = blockIdx.x * 4 + wid;
    if (d >= N) return;
    const int beg = offs[(size_t)r * N + d];
    const int dg = deg[(size_t)r * N + d];
    float ac[8] = {0.f, 0.f, 0.f, 0.f, 0.f, 0.f, 0.f, 0.f};
    if (dg > 0) {
        const float erd = er[(size_t)r * N + d];
        const float* elr = el + (size_t)r * N;
        const int* csrr = csr + (size_t)r * E;
        const unsigned short* hsr = hsb + (size_t)r * N * 128;

        // pass 1: max over edges (64-lane strided)
        float m = -3.0e38f;
        for (int i = beg + l; i < beg + dg; i += 64) {
            float e = elr[csrr[i]] + erd;
            e = e > 0.f ? e : 0.2f * e;
            m = fmaxf(m, e);
        }
#pragma unroll
        for (int off = 32; off >= 1; off >>= 1) m = fmaxf(m, __shfl_xor(m, off, 64));

        // pass 2: group-parallel exp + broadcast-accumulate
        float ssum = 0.f;
        for (int c = beg; c < beg + dg; c += 64) {
            int nn = min(64, beg + dg - c);
            int pos = grp + gl * 4;  // this lane's edge slot in chunk
            int src = 0; float p = 0.f;
            if (pos < nn) {
                src = csrr[c + pos];
                float e = elr[src] + erd;
                e = e > 0.f ? e : 0.2f * e;
                p = __expf(e - m);
                ssum += p;
            }
            int ng = (nn - grp + 3) >> 2;  // edges owned by this group (group-uniform)
            for (int j = 0; j < ng; ++j) {
                float pj = __shfl(p, (l & 48) + j, 64);
                int sj = __shfl(src, (l & 48) + j, 64);
                uint4 hw = *(const uint4*)(hsr + (size_t)sj * 128 + gl * 8);
                ac[0] += pj * bf2f((unsigned short)(hw.x & 0xffffu));
                ac[1] += pj * bf2f((unsigned short)(hw.x >> 16));
                ac[2] += pj * bf2f((unsigned short)(hw.y & 0xffffu));
                ac[3] += pj * bf2f((unsigned short)(hw.y >> 16));
                ac[4] += pj * bf2f((unsigned short)(hw.z & 0xffffu));
                ac[5] += pj * bf2f((unsigned short)(hw.z >> 16));
                ac[6] += pj * bf2f((unsigned short)(hw.w & 0xffffu));
                ac[7] += pj * bf2f((unsigned short)(hw.w >> 16));
            }
        }
#pragma unroll
        for (int off = 1; off <= 32; off <<= 1) ssum += __shfl_xor(ssum, off, 64);
#pragma unroll
        for (int k = 0; k < 8; ++k) {
            ac[k] += __shfl_xor(ac[k], 16, 64);
            ac[k] += __shfl_xor(ac[k], 32, 64);
        }
        float inv = 1.f / ssum;
#pragma unroll
        for (int k = 0; k < 8; ++k) ac[k] *= inv;
    }
    if (grp == 0) {
        const float* bg = b_gat + r * 128 + gl * 8;
        uint4 ow;
        ow.x = pk2bf(eluf(ac[0] + bg[0]), eluf(ac[1] + bg[1]));
        ow.y = pk2bf(eluf(ac[2] + bg[2]), eluf(ac[3] + bg[3]));
        ow.z = pk2bf(eluf(ac[4] + bg[4]), eluf(ac[5] + bg[5]));
        ow.w = pk2bf(eluf(ac[6] + bg[6]), eluf(ac[7] + bg[7]));
        *(uint4*)(z + ((size_t)r * N + d) * 128 + gl * 8) = ow;
    }
}

// ---------------- semantic attention GEMM (MFMA) -> per-block partial sums ----------------

__global__ __launch_bounds__(256) void gemm_sem(
    const unsigned short* __restrict__ z, const unsigned short* __restrict__ W1p,
    const float* __restrict__ b1, const float* __restrict__ w2,
    float* __restrict__ wpart, int N) {
    const int r = blockIdx.y;
    const int n0 = blockIdx.x * 64;
    const int t = threadIdx.x;
    const int w = t >> 6, l = t & 63;
    __shared__ unsigned short Alds[64 * 128];
    __shared__ float sred[4];
    const unsigned short* A = z + (size_t)r * N * 128;
#pragma unroll
    for (int i = 0; i < 4; ++i) {
        int cid = t + 256 * i;
        int row = cid >> 4, kc = cid & 15;
        uint4 v = make_uint4(0, 0, 0, 0);
        if (n0 + row < N) v = *(const uint4*)(A + (size_t)(n0 + row) * 128 + kc * 8);
        int off = ((row * 256) + kc * 16) ^ ((row & 7) << 4);
        *(uint4*)((char*)Alds + off) = v;
    }
    __syncthreads();

    const bf16x8* bp = (const bf16x8*)W1p;
    f32x4 acc[8] = {};
    const int arow = w * 16 + (l & 15);
#pragma unroll
    for (int ks = 0; ks < 4; ++ks) {
        int aoff = ((arow * 256) + ks * 64 + (l >> 4) * 16) ^ ((arow & 7) << 4);
        bf16x8 av = *(const bf16x8*)((char*)Alds + aoff);
#pragma unroll
        for (int cf = 0; cf < 8; ++cf) {
            bf16x8 bv = bp[(ks * 8 + cf) * 64 + l];
            acc[cf] = __builtin_amdgcn_mfma_f32_16x16x32_bf16(av, bv, acc[cf], 0, 0, 0);
        }
    }
    float b1v[8], w2v[8];
#pragma unroll
    for (int cf = 0; cf < 8; ++cf) {
        int col = cf * 16 + (l & 15);
        b1v[cf] = b1[col];
        w2v[cf] = w2[col];
    }
    float wloc = 0.f;
#pragma unroll
    for (int i = 0; i < 4; ++i) {
        int row = n0 + w * 16 + (l >> 4) * 4 + i;
        float s = 0.f;
#pragma unroll
        for (int cf = 0; cf < 8; ++cf) s += tanhf(acc[cf][i] + b1v[cf]) * w2v[cf];
        s += __shfl_xor(s, 1, 64);
        s += __shfl_xor(s, 2, 64);
        s += __shfl_xor(s, 4, 64);
        s += __shfl_xor(s, 8, 64);
        if ((l & 15) == 0 && row < N) wloc += s;
    }
    wloc += __shfl_xor(wloc, 16, 64);
    wloc += __shfl_xor(wloc, 32, 64);
    if (l == 0) sred[w] = wloc;
    __syncthreads();
    if (t == 0)
        wpart[(size_t)r * gridDim.x + blockIdx.x] = sred[0] + sred[1] + sred[2] + sred[3];
}

// ---------------- reduce partials + 3-way softmax -> aw ----------------

__global__ void reduce_sem(const float* __restrict__ wpart, float* __restrict__ aw,
                           int nblk, int N) {
    const int t = threadIdx.x, l = t & 63, w = t >> 6;
    __shared__ float sred[R_REL][4];
    float s[R_REL] = {0.f, 0.f, 0.f};
    for (int i = t; i < nblk; i += 256) {
#pragma unroll
        for (int r = 0; r < R_REL; ++r) s[r] += wpart[(size_t)r * nblk + i];
    }
#pragma unroll
    for (int r = 0; r < R_REL; ++r) {
#pragma unroll
        for (int off = 32; off >= 1; off >>= 1) s[r] += __shfl_xor(s[r], off, 64);
        if (l == 0) sred[r][w] = s[r];
    }
    __syncthreads();
    if (t == 0) {
        float w0 = (sred[0][0] + sred[0][1] + sred[0][2] + sred[0][3]) / (float)N;
        float w1 = (sred[1][0] + sred[1][1] + sred[1][2] + sred[1][3]) / (float)N;
        float w2 = (sred[2][0] + sred[2][1] + sred[2][2] + sred[2][3]) / (float)N;
        float m = fmaxf(w0, fmaxf(w1, w2));
        float e0 = __expf(w0 - m), e1 = __expf(w1 - m), e2 = __expf(w2 - m);
        float si = e0 + e1 + e2;
        aw[0] = e0 / si; aw[1] = e1 / si; aw[2] = e2 / si;
    }
}

__global__ void combine(const unsigned short* __restrict__ z, const float* __restrict__ aw,
                        float* __restrict__ out, int N) {
    int idx = blockIdx.x * 256 + threadIdx.x;
    if (idx >= N * 32) return;
    int n = idx >> 5, c4 = idx & 31;
    float a0 = aw[0], a1 = aw[1], a2 = aw[2];
    uint2 z0 = *(const uint2*)(z + ((size_t)0 * N + n) * 128 + c4 * 4);
    uint2 z1 = *(const uint2*)(z + ((size_t)1 * N + n) * 128 + c4 * 4);
    uint2 z2 = *(const uint2*)(z + ((size_t)2 * N + n) * 128 + c4 * 4);
    float4 o;
    o.x = a0 * bf2f((unsigned short)(z0.x & 0xffffu)) + a1 * bf2f((unsigned short)(z1.x & 0xffffu)) + a2 * bf2f((unsigned short)(z2.x & 0xffffu));
    o.y = a0 * bf2f((unsigned short)(z0.x >> 16))     + a1 * bf2f((unsigned short)(z1.x >> 16))     + a2 * bf2f((unsigned short)(z2.x >> 16));
    o.z = a0 * bf2f((unsigned short)(z0.y & 0xffffu)) + a1 * bf2f((unsigned short)(z1.y & 0xffffu)) + a2 * bf2f((unsigned short)(z2.y & 0xffffu));
    o.w = a0 * bf2f((unsigned short)(z0.y >> 16))     + a1 * bf2f((unsigned short)(z1.y >> 16))     + a2 * bf2f((unsigned short)(z2.y >> 16));
    *(float4*)(out + (size_t)idx * 4) = o;
}

// ---------------- launch ----------------

extern "C" void kernel_launch(void* const* d_in, const int* in_sizes, int n_in,
                              void* d_out, int out_size, void* d_ws, size_t ws_size,
                              hipStream_t stream) {
    const float* dst_feat = (const float*)d_in[0];
    const float* src_feats = (const float*)d_in[1];
    const int*   src_idx  = (const int*)d_in[2];
    const int*   dst_idx  = (const int*)d_in[3];
    const float* WT_dst   = (const float*)d_in[4];
    const float* bT_dst   = (const float*)d_in[5];
    const float* WT_src   = (const float*)d_in[6];
    const float* bT_src   = (const float*)d_in[7];
    const float* W_gat    = (const float*)d_in[8];
    const float* attn_l   = (const float*)d_in[9];
    const float* attn_r   = (const float*)d_in[10];
    const float* b_gat    = (const float*)d_in[11];
    const float* W1_sem   = (const float*)d_in[12];
    const float* b1_sem   = (const float*)d_in[13];
    const float* w2_sem   = (const float*)d_in[14];

    const int N = in_sizes[0] / 256;
    const int E = in_sizes[2] / R_REL;
    float* out = (float*)d_out;

    const int nblk = (N + 63) / 64;

    char* ws = (char*)d_ws;
    size_t off = 0;
    auto alloc = [&](size_t bytes) { char* p = ws + off; off = align_up(off + bytes, 256); return p; };
    unsigned short* hsb   = (unsigned short*)alloc((size_t)R_REL * N * 128 * 2);
    unsigned short* zbuf  = (unsigned short*)alloc((size_t)R_REL * N * 128 * 2);
    float*    Wc    = (float*)alloc((size_t)R_REL * 256 * 128 * 4);
    unsigned short* Wcp   = (unsigned short*)alloc((size_t)R_REL * 256 * 128 * 2);
    unsigned short* W1p   = (unsigned short*)alloc((size_t)128 * 128 * 2);
    float*    bc    = (float*)alloc(R_REL * 128 * 4);
    float*    u     = (float*)alloc(R_REL * 256 * 4);
    float*    vv    = (float*)alloc(R_REL * 128 * 4);
    float*    cc    = (float*)alloc(R_REL * 4);
    float*    el    = (float*)alloc((size_t)R_REL * N * 4);
    float*    er    = (float*)alloc((size_t)R_REL * N * 4);
    int*      deg   = (int*)alloc((size_t)R_REL * N * 4);
    int*      offs  = (int*)alloc((size_t)R_REL * N * 4);
    int*      cur   = (int*)alloc((size_t)R_REL * N * 4);
    int*      csr   = (int*)alloc((size_t)R_REL * E * 4);
    float*    wpart = (float*)alloc((size_t)R_REL * nblk * 4);
    float*    aw    = (float*)alloc(R_REL * 4);

    hipMemsetAsync(deg, 0, (size_t)R_REL * N * 4, stream);

    // weight prep
    v_kernel<<<R_REL, 128, 0, stream>>>(W_gat, attn_r, vv);
    u_kernel<<<R_REL, 256, 0, stream>>>(WT_dst, bT_dst, vv, u, cc);
    wc_kernel<<<dim3(257, R_REL), 128, 0, stream>>>(WT_src, bT_src, W_gat, Wc, bc);
    pack_kernel<<<dim3(64, R_REL), 64, 0, stream>>>(Wc, Wcp, 256 * 128, 8);
    pack_kernel<<<dim3(32, 1), 64, 0, stream>>>(W1_sem, W1p, 0, 4);

    // CSR build
    deg_kernel<<<dim3((E + 255) / 256, R_REL), 256, 0, stream>>>(dst_idx, deg, N, E);
    scan_kernel<<<R_REL, 1024, 0, stream>>>(deg, offs, cur, N);
    fill_kernel<<<dim3((E + 255) / 256, R_REL), 256, 0, stream>>>(src_idx, dst_idx, cur, csr, N, E);

    // node projections
    dim3 g1(nblk, R_REL);
    gemm_hs<<<g1, 256, 0, stream>>>(src_feats, Wcp, bc, attn_l, hsb, el, N);
    er_kernel<<<(N + 3) / 4, 256, 0, stream>>>(dst_feat, u, cc, er, N);

    // fused edge softmax + aggregation -> z
    gather_kernel<<<dim3((N + 3) / 4, R_REL), 256, 0, stream>>>(csr, offs, deg, el, er, hsb, b_gat, zbuf, N, E);

    // semantic attention + combine
    gemm_sem<<<g1, 256, 0, stream>>>(zbuf, W1p, b1_sem, w2_sem, wpart, N);
    reduce_sem<<<1, 256, 0, stream>>>(wpart, aw, nblk, N);
    combine<<<(N * 32 + 255) / 256, 256, 0, stream>>>(zbuf, aw, out, N);
}

// Round 6
// 405.038 us; speedup vs baseline: 7.7682x; 1.1476x over previous
//
#include <hip/hip_runtime.h>
#include <hip/hip_bf16.h>

#define R_REL 3

typedef __attribute__((ext_vector_type(8))) short bf16x8;
typedef __attribute__((ext_vector_type(4))) float f32x4;

static inline size_t align_up(size_t x, size_t a) { return (x + a - 1) & ~(a - 1); }

__device__ __forceinline__ float eluf(float x) {
    return x > 0.f ? x : (__expf(x) - 1.f);
}
__device__ __forceinline__ unsigned short f2bf(float f) {
    __hip_bfloat16 h = __float2bfloat16(f);
    return *reinterpret_cast<unsigned short*>(&h);
}
__device__ __forceinline__ unsigned pk2bf(float lo, float hi) {
    __hip_bfloat162 h = __float22bfloat162_rn(make_float2(lo, hi));
    return *reinterpret_cast<unsigned*>(&h);
}
__device__ __forceinline__ float bf2f(unsigned short h) {
    return __uint_as_float((unsigned)h << 16);
}

// ---------------- tiny weight-prep kernels ----------------

__global__ void v_kernel(const float* __restrict__ W_gat, const float* __restrict__ attn_r,
                         float* __restrict__ v) {
    int r = blockIdx.x;
    __shared__ float ar[128];
    if (threadIdx.x < 128) ar[threadIdx.x] = attn_r[r * 128 + threadIdx.x];
    __syncthreads();
    if (threadIdx.x < 128) {
        const float* W = W_gat + (size_t)r * 128 * 128 + (size_t)threadIdx.x * 128;
        float s = 0.f;
        for (int j = 0; j < 128; ++j) s += W[j] * ar[j];
        v[r * 128 + threadIdx.x] = s;
    }
}

__global__ void u_kernel(const float* __restrict__ WT_dst, const float* __restrict__ bT_dst,
                         const float* __restrict__ v, float* __restrict__ u,
                         float* __restrict__ cc) {
    int r = blockIdx.x;
    __shared__ float vs[128];
    if (threadIdx.x < 128) vs[threadIdx.x] = v[r * 128 + threadIdx.x];
    __syncthreads();
    const float* W = WT_dst + (size_t)threadIdx.x * 128;
    float s = 0.f;
    for (int i = 0; i < 128; ++i) s += W[i] * vs[i];
    u[r * 256 + threadIdx.x] = s;
    if (threadIdx.x == 0) {
        float c = 0.f;
        for (int i = 0; i < 128; ++i) c += bT_dst[i] * vs[i];
        cc[r] = c;
    }
}

__global__ void wc_kernel(const float* __restrict__ WT_src, const float* __restrict__ bT_src,
                          const float* __restrict__ W_gat, float* __restrict__ Wc,
                          float* __restrict__ bc) {
    int r = blockIdx.y;
    int k = blockIdx.x;  // 0..256
    int j = threadIdx.x; // 0..127
    __shared__ float as[128];
    const float* arow = (k < 256) ? (WT_src + ((size_t)r * 256 + k) * 128)
                                  : (bT_src + (size_t)r * 128);
    as[j] = arow[j];
    __syncthreads();
    const float* W = W_gat + (size_t)r * 128 * 128;
    float s = 0.f;
    for (int i = 0; i < 128; ++i) s += as[i] * W[(size_t)i * 128 + j];
    if (k < 256) Wc[((size_t)r * 256 + k) * 128 + j] = s;
    else         bc[(size_t)r * 128 + j] = s;
}

// pack fp32 [relstride rows...][K][128] matrix into per-lane MFMA B-fragment order
__global__ void pack_kernel(const float* __restrict__ S, unsigned short* __restrict__ P,
                            int relstride, int KS) {
    int r = blockIdx.y;
    int ks = blockIdx.x >> 3, cb = blockIdx.x & 7;
    int l = threadIdx.x;
    const float* Sr = S + (size_t)r * relstride;
    int col = cb * 16 + (l & 15);
    int kb = ks * 32 + (l >> 4) * 8;
    unsigned short v[8];
#pragma unroll
    for (int j = 0; j < 8; ++j) v[j] = f2bf(Sr[(size_t)(kb + j) * 128 + col]);
    unsigned short* dst = P + ((((size_t)r * KS + ks) * 8 + cb) * 64 + l) * 8;
    *(uint4*)dst = *(uint4*)v;
}

// ---------------- hs GEMM (MFMA, A direct from global): hs = bf16(src@Wc + bc); el = hs.attn_l ----

__global__ __launch_bounds__(256) void gemm_hs(
    const float* __restrict__ src, const unsigned short* __restrict__ Bpack,
    const float* __restrict__ bc, const float* __restrict__ attn_l,
    unsigned short* __restrict__ hsb, float* __restrict__ el, int N) {
    const int r = blockIdx.y;
    const int t = threadIdx.x;
    const int w = t >> 6, l = t & 63;
    const int rowbase = blockIdx.x * 64 + w * 16;
    const int arow_i = rowbase + (l & 15);
    const int kg = l >> 4;
    const float* A = src + (size_t)r * N * 256;
    const float* arow = A + (size_t)(arow_i < N ? arow_i : N - 1) * 256;
    const bf16x8* bp = (const bf16x8*)(Bpack + (size_t)r * 256 * 128);
    f32x4 acc[8] = {};
#pragma unroll
    for (int ks = 0; ks < 8; ++ks) {
        float4 a0 = *(const float4*)(arow + ks * 32 + kg * 8);
        float4 a1 = *(const float4*)(arow + ks * 32 + kg * 8 + 4);
        uint4 uv;
        uv.x = pk2bf(a0.x, a0.y);
        uv.y = pk2bf(a0.z, a0.w);
        uv.z = pk2bf(a1.x, a1.y);
        uv.w = pk2bf(a1.z, a1.w);
        bf16x8 av = *(bf16x8*)&uv;
#pragma unroll
        for (int cf = 0; cf < 8; ++cf) {
            bf16x8 bv = bp[(ks * 8 + cf) * 64 + l];
            acc[cf] = __builtin_amdgcn_mfma_f32_16x16x32_bf16(av, bv, acc[cf], 0, 0, 0);
        }
    }
    float bcv[8], alv[8];
#pragma unroll
    for (int cf = 0; cf < 8; ++cf) {
        int col = cf * 16 + (l & 15);
        bcv[cf] = bc[r * 128 + col];
        alv[cf] = attn_l[r * 128 + col];
    }
#pragma unroll
    for (int i = 0; i < 4; ++i) {
        int row = rowbase + (l >> 4) * 4 + i;
        float pe = 0.f;
        unsigned short hv[8];
#pragma unroll
        for (int cf = 0; cf < 8; ++cf) {
            float v = acc[cf][i] + bcv[cf];
            pe += v * alv[cf];
            hv[cf] = f2bf(v);
        }
        if (row < N) {
            unsigned short* hp = hsb + ((size_t)r * N + row) * 128 + (l & 15);
#pragma unroll
            for (int cf = 0; cf < 8; ++cf) hp[cf * 16] = hv[cf];
        }
        pe += __shfl_xor(pe, 1, 64);
        pe += __shfl_xor(pe, 2, 64);
        pe += __shfl_xor(pe, 4, 64);
        pe += __shfl_xor(pe, 8, 64);
        if ((l & 15) == 0 && row < N) el[(size_t)r * N + row] = pe;
    }
}

// ---------------- er: er[r][n] = dst_feat[n] . u[r] + cc[r] ----------------

__global__ void er_kernel(const float* __restrict__ dst_feat, const float* __restrict__ u,
                          const float* __restrict__ cc, float* __restrict__ er, int N) {
    __shared__ float us[3][256];
    for (int i = threadIdx.x; i < 3 * 256; i += 256) us[i / 256][i & 255] = u[i];
    __syncthreads();
    int wave = threadIdx.x >> 6, lane = threadIdx.x & 63;
    int n = blockIdx.x * 4 + wave;
    if (n >= N) return;
    float4 f = *(const float4*)(dst_feat + (size_t)n * 256 + lane * 4);
#pragma unroll
    for (int r = 0; r < R_REL; ++r) {
        float4 uv = *(float4*)&us[r][lane * 4];
        float s = f.x * uv.x + f.y * uv.y + f.z * uv.z + f.w * uv.w;
#pragma unroll
        for (int off = 32; off >= 1; off >>= 1) s += __shfl_xor(s, off, 64);
        if (lane == 0) er[(size_t)r * N + n] = s + cc[r];
    }
}

// ---------------- CSR build (dst-sorted, ushort src ids) ----------------

__global__ void deg_kernel(const int* __restrict__ di, int* __restrict__ deg, int N, int E) {
    int r = blockIdx.y;
    int i = blockIdx.x * 256 + threadIdx.x;
    if (i >= E) return;
    atomicAdd(&deg[(size_t)r * N + di[(size_t)r * E + i]], 1);
}

// per-1024-chunk exclusive scan; writes in-chunk exclusive values to offs and chunk totals
__global__ __launch_bounds__(1024) void scan1_kernel(const int* __restrict__ deg,
                                                     int* __restrict__ offs,
                                                     int* __restrict__ btot, int N, int nchunk) {
    const int r = blockIdx.y;
    const int idx = blockIdx.x * 1024 + threadIdx.x;
    const int lane = threadIdx.x & 63, wave = threadIdx.x >> 6;
    __shared__ int wsum[16];
    int v = (idx < N) ? deg[(size_t)r * N + idx] : 0;
    int x = v;
#pragma unroll
    for (int off = 1; off < 64; off <<= 1) {
        int y = __shfl_up(x, off, 64);
        if (lane >= off) x += y;
    }
    if (lane == 63) wsum[wave] = x;
    __syncthreads();
    if (wave == 0 && lane < 16) {
        int y = wsum[lane];
#pragma unroll
        for (int off = 1; off < 16; off <<= 1) {
            int z = __shfl_up(y, off, 64);
            if (lane >= off) y += z;
        }
        wsum[lane] = y;
    }
    __syncthreads();
    int woff = (wave > 0) ? wsum[wave - 1] : 0;
    if (idx < N) offs[(size_t)r * N + idx] = woff + x - v;
    if (threadIdx.x == 1023) btot[r * nchunk + blockIdx.x] = woff + x;
}

// add chunk-prefix (recomputed per block from btot) to offs; write cur copy
__global__ __launch_bounds__(256) void scan2_kernel(const int* __restrict__ btot,
                                                    int* __restrict__ offs,
                                                    int* __restrict__ cur, int N, int nchunk) {
    const int r = blockIdx.y;
    const int chunk = blockIdx.x;
    const int t = threadIdx.x;
    const int lane = t & 63, wave = t >> 6;
    __shared__ int red[4];
    int pre = 0;
    for (int i = t; i < chunk; i += 256) pre += btot[r * nchunk + i];
#pragma unroll
    for (int off = 32; off >= 1; off >>= 1) pre += __shfl_xor(pre, off, 64);
    if (lane == 0) red[wave] = pre;
    __syncthreads();
    int ptot = red[0] + red[1] + red[2] + red[3];
    for (int j = t; j < 1024; j += 256) {
        int idx = chunk * 1024 + j;
        if (idx < N) {
            int e = offs[(size_t)r * N + idx] + ptot;
            offs[(size_t)r * N + idx] = e;
            cur[(size_t)r * N + idx] = e;
        }
    }
}

__global__ void fill_kernel(const int* __restrict__ si, const int* __restrict__ di,
                            int* __restrict__ cur, unsigned short* __restrict__ csr,
                            int N, int E) {
    int r = blockIdx.y;
    int i = blockIdx.x * 256 + threadIdx.x;
    if (i >= E) return;
    size_t g = (size_t)r * E + i;
    int d = di[g];
    int pos = atomicAdd(&cur[(size_t)r * N + d], 1);
    csr[(size_t)r * E + pos] = (unsigned short)si[g];  // N < 65536
}

// ---------------- fused per-dst softmax + aggregation + bias + ELU -> z (bf16) ----------------
// 4x16-lane groups per wave: 4 src rows in flight per load instruction.

__global__ __launch_bounds__(256) void gather_kernel(
    const unsigned short* __restrict__ csr, const int* __restrict__ offs,
    const int* __restrict__ deg, const float* __restrict__ el, const float* __restrict__ er,
    const unsigned short* __restrict__ hsb, const float* __restrict__ b_gat,
    unsigned short* __restrict__ z, int N, int E) {
    const int r = blockIdx.y;
    const int wid = threadIdx.x >> 6;
    const int l = threadIdx.x & 63;
    const int grp = l >> 4, gl = l & 15;
    const int d = blockIdx.x * 4 + wid;
    if (d >= N) return;
    const int beg = offs[(size_t)r * N + d];
    const int dg = deg[(size_t)r * N + d];
    float ac[8] = {0.f, 0.f, 0.f, 0.f, 0.f, 0.f, 0.f, 0.f};
    if (dg > 0) {
        const float erd = er[(size_t)r * N + d];
        const float* elr = el + (size_t)r * N;
        const unsigned short* csrr = csr + (size_t)r * E;
        const unsigned short* hsr = hsb + (size_t)r * N * 128;

        // pass 1: max over edges (64-lane strided)
        float m = -3.0e38f;
        for (int i = beg + l; i < beg + dg; i += 64) {
            float e = elr[csrr[i]] + erd;
            e = e > 0.f ? e : 0.2f * e;
            m = fmaxf(m, e);
        }
#pragma unroll
        for (int off = 32; off >= 1; off >>= 1) m = fmaxf(m, __shfl_xor(m, off, 64));

        // pass 2: group-parallel exp + broadcast-accumulate
        float ssum = 0.f;
        for (int c = beg; c < beg + dg; c += 64) {
            int nn = min(64, beg + dg - c);
            int pos = grp + gl * 4;  // this lane's edge slot in chunk
            int src = 0; float p = 0.f;
            if (pos < nn) {
                src = csrr[c + pos];
                float e = elr[src] + erd;
                e = e > 0.f ? e : 0.2f * e;
                p = __expf(e - m);
                ssum += p;
            }
            int ng = (nn - grp + 3) >> 2;  // edges owned by this group (group-uniform)
            for (int j = 0; j < ng; ++j) {
                float pj = __shfl(p, (l & 48) + j, 64);
                int sj = __shfl(src, (l & 48) + j, 64);
                uint4 hw = *(const uint4*)(hsr + (size_t)sj * 128 + gl * 8);
                ac[0] += pj * bf2f((unsigned short)(hw.x & 0xffffu));
                ac[1] += pj * bf2f((unsigned short)(hw.x >> 16));
                ac[2] += pj * bf2f((unsigned short)(hw.y & 0xffffu));
                ac[3] += pj * bf2f((unsigned short)(hw.y >> 16));
                ac[4] += pj * bf2f((unsigned short)(hw.z & 0xffffu));
                ac[5] += pj * bf2f((unsigned short)(hw.z >> 16));
                ac[6] += pj * bf2f((unsigned short)(hw.w & 0xffffu));
                ac[7] += pj * bf2f((unsigned short)(hw.w >> 16));
            }
        }
#pragma unroll
        for (int off = 1; off <= 32; off <<= 1) ssum += __shfl_xor(ssum, off, 64);
#pragma unroll
        for (int k = 0; k < 8; ++k) {
            ac[k] += __shfl_xor(ac[k], 16, 64);
            ac[k] += __shfl_xor(ac[k], 32, 64);
        }
        float inv = 1.f / ssum;
#pragma unroll
        for (int k = 0; k < 8; ++k) ac[k] *= inv;
    }
    if (grp == 0) {
        const float* bg = b_gat + r * 128 + gl * 8;
        uint4 ow;
        ow.x = pk2bf(eluf(ac[0] + bg[0]), eluf(ac[1] + bg[1]));
        ow.y = pk2bf(eluf(ac[2] + bg[2]), eluf(ac[3] + bg[3]));
        ow.z = pk2bf(eluf(ac[4] + bg[4]), eluf(ac[5] + bg[5]));
        ow.w = pk2bf(eluf(ac[6] + bg[6]), eluf(ac[7] + bg[7]));
        *(uint4*)(z + ((size_t)r * N + d) * 128 + gl * 8) = ow;
    }
}

// ---------------- semantic attention GEMM (MFMA) -> per-block partial sums ----------------

__global__ __launch_bounds__(256) void gemm_sem(
    const unsigned short* __restrict__ z, const unsigned short* __restrict__ W1p,
    const float* __restrict__ b1, const float* __restrict__ w2,
    float* __restrict__ wpart, int N) {
    const int r = blockIdx.y;
    const int n0 = blockIdx.x * 64;
    const int t = threadIdx.x;
    const int w = t >> 6, l = t & 63;
    __shared__ unsigned short Alds[64 * 128];
    __shared__ float sred[4];
    const unsigned short* A = z + (size_t)r * N * 128;
#pragma unroll
    for (int i = 0; i < 4; ++i) {
        int cid = t + 256 * i;
        int row = cid >> 4, kc = cid & 15;
        uint4 v = make_uint4(0, 0, 0, 0);
        if (n0 + row < N) v = *(const uint4*)(A + (size_t)(n0 + row) * 128 + kc * 8);
        int off = ((row * 256) + kc * 16) ^ ((row & 7) << 4);
        *(uint4*)((char*)Alds + off) = v;
    }
    __syncthreads();

    const bf16x8* bp = (const bf16x8*)W1p;
    f32x4 acc[8] = {};
    const int arow = w * 16 + (l & 15);
#pragma unroll
    for (int ks = 0; ks < 4; ++ks) {
        int aoff = ((arow * 256) + ks * 64 + (l >> 4) * 16) ^ ((arow & 7) << 4);
        bf16x8 av = *(const bf16x8*)((char*)Alds + aoff);
#pragma unroll
        for (int cf = 0; cf < 8; ++cf) {
            bf16x8 bv = bp[(ks * 8 + cf) * 64 + l];
            acc[cf] = __builtin_amdgcn_mfma_f32_16x16x32_bf16(av, bv, acc[cf], 0, 0, 0);
        }
    }
    float b1v[8], w2v[8];
#pragma unroll
    for (int cf = 0; cf < 8; ++cf) {
        int col = cf * 16 + (l & 15);
        b1v[cf] = b1[col];
        w2v[cf] = w2[col];
    }
    float wloc = 0.f;
#pragma unroll
    for (int i = 0; i < 4; ++i) {
        int row = n0 + w * 16 + (l >> 4) * 4 + i;
        float s = 0.f;
#pragma unroll
        for (int cf = 0; cf < 8; ++cf) s += tanhf(acc[cf][i] + b1v[cf]) * w2v[cf];
        s += __shfl_xor(s, 1, 64);
        s += __shfl_xor(s, 2, 64);
        s += __shfl_xor(s, 4, 64);
        s += __shfl_xor(s, 8, 64);
        if ((l & 15) == 0 && row < N) wloc += s;
    }
    wloc += __shfl_xor(wloc, 16, 64);
    wloc += __shfl_xor(wloc, 32, 64);
    if (l == 0) sred[w] = wloc;
    __syncthreads();
    if (t == 0)
        wpart[(size_t)r * gridDim.x + blockIdx.x] = sred[0] + sred[1] + sred[2] + sred[3];
}

// ---------------- reduce partials + 3-way softmax -> aw ----------------

__global__ void reduce_sem(const float* __restrict__ wpart, float* __restrict__ aw,
                           int nblk, int N) {
    const int t = threadIdx.x, l = t & 63, w = t >> 6;
    __shared__ float sred[R_REL][4];
    float s[R_REL] = {0.f, 0.f, 0.f};
    for (int i = t; i < nblk; i += 256) {
#pragma unroll
        for (int r = 0; r < R_REL; ++r) s[r] += wpart[(size_t)r * nblk + i];
    }
#pragma unroll
    for (int r = 0; r < R_REL; ++r) {
#pragma unroll
        for (int off = 32; off >= 1; off >>= 1) s[r] += __shfl_xor(s[r], off, 64);
        if (l == 0) sred[r][w] = s[r];
    }
    __syncthreads();
    if (t == 0) {
        float w0 = (sred[0][0] + sred[0][1] + sred[0][2] + sred[0][3]) / (float)N;
        float w1 = (sred[1][0] + sred[1][1] + sred[1][2] + sred[1][3]) / (float)N;
        float w2 = (sred[2][0] + sred[2][1] + sred[2][2] + sred[2][3]) / (float)N;
        float m = fmaxf(w0, fmaxf(w1, w2));
        float e0 = __expf(w0 - m), e1 = __expf(w1 - m), e2 = __expf(w2 - m);
        float si = e0 + e1 + e2;
        aw[0] = e0 / si; aw[1] = e1 / si; aw[2] = e2 / si;
    }
}

__global__ void combine(const unsigned short* __restrict__ z, const float* __restrict__ aw,
                        float* __restrict__ out, int N) {
    int idx = blockIdx.x * 256 + threadIdx.x;
    if (idx >= N * 32) return;
    int n = idx >> 5, c4 = idx & 31;
    float a0 = aw[0], a1 = aw[1], a2 = aw[2];
    uint2 z0 = *(const uint2*)(z + ((size_t)0 * N + n) * 128 + c4 * 4);
    uint2 z1 = *(const uint2*)(z + ((size_t)1 * N + n) * 128 + c4 * 4);
    uint2 z2 = *(const uint2*)(z + ((size_t)2 * N + n) * 128 + c4 * 4);
    float4 o;
    o.x = a0 * bf2f((unsigned short)(z0.x & 0xffffu)) + a1 * bf2f((unsigned short)(z1.x & 0xffffu)) + a2 * bf2f((unsigned short)(z2.x & 0xffffu));
    o.y = a0 * bf2f((unsigned short)(z0.x >> 16))     + a1 * bf2f((unsigned short)(z1.x >> 16))     + a2 * bf2f((unsigned short)(z2.x >> 16));
    o.z = a0 * bf2f((unsigned short)(z0.y & 0xffffu)) + a1 * bf2f((unsigned short)(z1.y & 0xffffu)) + a2 * bf2f((unsigned short)(z2.y & 0xffffu));
    o.w = a0 * bf2f((unsigned short)(z0.y >> 16))     + a1 * bf2f((unsigned short)(z1.y >> 16))     + a2 * bf2f((unsigned short)(z2.y >> 16));
    *(float4*)(out + (size_t)idx * 4) = o;
}

// ---------------- launch ----------------

extern "C" void kernel_launch(void* const* d_in, const int* in_sizes, int n_in,
                              void* d_out, int out_size, void* d_ws, size_t ws_size,
                              hipStream_t stream) {
    const float* dst_feat = (const float*)d_in[0];
    const float* src_feats = (const float*)d_in[1];
    const int*   src_idx  = (const int*)d_in[2];
    const int*   dst_idx  = (const int*)d_in[3];
    const float* WT_dst   = (const float*)d_in[4];
    const float* bT_dst   = (const float*)d_in[5];
    const float* WT_src   = (const float*)d_in[6];
    const float* bT_src   = (const float*)d_in[7];
    const float* W_gat    = (const float*)d_in[8];
    const float* attn_l   = (const float*)d_in[9];
    const float* attn_r   = (const float*)d_in[10];
    const float* b_gat    = (const float*)d_in[11];
    const float* W1_sem   = (const float*)d_in[12];
    const float* b1_sem   = (const float*)d_in[13];
    const float* w2_sem   = (const float*)d_in[14];

    const int N = in_sizes[0] / 256;
    const int E = in_sizes[2] / R_REL;
    float* out = (float*)d_out;

    const int nblk = (N + 63) / 64;
    const int nchunk = (N + 1023) / 1024;

    char* ws = (char*)d_ws;
    size_t off = 0;
    auto alloc = [&](size_t bytes) { char* p = ws + off; off = align_up(off + bytes, 256); return p; };
    unsigned short* hsb   = (unsigned short*)alloc((size_t)R_REL * N * 128 * 2);
    unsigned short* zbuf  = (unsigned short*)alloc((size_t)R_REL * N * 128 * 2);
    float*    Wc    = (float*)alloc((size_t)R_REL * 256 * 128 * 4);
    unsigned short* Wcp   = (unsigned short*)alloc((size_t)R_REL * 256 * 128 * 2);
    unsigned short* W1p   = (unsigned short*)alloc((size_t)128 * 128 * 2);
    float*    bc    = (float*)alloc(R_REL * 128 * 4);
    float*    u     = (float*)alloc(R_REL * 256 * 4);
    float*    vv    = (float*)alloc(R_REL * 128 * 4);
    float*    cc    = (float*)alloc(R_REL * 4);
    float*    el    = (float*)alloc((size_t)R_REL * N * 4);
    float*    er    = (float*)alloc((size_t)R_REL * N * 4);
    int*      deg   = (int*)alloc((size_t)R_REL * N * 4);
    int*      offs  = (int*)alloc((size_t)R_REL * N * 4);
    int*      cur   = (int*)alloc((size_t)R_REL * N * 4);
    int*      btot  = (int*)alloc((size_t)R_REL * nchunk * 4);
    unsigned short* csr = (unsigned short*)alloc((size_t)R_REL * E * 2);
    float*    wpart = (float*)alloc((size_t)R_REL * nblk * 4);
    float*    aw    = (float*)alloc(R_REL * 4);

    hipMemsetAsync(deg, 0, (size_t)R_REL * N * 4, stream);

    // weight prep
    v_kernel<<<R_REL, 128, 0, stream>>>(W_gat, attn_r, vv);
    u_kernel<<<R_REL, 256, 0, stream>>>(WT_dst, bT_dst, vv, u, cc);
    wc_kernel<<<dim3(257, R_REL), 128, 0, stream>>>(WT_src, bT_src, W_gat, Wc, bc);
    pack_kernel<<<dim3(64, R_REL), 64, 0, stream>>>(Wc, Wcp, 256 * 128, 8);
    pack_kernel<<<dim3(32, 1), 64, 0, stream>>>(W1_sem, W1p, 0, 4);

    // CSR build
    deg_kernel<<<dim3((E + 255) / 256, R_REL), 256, 0, stream>>>(dst_idx, deg, N, E);
    scan1_kernel<<<dim3(nchunk, R_REL), 1024, 0, stream>>>(deg, offs, btot, N, nchunk);
    scan2_kernel<<<dim3(nchunk, R_REL), 256, 0, stream>>>(btot, offs, cur, N, nchunk);
    fill_kernel<<<dim3((E + 255) / 256, R_REL), 256, 0, stream>>>(src_idx, dst_idx, cur, csr, N, E);

    // node projections
    dim3 g1(nblk, R_REL);
    gemm_hs<<<g1, 256, 0, stream>>>(src_feats, Wcp, bc, attn_l, hsb, el, N);
    er_kernel<<<(N + 3) / 4, 256, 0, stream>>>(dst_feat, u, cc, er, N);

    // fused edge softmax + aggregation -> z
    gather_kernel<<<dim3((N + 3) / 4, R_REL), 256, 0, stream>>>(csr, offs, deg, el, er, hsb, b_gat, zbuf, N, E);

    // semantic attention + combine
    gemm_sem<<<g1, 256, 0, stream>>>(zbuf, W1p, b1_sem, w2_sem, wpart, N);
    reduce_sem<<<1, 256, 0, stream>>>(wpart, aw, nblk, N);
    combine<<<(N * 32 + 255) / 256, 256, 0, stream>>>(zbuf, aw, out, N);
}

// Round 7
// 391.233 us; speedup vs baseline: 8.0423x; 1.0353x over previous
//
#include <hip/hip_runtime.h>
#include <hip/hip_bf16.h>

#define R_REL 3

typedef __attribute__((ext_vector_type(8))) short bf16x8;
typedef __attribute__((ext_vector_type(4))) float f32x4;

static inline size_t align_up(size_t x, size_t a) { return (x + a - 1) & ~(a - 1); }

__device__ __forceinline__ float eluf(float x) {
    return x > 0.f ? x : (__expf(x) - 1.f);
}
__device__ __forceinline__ unsigned short f2bf(float f) {
    __hip_bfloat16 h = __float2bfloat16(f);
    return *reinterpret_cast<unsigned short*>(&h);
}
__device__ __forceinline__ unsigned pk2bf(float lo, float hi) {
    __hip_bfloat162 h = __float22bfloat162_rn(make_float2(lo, hi));
    return *reinterpret_cast<unsigned*>(&h);
}
__device__ __forceinline__ float bf2f(unsigned short h) {
    return __uint_as_float((unsigned)h << 16);
}

// ---------------- fused v+u weight prep ----------------
// v[i] = sum_j W_gat[r][i][j]*attn_r[r][j];  u[r][k] = sum_i WT_dst[k][i]*v[i];
// cc[r] = sum_i bT_dst[i]*v[i]
__global__ void vu_kernel(const float* __restrict__ W_gat, const float* __restrict__ attn_r,
                          const float* __restrict__ WT_dst, const float* __restrict__ bT_dst,
                          float* __restrict__ u, float* __restrict__ cc) {
    int r = blockIdx.x;
    int t = threadIdx.x;
    __shared__ float ar[128];
    __shared__ float vs[128];
    if (t < 128) ar[t] = attn_r[r * 128 + t];
    __syncthreads();
    if (t < 128) {
        const float* W = W_gat + (size_t)r * 128 * 128 + (size_t)t * 128;
        float s = 0.f;
        for (int j = 0; j < 128; ++j) s += W[j] * ar[j];
        vs[t] = s;
    }
    __syncthreads();
    const float* W = WT_dst + (size_t)t * 128;
    float s = 0.f;
    for (int i = 0; i < 128; ++i) s += W[i] * vs[i];
    u[r * 256 + t] = s;
    if (t == 0) {
        float c = 0.f;
        for (int i = 0; i < 128; ++i) c += bT_dst[i] * vs[i];
        cc[r] = c;
    }
}

__global__ void wc_kernel(const float* __restrict__ WT_src, const float* __restrict__ bT_src,
                          const float* __restrict__ W_gat, float* __restrict__ Wc,
                          float* __restrict__ bc) {
    int r = blockIdx.y;
    int k = blockIdx.x;  // 0..256
    int j = threadIdx.x; // 0..127
    __shared__ float as[128];
    const float* arow = (k < 256) ? (WT_src + ((size_t)r * 256 + k) * 128)
                                  : (bT_src + (size_t)r * 128);
    as[j] = arow[j];
    __syncthreads();
    const float* W = W_gat + (size_t)r * 128 * 128;
    float s = 0.f;
    for (int i = 0; i < 128; ++i) s += as[i] * W[(size_t)i * 128 + j];
    if (k < 256) Wc[((size_t)r * 256 + k) * 128 + j] = s;
    else         bc[(size_t)r * 128 + j] = s;
}

// pack fp32 [relstride rows...][K][128] matrix into per-lane MFMA B-fragment order
__global__ void pack_kernel(const float* __restrict__ S, unsigned short* __restrict__ P,
                            int relstride, int KS) {
    int r = blockIdx.y;
    int ks = blockIdx.x >> 3, cb = blockIdx.x & 7;
    int l = threadIdx.x;
    const float* Sr = S + (size_t)r * relstride;
    int col = cb * 16 + (l & 15);
    int kb = ks * 32 + (l >> 4) * 8;
    unsigned short v[8];
#pragma unroll
    for (int j = 0; j < 8; ++j) v[j] = f2bf(Sr[(size_t)(kb + j) * 128 + col]);
    unsigned short* dst = P + ((((size_t)r * KS + ks) * 8 + cb) * 64 + l) * 8;
    *(uint4*)dst = *(uint4*)v;
}

// ---------------- hs GEMM (MFMA, A direct from global): hs = bf16(src@Wc + bc); el = hs.attn_l ----

__global__ __launch_bounds__(256) void gemm_hs(
    const float* __restrict__ src, const unsigned short* __restrict__ Bpack,
    const float* __restrict__ bc, const float* __restrict__ attn_l,
    unsigned short* __restrict__ hsb, float* __restrict__ el, int N) {
    const int r = blockIdx.y;
    const int t = threadIdx.x;
    const int w = t >> 6, l = t & 63;
    const int rowbase = blockIdx.x * 64 + w * 16;
    const int arow_i = rowbase + (l & 15);
    const int kg = l >> 4;
    const float* A = src + (size_t)r * N * 256;
    const float* arow = A + (size_t)(arow_i < N ? arow_i : N - 1) * 256;
    const bf16x8* bp = (const bf16x8*)(Bpack + (size_t)r * 256 * 128);
    f32x4 acc[8] = {};
#pragma unroll
    for (int ks = 0; ks < 8; ++ks) {
        float4 a0 = *(const float4*)(arow + ks * 32 + kg * 8);
        float4 a1 = *(const float4*)(arow + ks * 32 + kg * 8 + 4);
        uint4 uv;
        uv.x = pk2bf(a0.x, a0.y);
        uv.y = pk2bf(a0.z, a0.w);
        uv.z = pk2bf(a1.x, a1.y);
        uv.w = pk2bf(a1.z, a1.w);
        bf16x8 av = *(bf16x8*)&uv;
#pragma unroll
        for (int cf = 0; cf < 8; ++cf) {
            bf16x8 bv = bp[(ks * 8 + cf) * 64 + l];
            acc[cf] = __builtin_amdgcn_mfma_f32_16x16x32_bf16(av, bv, acc[cf], 0, 0, 0);
        }
    }
    float bcv[8], alv[8];
#pragma unroll
    for (int cf = 0; cf < 8; ++cf) {
        int col = cf * 16 + (l & 15);
        bcv[cf] = bc[r * 128 + col];
        alv[cf] = attn_l[r * 128 + col];
    }
#pragma unroll
    for (int i = 0; i < 4; ++i) {
        int row = rowbase + (l >> 4) * 4 + i;
        float pe = 0.f;
        unsigned short hv[8];
#pragma unroll
        for (int cf = 0; cf < 8; ++cf) {
            float v = acc[cf][i] + bcv[cf];
            pe += v * alv[cf];
            hv[cf] = f2bf(v);
        }
        if (row < N) {
            unsigned short* hp = hsb + ((size_t)r * N + row) * 128 + (l & 15);
#pragma unroll
            for (int cf = 0; cf < 8; ++cf) hp[cf * 16] = hv[cf];
        }
        pe += __shfl_xor(pe, 1, 64);
        pe += __shfl_xor(pe, 2, 64);
        pe += __shfl_xor(pe, 4, 64);
        pe += __shfl_xor(pe, 8, 64);
        if ((l & 15) == 0 && row < N) el[(size_t)r * N + row] = pe;
    }
}

// ---------------- er: er[r][n] = dst_feat[n] . u[r] + cc[r] ----------------

__global__ void er_kernel(const float* __restrict__ dst_feat, const float* __restrict__ u,
                          const float* __restrict__ cc, float* __restrict__ er, int N) {
    __shared__ float us[3][256];
    for (int i = threadIdx.x; i < 3 * 256; i += 256) us[i / 256][i & 255] = u[i];
    __syncthreads();
    int wave = threadIdx.x >> 6, lane = threadIdx.x & 63;
    int n = blockIdx.x * 4 + wave;
    if (n >= N) return;
    float4 f = *(const float4*)(dst_feat + (size_t)n * 256 + lane * 4);
#pragma unroll
    for (int r = 0; r < R_REL; ++r) {
        float4 uv = *(float4*)&us[r][lane * 4];
        float s = f.x * uv.x + f.y * uv.y + f.z * uv.z + f.w * uv.w;
#pragma unroll
        for (int off = 32; off >= 1; off >>= 1) s += __shfl_xor(s, off, 64);
        if (lane == 0) er[(size_t)r * N + n] = s + cc[r];
    }
}

// ---------------- CSR build (dst-sorted, ushort src ids) ----------------

__global__ void deg_kernel(const int* __restrict__ di, int* __restrict__ deg, int N, int E) {
    int r = blockIdx.y;
    int i = blockIdx.x * 256 + threadIdx.x;
    if (i >= E) return;
    atomicAdd(&deg[(size_t)r * N + di[(size_t)r * E + i]], 1);
}

// per-1024-chunk exclusive scan; writes in-chunk exclusive values to offs and chunk totals
__global__ __launch_bounds__(1024) void scan1_kernel(const int* __restrict__ deg,
                                                     int* __restrict__ offs,
                                                     int* __restrict__ btot, int N, int nchunk) {
    const int r = blockIdx.y;
    const int idx = blockIdx.x * 1024 + threadIdx.x;
    const int lane = threadIdx.x & 63, wave = threadIdx.x >> 6;
    __shared__ int wsum[16];
    int v = (idx < N) ? deg[(size_t)r * N + idx] : 0;
    int x = v;
#pragma unroll
    for (int off = 1; off < 64; off <<= 1) {
        int y = __shfl_up(x, off, 64);
        if (lane >= off) x += y;
    }
    if (lane == 63) wsum[wave] = x;
    __syncthreads();
    if (wave == 0 && lane < 16) {
        int y = wsum[lane];
#pragma unroll
        for (int off = 1; off < 16; off <<= 1) {
            int z = __shfl_up(y, off, 64);
            if (lane >= off) y += z;
        }
        wsum[lane] = y;
    }
    __syncthreads();
    int woff = (wave > 0) ? wsum[wave - 1] : 0;
    if (idx < N) offs[(size_t)r * N + idx] = woff + x - v;
    if (threadIdx.x == 1023) btot[r * nchunk + blockIdx.x] = woff + x;
}

// add chunk-prefix (recomputed per block from btot) to offs; write cur copy
__global__ __launch_bounds__(256) void scan2_kernel(const int* __restrict__ btot,
                                                    int* __restrict__ offs,
                                                    int* __restrict__ cur, int N, int nchunk) {
    const int r = blockIdx.y;
    const int chunk = blockIdx.x;
    const int t = threadIdx.x;
    const int lane = t & 63, wave = t >> 6;
    __shared__ int red[4];
    int pre = 0;
    for (int i = t; i < chunk; i += 256) pre += btot[r * nchunk + i];
#pragma unroll
    for (int off = 32; off >= 1; off >>= 1) pre += __shfl_xor(pre, off, 64);
    if (lane == 0) red[wave] = pre;
    __syncthreads();
    int ptot = red[0] + red[1] + red[2] + red[3];
    for (int j = t; j < 1024; j += 256) {
        int idx = chunk * 1024 + j;
        if (idx < N) {
            int e = offs[(size_t)r * N + idx] + ptot;
            offs[(size_t)r * N + idx] = e;
            cur[(size_t)r * N + idx] = e;
        }
    }
}

__global__ void fill_kernel(const int* __restrict__ si, const int* __restrict__ di,
                            int* __restrict__ cur, unsigned short* __restrict__ csr,
                            int N, int E) {
    int r = blockIdx.y;
    int i = blockIdx.x * 256 + threadIdx.x;
    if (i >= E) return;
    size_t g = (size_t)r * E + i;
    int d = di[g];
    int pos = atomicAdd(&cur[(size_t)r * N + d], 1);
    csr[(size_t)r * E + pos] = (unsigned short)si[g];  // N < 65536
}

// ---------------- fused per-dst softmax + aggregation + bias + ELU -> z (bf16) ----------------
// Single-pass softmax (no max subtraction: e is bounded, exp(e) safe in fp32;
// alpha = exp(e)/sum exp(e) is shift-invariant so result identical).
// 4x16-lane groups per wave: 4 src rows in flight per load instruction.

__global__ __launch_bounds__(256) void gather_kernel(
    const unsigned short* __restrict__ csr, const int* __restrict__ offs,
    const int* __restrict__ deg, const float* __restrict__ el, const float* __restrict__ er,
    const unsigned short* __restrict__ hsb, const float* __restrict__ b_gat,
    unsigned short* __restrict__ z, int N, int E) {
    const int r = blockIdx.y;
    const int wid = threadIdx.x >> 6;
    const int l = threadIdx.x & 63;
    const int grp = l >> 4, gl = l & 15;
    const int d = blockIdx.x * 4 + wid;
    if (d >= N) return;
    const int beg = offs[(size_t)r * N + d];
    const int dg = deg[(size_t)r * N + d];
    float ac[8] = {0.f, 0.f, 0.f, 0.f, 0.f, 0.f, 0.f, 0.f};
    if (dg > 0) {
        const float erd = er[(size_t)r * N + d];
        const float* elr = el + (size_t)r * N;
        const unsigned short* csrr = csr + (size_t)r * E;
        const unsigned short* hsr = hsb + (size_t)r * N * 128;

        float ssum = 0.f;
        for (int c = beg; c < beg + dg; c += 64) {
            int nn = min(64, beg + dg - c);
            int pos = grp + gl * 4;  // this lane's edge slot in chunk
            int src = 0; float p = 0.f;
            if (pos < nn) {
                src = csrr[c + pos];
                float e = elr[src] + erd;
                e = e > 0.f ? e : 0.2f * e;
                p = __expf(e);
                ssum += p;
            }
            int ng = (nn - grp + 3) >> 2;  // edges owned by this group (group-uniform)
            for (int j = 0; j < ng; ++j) {
                float pj = __shfl(p, (l & 48) + j, 64);
                int sj = __shfl(src, (l & 48) + j, 64);
                uint4 hw = *(const uint4*)(hsr + (size_t)sj * 128 + gl * 8);
                ac[0] += pj * bf2f((unsigned short)(hw.x & 0xffffu));
                ac[1] += pj * bf2f((unsigned short)(hw.x >> 16));
                ac[2] += pj * bf2f((unsigned short)(hw.y & 0xffffu));
                ac[3] += pj * bf2f((unsigned short)(hw.y >> 16));
                ac[4] += pj * bf2f((unsigned short)(hw.z & 0xffffu));
                ac[5] += pj * bf2f((unsigned short)(hw.z >> 16));
                ac[6] += pj * bf2f((unsigned short)(hw.w & 0xffffu));
                ac[7] += pj * bf2f((unsigned short)(hw.w >> 16));
            }
        }
#pragma unroll
        for (int off = 1; off <= 32; off <<= 1) ssum += __shfl_xor(ssum, off, 64);
#pragma unroll
        for (int k = 0; k < 8; ++k) {
            ac[k] += __shfl_xor(ac[k], 16, 64);
            ac[k] += __shfl_xor(ac[k], 32, 64);
        }
        float inv = 1.f / ssum;
#pragma unroll
        for (int k = 0; k < 8; ++k) ac[k] *= inv;
    }
    if (grp == 0) {
        const float* bg = b_gat + r * 128 + gl * 8;
        uint4 ow;
        ow.x = pk2bf(eluf(ac[0] + bg[0]), eluf(ac[1] + bg[1]));
        ow.y = pk2bf(eluf(ac[2] + bg[2]), eluf(ac[3] + bg[3]));
        ow.z = pk2bf(eluf(ac[4] + bg[4]), eluf(ac[5] + bg[5]));
        ow.w = pk2bf(eluf(ac[6] + bg[6]), eluf(ac[7] + bg[7]));
        *(uint4*)(z + ((size_t)r * N + d) * 128 + gl * 8) = ow;
    }
}

// ---------------- semantic attention GEMM (MFMA) -> per-block partial sums ----------------

__global__ __launch_bounds__(256) void gemm_sem(
    const unsigned short* __restrict__ z, const unsigned short* __restrict__ W1p,
    const float* __restrict__ b1, const float* __restrict__ w2,
    float* __restrict__ wpart, int N) {
    const int r = blockIdx.y;
    const int n0 = blockIdx.x * 64;
    const int t = threadIdx.x;
    const int w = t >> 6, l = t & 63;
    __shared__ unsigned short Alds[64 * 128];
    __shared__ float sred[4];
    const unsigned short* A = z + (size_t)r * N * 128;
#pragma unroll
    for (int i = 0; i < 4; ++i) {
        int cid = t + 256 * i;
        int row = cid >> 4, kc = cid & 15;
        uint4 v = make_uint4(0, 0, 0, 0);
        if (n0 + row < N) v = *(const uint4*)(A + (size_t)(n0 + row) * 128 + kc * 8);
        int off = ((row * 256) + kc * 16) ^ ((row & 7) << 4);
        *(uint4*)((char*)Alds + off) = v;
    }
    __syncthreads();

    const bf16x8* bp = (const bf16x8*)W1p;
    f32x4 acc[8] = {};
    const int arow = w * 16 + (l & 15);
#pragma unroll
    for (int ks = 0; ks < 4; ++ks) {
        int aoff = ((arow * 256) + ks * 64 + (l >> 4) * 16) ^ ((arow & 7) << 4);
        bf16x8 av = *(const bf16x8*)((char*)Alds + aoff);
#pragma unroll
        for (int cf = 0; cf < 8; ++cf) {
            bf16x8 bv = bp[(ks * 8 + cf) * 64 + l];
            acc[cf] = __builtin_amdgcn_mfma_f32_16x16x32_bf16(av, bv, acc[cf], 0, 0, 0);
        }
    }
    float b1v[8], w2v[8];
#pragma unroll
    for (int cf = 0; cf < 8; ++cf) {
        int col = cf * 16 + (l & 15);
        b1v[cf] = b1[col];
        w2v[cf] = w2[col];
    }
    float wloc = 0.f;
#pragma unroll
    for (int i = 0; i < 4; ++i) {
        int row = n0 + w * 16 + (l >> 4) * 4 + i;
        float s = 0.f;
#pragma unroll
        for (int cf = 0; cf < 8; ++cf) s += tanhf(acc[cf][i] + b1v[cf]) * w2v[cf];
        s += __shfl_xor(s, 1, 64);
        s += __shfl_xor(s, 2, 64);
        s += __shfl_xor(s, 4, 64);
        s += __shfl_xor(s, 8, 64);
        if ((l & 15) == 0 && row < N) wloc += s;
    }
    wloc += __shfl_xor(wloc, 16, 64);
    wloc += __shfl_xor(wloc, 32, 64);
    if (l == 0) sred[w] = wloc;
    __syncthreads();
    if (t == 0)
        wpart[(size_t)r * gridDim.x + blockIdx.x] = sred[0] + sred[1] + sred[2] + sred[3];
}

// ---------------- reduce partials + 3-way softmax -> aw ----------------

__global__ void reduce_sem(const float* __restrict__ wpart, float* __restrict__ aw,
                           int nblk, int N) {
    const int t = threadIdx.x, l = t & 63, w = t >> 6;
    __shared__ float sred[R_REL][4];
    float s[R_REL] = {0.f, 0.f, 0.f};
    for (int i = t; i < nblk; i += 256) {
#pragma unroll
        for (int r = 0; r < R_REL; ++r) s[r] += wpart[(size_t)r * nblk + i];
    }
#pragma unroll
    for (int r = 0; r < R_REL; ++r) {
#pragma unroll
        for (int off = 32; off >= 1; off >>= 1) s[r] += __shfl_xor(s[r], off, 64);
        if (l == 0) sred[r][w] = s[r];
    }
    __syncthreads();
    if (t == 0) {
        float w0 = (sred[0][0] + sred[0][1] + sred[0][2] + sred[0][3]) / (float)N;
        float w1 = (sred[1][0] + sred[1][1] + sred[1][2] + sred[1][3]) / (float)N;
        float w2 = (sred[2][0] + sred[2][1] + sred[2][2] + sred[2][3]) / (float)N;
        float m = fmaxf(w0, fmaxf(w1, w2));
        float e0 = __expf(w0 - m), e1 = __expf(w1 - m), e2 = __expf(w2 - m);
        float si = e0 + e1 + e2;
        aw[0] = e0 / si; aw[1] = e1 / si; aw[2] = e2 / si;
    }
}

__global__ void combine(const unsigned short* __restrict__ z, const float* __restrict__ aw,
                        float* __restrict__ out, int N) {
    int idx = blockIdx.x * 256 + threadIdx.x;
    if (idx >= N * 32) return;
    int n = idx >> 5, c4 = idx & 31;
    float a0 = aw[0], a1 = aw[1], a2 = aw[2];
    uint2 z0 = *(const uint2*)(z + ((size_t)0 * N + n) * 128 + c4 * 4);
    uint2 z1 = *(const uint2*)(z + ((size_t)1 * N + n) * 128 + c4 * 4);
    uint2 z2 = *(const uint2*)(z + ((size_t)2 * N + n) * 128 + c4 * 4);
    float4 o;
    o.x = a0 * bf2f((unsigned short)(z0.x & 0xffffu)) + a1 * bf2f((unsigned short)(z1.x & 0xffffu)) + a2 * bf2f((unsigned short)(z2.x & 0xffffu));
    o.y = a0 * bf2f((unsigned short)(z0.x >> 16))     + a1 * bf2f((unsigned short)(z1.x >> 16))     + a2 * bf2f((unsigned short)(z2.x >> 16));
    o.z = a0 * bf2f((unsigned short)(z0.y & 0xffffu)) + a1 * bf2f((unsigned short)(z1.y & 0xffffu)) + a2 * bf2f((unsigned short)(z2.y & 0xffffu));
    o.w = a0 * bf2f((unsigned short)(z0.y >> 16))     + a1 * bf2f((unsigned short)(z1.y >> 16))     + a2 * bf2f((unsigned short)(z2.y >> 16));
    *(float4*)(out + (size_t)idx * 4) = o;
}

// ---------------- launch ----------------

extern "C" void kernel_launch(void* const* d_in, const int* in_sizes, int n_in,
                              void* d_out, int out_size, void* d_ws, size_t ws_size,
                              hipStream_t stream) {
    const float* dst_feat = (const float*)d_in[0];
    const float* src_feats = (const float*)d_in[1];
    const int*   src_idx  = (const int*)d_in[2];
    const int*   dst_idx  = (const int*)d_in[3];
    const float* WT_dst   = (const float*)d_in[4];
    const float* bT_dst   = (const float*)d_in[5];
    const float* WT_src   = (const float*)d_in[6];
    const float* bT_src   = (const float*)d_in[7];
    const float* W_gat    = (const float*)d_in[8];
    const float* attn_l   = (const float*)d_in[9];
    const float* attn_r   = (const float*)d_in[10];
    const float* b_gat    = (const float*)d_in[11];
    const float* W1_sem   = (const float*)d_in[12];
    const float* b1_sem   = (const float*)d_in[13];
    const float* w2_sem   = (const float*)d_in[14];

    const int N = in_sizes[0] / 256;
    const int E = in_sizes[2] / R_REL;
    float* out = (float*)d_out;

    const int nblk = (N + 63) / 64;
    const int nchunk = (N + 1023) / 1024;

    char* ws = (char*)d_ws;
    size_t off = 0;
    auto alloc = [&](size_t bytes) { char* p = ws + off; off = align_up(off + bytes, 256); return p; };
    unsigned short* hsb   = (unsigned short*)alloc((size_t)R_REL * N * 128 * 2);
    unsigned short* zbuf  = (unsigned short*)alloc((size_t)R_REL * N * 128 * 2);
    float*    Wc    = (float*)alloc((size_t)R_REL * 256 * 128 * 4);
    unsigned short* Wcp   = (unsigned short*)alloc((size_t)R_REL * 256 * 128 * 2);
    unsigned short* W1p   = (unsigned short*)alloc((size_t)128 * 128 * 2);
    float*    bc    = (float*)alloc(R_REL * 128 * 4);
    float*    u     = (float*)alloc(R_REL * 256 * 4);
    float*    cc    = (float*)alloc(R_REL * 4);
    float*    el    = (float*)alloc((size_t)R_REL * N * 4);
    float*    er    = (float*)alloc((size_t)R_REL * N * 4);
    int*      deg   = (int*)alloc((size_t)R_REL * N * 4);
    int*      offs  = (int*)alloc((size_t)R_REL * N * 4);
    int*      cur   = (int*)alloc((size_t)R_REL * N * 4);
    int*      btot  = (int*)alloc((size_t)R_REL * nchunk * 4);
    unsigned short* csr = (unsigned short*)alloc((size_t)R_REL * E * 2);
    float*    wpart = (float*)alloc((size_t)R_REL * nblk * 4);
    float*    aw    = (float*)alloc(R_REL * 4);

    hipMemsetAsync(deg, 0, (size_t)R_REL * N * 4, stream);

    // weight prep
    vu_kernel<<<R_REL, 256, 0, stream>>>(W_gat, attn_r, WT_dst, bT_dst, u, cc);
    wc_kernel<<<dim3(257, R_REL), 128, 0, stream>>>(WT_src, bT_src, W_gat, Wc, bc);
    pack_kernel<<<dim3(64, R_REL), 64, 0, stream>>>(Wc, Wcp, 256 * 128, 8);
    pack_kernel<<<dim3(32, 1), 64, 0, stream>>>(W1_sem, W1p, 0, 4);

    // CSR build
    deg_kernel<<<dim3((E + 255) / 256, R_REL), 256, 0, stream>>>(dst_idx, deg, N, E);
    scan1_kernel<<<dim3(nchunk, R_REL), 1024, 0, stream>>>(deg, offs, btot, N, nchunk);
    scan2_kernel<<<dim3(nchunk, R_REL), 256, 0, stream>>>(btot, offs, cur, N, nchunk);
    fill_kernel<<<dim3((E + 255) / 256, R_REL), 256, 0, stream>>>(src_idx, dst_idx, cur, csr, N, E);

    // node projections
    dim3 g1(nblk, R_REL);
    gemm_hs<<<g1, 256, 0, stream>>>(src_feats, Wcp, bc, attn_l, hsb, el, N);
    er_kernel<<<(N + 3) / 4, 256, 0, stream>>>(dst_feat, u, cc, er, N);

    // fused single-pass edge softmax + aggregation -> z
    gather_kernel<<<dim3((N + 3) / 4, R_REL), 256, 0, stream>>>(csr, offs, deg, el, er, hsb, b_gat, zbuf, N, E);

    // semantic attention + combine
    gemm_sem<<<g1, 256, 0, stream>>>(zbuf, W1p, b1_sem, w2_sem, wpart, N);
    reduce_sem<<<1, 256, 0, stream>>>(wpart, aw, nblk, N);
    combine<<<(N * 32 + 255) / 256, 256, 0, stream>>>(zbuf, aw, out, N);
}

// Round 8
// 284.103 us; speedup vs baseline: 11.0749x; 1.3771x over previous
//
#include <hip/hip_runtime.h>
#include <hip/hip_bf16.h>

#define R_REL 3
#define NODE_CHUNK 512
#define BCAP 6144

typedef __attribute__((ext_vector_type(8))) short bf16x8;
typedef __attribute__((ext_vector_type(4))) float f32x4;

static inline size_t align_up(size_t x, size_t a) { return (x + a - 1) & ~(a - 1); }

__device__ __forceinline__ float eluf(float x) {
    return x > 0.f ? x : (__expf(x) - 1.f);
}
__device__ __forceinline__ unsigned short f2bf(float f) {
    __hip_bfloat16 h = __float2bfloat16(f);
    return *reinterpret_cast<unsigned short*>(&h);
}
__device__ __forceinline__ unsigned pk2bf(float lo, float hi) {
    __hip_bfloat162 h = __float22bfloat162_rn(make_float2(lo, hi));
    return *reinterpret_cast<unsigned*>(&h);
}
__device__ __forceinline__ float bf2f(unsigned short h) {
    return __uint_as_float((unsigned)h << 16);
}

// ---------------- fused v+u weight prep ----------------

__global__ void vu_kernel(const float* __restrict__ W_gat, const float* __restrict__ attn_r,
                          const float* __restrict__ WT_dst, const float* __restrict__ bT_dst,
                          float* __restrict__ u, float* __restrict__ cc) {
    int r = blockIdx.x;
    int t = threadIdx.x;
    __shared__ float ar[128];
    __shared__ float vs[128];
    if (t < 128) ar[t] = attn_r[r * 128 + t];
    __syncthreads();
    if (t < 128) {
        const float* W = W_gat + (size_t)r * 128 * 128 + (size_t)t * 128;
        float s = 0.f;
        for (int j = 0; j < 128; ++j) s += W[j] * ar[j];
        vs[t] = s;
    }
    __syncthreads();
    const float* W = WT_dst + (size_t)t * 128;
    float s = 0.f;
    for (int i = 0; i < 128; ++i) s += W[i] * vs[i];
    u[r * 256 + t] = s;
    if (t == 0) {
        float c = 0.f;
        for (int i = 0; i < 128; ++i) c += bT_dst[i] * vs[i];
        cc[r] = c;
    }
}

__global__ void wc_kernel(const float* __restrict__ WT_src, const float* __restrict__ bT_src,
                          const float* __restrict__ W_gat, float* __restrict__ Wc,
                          float* __restrict__ bc) {
    int r = blockIdx.y;
    int k = blockIdx.x;  // 0..256
    int j = threadIdx.x; // 0..127
    __shared__ float as[128];
    const float* arow = (k < 256) ? (WT_src + ((size_t)r * 256 + k) * 128)
                                  : (bT_src + (size_t)r * 128);
    as[j] = arow[j];
    __syncthreads();
    const float* W = W_gat + (size_t)r * 128 * 128;
    float s = 0.f;
    for (int i = 0; i < 128; ++i) s += as[i] * W[(size_t)i * 128 + j];
    if (k < 256) Wc[((size_t)r * 256 + k) * 128 + j] = s;
    else         bc[(size_t)r * 128 + j] = s;
}

// pack fp32 [relstride rows...][K][128] matrix into per-lane MFMA B-fragment order
__global__ void pack_kernel(const float* __restrict__ S, unsigned short* __restrict__ P,
                            int relstride, int KS) {
    int r = blockIdx.y;
    int ks = blockIdx.x >> 3, cb = blockIdx.x & 7;
    int l = threadIdx.x;
    const float* Sr = S + (size_t)r * relstride;
    int col = cb * 16 + (l & 15);
    int kb = ks * 32 + (l >> 4) * 8;
    unsigned short v[8];
#pragma unroll
    for (int j = 0; j < 8; ++j) v[j] = f2bf(Sr[(size_t)(kb + j) * 128 + col]);
    unsigned short* dst = P + ((((size_t)r * KS + ks) * 8 + cb) * 64 + l) * 8;
    *(uint4*)dst = *(uint4*)v;
}

// ---------------- hs GEMM (MFMA, A direct from global): hs = bf16(src@Wc + bc); el = hs.attn_l ----

__global__ __launch_bounds__(256) void gemm_hs(
    const float* __restrict__ src, const unsigned short* __restrict__ Bpack,
    const float* __restrict__ bc, const float* __restrict__ attn_l,
    unsigned short* __restrict__ hsb, float* __restrict__ el, int N) {
    const int r = blockIdx.y;
    const int t = threadIdx.x;
    const int w = t >> 6, l = t & 63;
    const int rowbase = blockIdx.x * 64 + w * 16;
    const int arow_i = rowbase + (l & 15);
    const int kg = l >> 4;
    const float* A = src + (size_t)r * N * 256;
    const float* arow = A + (size_t)(arow_i < N ? arow_i : N - 1) * 256;
    const bf16x8* bp = (const bf16x8*)(Bpack + (size_t)r * 256 * 128);
    f32x4 acc[8] = {};
#pragma unroll
    for (int ks = 0; ks < 8; ++ks) {
        float4 a0 = *(const float4*)(arow + ks * 32 + kg * 8);
        float4 a1 = *(const float4*)(arow + ks * 32 + kg * 8 + 4);
        uint4 uv;
        uv.x = pk2bf(a0.x, a0.y);
        uv.y = pk2bf(a0.z, a0.w);
        uv.z = pk2bf(a1.x, a1.y);
        uv.w = pk2bf(a1.z, a1.w);
        bf16x8 av = *(bf16x8*)&uv;
#pragma unroll
        for (int cf = 0; cf < 8; ++cf) {
            bf16x8 bv = bp[(ks * 8 + cf) * 64 + l];
            acc[cf] = __builtin_amdgcn_mfma_f32_16x16x32_bf16(av, bv, acc[cf], 0, 0, 0);
        }
    }
    float bcv[8], alv[8];
#pragma unroll
    for (int cf = 0; cf < 8; ++cf) {
        int col = cf * 16 + (l & 15);
        bcv[cf] = bc[r * 128 + col];
        alv[cf] = attn_l[r * 128 + col];
    }
#pragma unroll
    for (int i = 0; i < 4; ++i) {
        int row = rowbase + (l >> 4) * 4 + i;
        float pe = 0.f;
        unsigned short hv[8];
#pragma unroll
        for (int cf = 0; cf < 8; ++cf) {
            float v = acc[cf][i] + bcv[cf];
            pe += v * alv[cf];
            hv[cf] = f2bf(v);
        }
        if (row < N) {
            unsigned short* hp = hsb + ((size_t)r * N + row) * 128 + (l & 15);
#pragma unroll
            for (int cf = 0; cf < 8; ++cf) hp[cf * 16] = hv[cf];
        }
        pe += __shfl_xor(pe, 1, 64);
        pe += __shfl_xor(pe, 2, 64);
        pe += __shfl_xor(pe, 4, 64);
        pe += __shfl_xor(pe, 8, 64);
        if ((l & 15) == 0 && row < N) el[(size_t)r * N + row] = pe;
    }
}

// ---------------- er: er[r][n] = dst_feat[n] . u[r] + cc[r] ----------------

__global__ void er_kernel(const float* __restrict__ dst_feat, const float* __restrict__ u,
                          const float* __restrict__ cc, float* __restrict__ er, int N) {
    __shared__ float us[3][256];
    for (int i = threadIdx.x; i < 3 * 256; i += 256) us[i / 256][i & 255] = u[i];
    __syncthreads();
    int wave = threadIdx.x >> 6, lane = threadIdx.x & 63;
    int n = blockIdx.x * 4 + wave;
    if (n >= N) return;
    float4 f = *(const float4*)(dst_feat + (size_t)n * 256 + lane * 4);
#pragma unroll
    for (int r = 0; r < R_REL; ++r) {
        float4 uv = *(float4*)&us[r][lane * 4];
        float s = f.x * uv.x + f.y * uv.y + f.z * uv.z + f.w * uv.w;
#pragma unroll
        for (int off = 32; off >= 1; off >>= 1) s += __shfl_xor(s, off, 64);
        if (lane == 0) er[(size_t)r * N + n] = s + cc[r];
    }
}

// ---------------- CSR build via 2-level bucket sort ----------------
// pass 1: multi-split edges into per-(rel,bucket) regions (bucket = dst >> 9)

__global__ __launch_bounds__(256) void bucket_kernel(
    const int* __restrict__ si, const int* __restrict__ di,
    int* __restrict__ gcnt, unsigned* __restrict__ bbuf, int NB, int E) {
    const int r = blockIdx.y;
    const int t = threadIdx.x;
    const int e0 = blockIdx.x * 1024;
    __shared__ int cnt[128];
    __shared__ int base[128];
    if (t < 128) cnt[t] = 0;
    __syncthreads();
    int bk[4], rank[4]; unsigned pack[4]; bool val[4];
#pragma unroll
    for (int j = 0; j < 4; ++j) {
        int e = e0 + j * 256 + t;
        val[j] = e < E;
        bk[j] = 0; rank[j] = 0; pack[j] = 0;
        if (val[j]) {
            size_t g = (size_t)r * E + e;
            int s = si[g], d = di[g];
            bk[j] = d >> 9;
            pack[j] = (unsigned)s | ((unsigned)d << 16);
            rank[j] = atomicAdd(&cnt[bk[j]], 1);
        }
    }
    __syncthreads();
    if (t < NB && cnt[t] > 0) base[t] = atomicAdd(&gcnt[r * NB + t], cnt[t]);
    __syncthreads();
#pragma unroll
    for (int j = 0; j < 4; ++j) {
        if (val[j])
            bbuf[((size_t)r * NB + bk[j]) * BCAP + base[bk[j]] + rank[j]] = pack[j];
    }
}

// pass 2a: per-bucket LDS histogram -> coalesced deg write
__global__ __launch_bounds__(256) void hist_kernel(
    const unsigned* __restrict__ bbuf, const int* __restrict__ gcnt,
    int* __restrict__ deg, int NB, int N) {
    const int r = blockIdx.y;
    const int b = blockIdx.x;
    const int t = threadIdx.x;
    __shared__ int hist[NODE_CHUNK];
    for (int i = t; i < NODE_CHUNK; i += 256) hist[i] = 0;
    __syncthreads();
    const int cnt = gcnt[r * NB + b];
    const unsigned* bb = bbuf + ((size_t)r * NB + b) * BCAP;
    for (int i = t; i < cnt; i += 256) {
        int dloc = (bb[i] >> 16) & (NODE_CHUNK - 1);
        atomicAdd(&hist[dloc], 1);
    }
    __syncthreads();
    for (int i = t; i < NODE_CHUNK; i += 256) {
        int idx = b * NODE_CHUNK + i;
        if (idx < N) deg[(size_t)r * N + idx] = hist[i];
    }
}

// per-1024-chunk exclusive scan; writes in-chunk exclusive values to offs and chunk totals
__global__ __launch_bounds__(1024) void scan1_kernel(const int* __restrict__ deg,
                                                     int* __restrict__ offs,
                                                     int* __restrict__ btot, int N, int nchunk) {
    const int r = blockIdx.y;
    const int idx = blockIdx.x * 1024 + threadIdx.x;
    const int lane = threadIdx.x & 63, wave = threadIdx.x >> 6;
    __shared__ int wsum[16];
    int v = (idx < N) ? deg[(size_t)r * N + idx] : 0;
    int x = v;
#pragma unroll
    for (int off = 1; off < 64; off <<= 1) {
        int y = __shfl_up(x, off, 64);
        if (lane >= off) x += y;
    }
    if (lane == 63) wsum[wave] = x;
    __syncthreads();
    if (wave == 0 && lane < 16) {
        int y = wsum[lane];
#pragma unroll
        for (int off = 1; off < 16; off <<= 1) {
            int z = __shfl_up(y, off, 64);
            if (lane >= off) y += z;
        }
        wsum[lane] = y;
    }
    __syncthreads();
    int woff = (wave > 0) ? wsum[wave - 1] : 0;
    if (idx < N) offs[(size_t)r * N + idx] = woff + x - v;
    if (threadIdx.x == 1023) btot[r * nchunk + blockIdx.x] = woff + x;
}

// add chunk-prefix to offs
__global__ __launch_bounds__(256) void scan2_kernel(const int* __restrict__ btot,
                                                    int* __restrict__ offs, int N, int nchunk) {
    const int r = blockIdx.y;
    const int chunk = blockIdx.x;
    const int t = threadIdx.x;
    const int lane = t & 63, wave = t >> 6;
    __shared__ int red[4];
    int pre = 0;
    for (int i = t; i < chunk; i += 256) pre += btot[r * nchunk + i];
#pragma unroll
    for (int off = 32; off >= 1; off >>= 1) pre += __shfl_xor(pre, off, 64);
    if (lane == 0) red[wave] = pre;
    __syncthreads();
    int ptot = red[0] + red[1] + red[2] + red[3];
    for (int j = t; j < 1024; j += 256) {
        int idx = chunk * 1024 + j;
        if (idx < N) offs[(size_t)r * N + idx] += ptot;
    }
}

// pass 2b: per-bucket fill with LDS cursors; csr stores land in bucket-local window
__global__ __launch_bounds__(256) void fill2_kernel(
    const unsigned* __restrict__ bbuf, const int* __restrict__ gcnt,
    const int* __restrict__ offs, unsigned short* __restrict__ csr, int NB, int N, int E) {
    const int r = blockIdx.y;
    const int b = blockIdx.x;
    const int t = threadIdx.x;
    __shared__ int curl[NODE_CHUNK];
    for (int i = t; i < NODE_CHUNK; i += 256) {
        int idx = b * NODE_CHUNK + i;
        curl[i] = (idx < N) ? offs[(size_t)r * N + idx] : 0;
    }
    __syncthreads();
    const int cnt = gcnt[r * NB + b];
    const unsigned* bb = bbuf + ((size_t)r * NB + b) * BCAP;
    unsigned short* csrr = csr + (size_t)r * E;
    for (int i = t; i < cnt; i += 256) {
        unsigned pk = bb[i];
        int dloc = (pk >> 16) & (NODE_CHUNK - 1);
        int pos = atomicAdd(&curl[dloc], 1);
        csrr[pos] = (unsigned short)(pk & 0xffffu);
    }
}

// ---------------- fused per-dst softmax + aggregation + bias + ELU -> z (bf16) ----------------

__global__ __launch_bounds__(256) void gather_kernel(
    const unsigned short* __restrict__ csr, const int* __restrict__ offs,
    const int* __restrict__ deg, const float* __restrict__ el, const float* __restrict__ er,
    const unsigned short* __restrict__ hsb, const float* __restrict__ b_gat,
    unsigned short* __restrict__ z, int N, int E) {
    const int r = blockIdx.y;
    const int wid = threadIdx.x >> 6;
    const int l = threadIdx.x & 63;
    const int grp = l >> 4, gl = l & 15;
    const int d = blockIdx.x * 4 + wid;
    if (d >= N) return;
    const int beg = offs[(size_t)r * N + d];
    const int dg = deg[(size_t)r * N + d];
    float ac[8] = {0.f, 0.f, 0.f, 0.f, 0.f, 0.f, 0.f, 0.f};
    if (dg > 0) {
        const float erd = er[(size_t)r * N + d];
        const float* elr = el + (size_t)r * N;
        const unsigned short* csrr = csr + (size_t)r * E;
        const unsigned short* hsr = hsb + (size_t)r * N * 128;

        float ssum = 0.f;
        for (int c = beg; c < beg + dg; c += 64) {
            int nn = min(64, beg + dg - c);
            int pos = grp + gl * 4;
            int src = 0; float p = 0.f;
            if (pos < nn) {
                src = csrr[c + pos];
                float e = elr[src] + erd;
                e = e > 0.f ? e : 0.2f * e;
                p = __expf(e);
                ssum += p;
            }
            int ng = (nn - grp + 3) >> 2;
            for (int j = 0; j < ng; ++j) {
                float pj = __shfl(p, (l & 48) + j, 64);
                int sj = __shfl(src, (l & 48) + j, 64);
                uint4 hw = *(const uint4*)(hsr + (size_t)sj * 128 + gl * 8);
                ac[0] += pj * bf2f((unsigned short)(hw.x & 0xffffu));
                ac[1] += pj * bf2f((unsigned short)(hw.x >> 16));
                ac[2] += pj * bf2f((unsigned short)(hw.y & 0xffffu));
                ac[3] += pj * bf2f((unsigned short)(hw.y >> 16));
                ac[4] += pj * bf2f((unsigned short)(hw.z & 0xffffu));
                ac[5] += pj * bf2f((unsigned short)(hw.z >> 16));
                ac[6] += pj * bf2f((unsigned short)(hw.w & 0xffffu));
                ac[7] += pj * bf2f((unsigned short)(hw.w >> 16));
            }
        }
#pragma unroll
        for (int off = 1; off <= 32; off <<= 1) ssum += __shfl_xor(ssum, off, 64);
#pragma unroll
        for (int k = 0; k < 8; ++k) {
            ac[k] += __shfl_xor(ac[k], 16, 64);
            ac[k] += __shfl_xor(ac[k], 32, 64);
        }
        float inv = 1.f / ssum;
#pragma unroll
        for (int k = 0; k < 8; ++k) ac[k] *= inv;
    }
    if (grp == 0) {
        const float* bg = b_gat + r * 128 + gl * 8;
        uint4 ow;
        ow.x = pk2bf(eluf(ac[0] + bg[0]), eluf(ac[1] + bg[1]));
        ow.y = pk2bf(eluf(ac[2] + bg[2]), eluf(ac[3] + bg[3]));
        ow.z = pk2bf(eluf(ac[4] + bg[4]), eluf(ac[5] + bg[5]));
        ow.w = pk2bf(eluf(ac[6] + bg[6]), eluf(ac[7] + bg[7]));
        *(uint4*)(z + ((size_t)r * N + d) * 128 + gl * 8) = ow;
    }
}

// ---------------- semantic attention GEMM (MFMA) -> per-block partial sums ----------------

__global__ __launch_bounds__(256) void gemm_sem(
    const unsigned short* __restrict__ z, const unsigned short* __restrict__ W1p,
    const float* __restrict__ b1, const float* __restrict__ w2,
    float* __restrict__ wpart, int N) {
    const int r = blockIdx.y;
    const int n0 = blockIdx.x * 64;
    const int t = threadIdx.x;
    const int w = t >> 6, l = t & 63;
    __shared__ unsigned short Alds[64 * 128];
    __shared__ float sred[4];
    const unsigned short* A = z + (size_t)r * N * 128;
#pragma unroll
    for (int i = 0; i < 4; ++i) {
        int cid = t + 256 * i;
        int row = cid >> 4, kc = cid & 15;
        uint4 v = make_uint4(0, 0, 0, 0);
        if (n0 + row < N) v = *(const uint4*)(A + (size_t)(n0 + row) * 128 + kc * 8);
        int off = ((row * 256) + kc * 16) ^ ((row & 7) << 4);
        *(uint4*)((char*)Alds + off) = v;
    }
    __syncthreads();

    const bf16x8* bp = (const bf16x8*)W1p;
    f32x4 acc[8] = {};
    const int arow = w * 16 + (l & 15);
#pragma unroll
    for (int ks = 0; ks < 4; ++ks) {
        int aoff = ((arow * 256) + ks * 64 + (l >> 4) * 16) ^ ((arow & 7) << 4);
        bf16x8 av = *(const bf16x8*)((char*)Alds + aoff);
#pragma unroll
        for (int cf = 0; cf < 8; ++cf) {
            bf16x8 bv = bp[(ks * 8 + cf) * 64 + l];
            acc[cf] = __builtin_amdgcn_mfma_f32_16x16x32_bf16(av, bv, acc[cf], 0, 0, 0);
        }
    }
    float b1v[8], w2v[8];
#pragma unroll
    for (int cf = 0; cf < 8; ++cf) {
        int col = cf * 16 + (l & 15);
        b1v[cf] = b1[col];
        w2v[cf] = w2[col];
    }
    float wloc = 0.f;
#pragma unroll
    for (int i = 0; i < 4; ++i) {
        int row = n0 + w * 16 + (l >> 4) * 4 + i;
        float s = 0.f;
#pragma unroll
        for (int cf = 0; cf < 8; ++cf) s += tanhf(acc[cf][i] + b1v[cf]) * w2v[cf];
        s += __shfl_xor(s, 1, 64);
        s += __shfl_xor(s, 2, 64);
        s += __shfl_xor(s, 4, 64);
        s += __shfl_xor(s, 8, 64);
        if ((l & 15) == 0 && row < N) wloc += s;
    }
    wloc += __shfl_xor(wloc, 16, 64);
    wloc += __shfl_xor(wloc, 32, 64);
    if (l == 0) sred[w] = wloc;
    __syncthreads();
    if (t == 0)
        wpart[(size_t)r * gridDim.x + blockIdx.x] = sred[0] + sred[1] + sred[2] + sred[3];
}

// ---------------- reduce partials + 3-way softmax -> aw ----------------

__global__ void reduce_sem(const float* __restrict__ wpart, float* __restrict__ aw,
                           int nblk, int N) {
    const int t = threadIdx.x, l = t & 63, w = t >> 6;
    __shared__ float sred[R_REL][4];
    float s[R_REL] = {0.f, 0.f, 0.f};
    for (int i = t; i < nblk; i += 256) {
#pragma unroll
        for (int r = 0; r < R_REL; ++r) s[r] += wpart[(size_t)r * nblk + i];
    }
#pragma unroll
    for (int r = 0; r < R_REL; ++r) {
#pragma unroll
        for (int off = 32; off >= 1; off >>= 1) s[r] += __shfl_xor(s[r], off, 64);
        if (l == 0) sred[r][w] = s[r];
    }
    __syncthreads();
    if (t == 0) {
        float w0 = (sred[0][0] + sred[0][1] + sred[0][2] + sred[0][3]) / (float)N;
        float w1 = (sred[1][0] + sred[1][1] + sred[1][2] + sred[1][3]) / (float)N;
        float w2 = (sred[2][0] + sred[2][1] + sred[2][2] + sred[2][3]) / (float)N;
        float m = fmaxf(w0, fmaxf(w1, w2));
        float e0 = __expf(w0 - m), e1 = __expf(w1 - m), e2 = __expf(w2 - m);
        float si = e0 + e1 + e2;
        aw[0] = e0 / si; aw[1] = e1 / si; aw[2] = e2 / si;
    }
}

__global__ void combine(const unsigned short* __restrict__ z, const float* __restrict__ aw,
                        float* __restrict__ out, int N) {
    int idx = blockIdx.x * 256 + threadIdx.x;
    if (idx >= N * 32) return;
    int n = idx >> 5, c4 = idx & 31;
    float a0 = aw[0], a1 = aw[1], a2 = aw[2];
    uint2 z0 = *(const uint2*)(z + ((size_t)0 * N + n) * 128 + c4 * 4);
    uint2 z1 = *(const uint2*)(z + ((size_t)1 * N + n) * 128 + c4 * 4);
    uint2 z2 = *(const uint2*)(z + ((size_t)2 * N + n) * 128 + c4 * 4);
    float4 o;
    o.x = a0 * bf2f((unsigned short)(z0.x & 0xffffu)) + a1 * bf2f((unsigned short)(z1.x & 0xffffu)) + a2 * bf2f((unsigned short)(z2.x & 0xffffu));
    o.y = a0 * bf2f((unsigned short)(z0.x >> 16))     + a1 * bf2f((unsigned short)(z1.x >> 16))     + a2 * bf2f((unsigned short)(z2.x >> 16));
    o.z = a0 * bf2f((unsigned short)(z0.y & 0xffffu)) + a1 * bf2f((unsigned short)(z1.y & 0xffffu)) + a2 * bf2f((unsigned short)(z2.y & 0xffffu));
    o.w = a0 * bf2f((unsigned short)(z0.y >> 16))     + a1 * bf2f((unsigned short)(z1.y >> 16))     + a2 * bf2f((unsigned short)(z2.y >> 16));
    *(float4*)(out + (size_t)idx * 4) = o;
}

// ---------------- launch ----------------

extern "C" void kernel_launch(void* const* d_in, const int* in_sizes, int n_in,
                              void* d_out, int out_size, void* d_ws, size_t ws_size,
                              hipStream_t stream) {
    const float* dst_feat = (const float*)d_in[0];
    const float* src_feats = (const float*)d_in[1];
    const int*   src_idx  = (const int*)d_in[2];
    const int*   dst_idx  = (const int*)d_in[3];
    const float* WT_dst   = (const float*)d_in[4];
    const float* bT_dst   = (const float*)d_in[5];
    const float* WT_src   = (const float*)d_in[6];
    const float* bT_src   = (const float*)d_in[7];
    const float* W_gat    = (const float*)d_in[8];
    const float* attn_l   = (const float*)d_in[9];
    const float* attn_r   = (const float*)d_in[10];
    const float* b_gat    = (const float*)d_in[11];
    const float* W1_sem   = (const float*)d_in[12];
    const float* b1_sem   = (const float*)d_in[13];
    const float* w2_sem   = (const float*)d_in[14];

    const int N = in_sizes[0] / 256;
    const int E = in_sizes[2] / R_REL;
    float* out = (float*)d_out;

    const int nblk = (N + 63) / 64;
    const int nchunk = (N + 1023) / 1024;
    const int NB = (N + NODE_CHUNK - 1) / NODE_CHUNK;

    char* ws = (char*)d_ws;
    size_t off = 0;
    auto alloc = [&](size_t bytes) { char* p = ws + off; off = align_up(off + bytes, 256); return p; };
    unsigned short* hsb   = (unsigned short*)alloc((size_t)R_REL * N * 128 * 2);
    unsigned short* zbuf  = (unsigned short*)alloc((size_t)R_REL * N * 128 * 2);
    float*    Wc    = (float*)alloc((size_t)R_REL * 256 * 128 * 4);
    unsigned short* Wcp   = (unsigned short*)alloc((size_t)R_REL * 256 * 128 * 2);
    unsigned short* W1p   = (unsigned short*)alloc((size_t)128 * 128 * 2);
    float*    bc    = (float*)alloc(R_REL * 128 * 4);
    float*    u     = (float*)alloc(R_REL * 256 * 4);
    float*    cc    = (float*)alloc(R_REL * 4);
    float*    el    = (float*)alloc((size_t)R_REL * N * 4);
    float*    er    = (float*)alloc((size_t)R_REL * N * 4);
    int*      deg   = (int*)alloc((size_t)R_REL * N * 4);
    int*      offs  = (int*)alloc((size_t)R_REL * N * 4);
    int*      btot  = (int*)alloc((size_t)R_REL * nchunk * 4);
    int*      gcnt  = (int*)alloc((size_t)R_REL * NB * 4);
    unsigned* bbuf  = (unsigned*)alloc((size_t)R_REL * NB * BCAP * 4);
    unsigned short* csr = (unsigned short*)alloc((size_t)R_REL * E * 2);
    float*    wpart = (float*)alloc((size_t)R_REL * nblk * 4);
    float*    aw    = (float*)alloc(R_REL * 4);

    hipMemsetAsync(gcnt, 0, (size_t)R_REL * NB * 4, stream);

    // weight prep
    vu_kernel<<<R_REL, 256, 0, stream>>>(W_gat, attn_r, WT_dst, bT_dst, u, cc);
    wc_kernel<<<dim3(257, R_REL), 128, 0, stream>>>(WT_src, bT_src, W_gat, Wc, bc);
    pack_kernel<<<dim3(64, R_REL), 64, 0, stream>>>(Wc, Wcp, 256 * 128, 8);
    pack_kernel<<<dim3(32, 1), 64, 0, stream>>>(W1_sem, W1p, 0, 4);

    // CSR build (2-level bucket sort)
    bucket_kernel<<<dim3((E + 1023) / 1024, R_REL), 256, 0, stream>>>(src_idx, dst_idx, gcnt, bbuf, NB, E);
    hist_kernel<<<dim3(NB, R_REL), 256, 0, stream>>>(bbuf, gcnt, deg, NB, N);
    scan1_kernel<<<dim3(nchunk, R_REL), 1024, 0, stream>>>(deg, offs, btot, N, nchunk);
    scan2_kernel<<<dim3(nchunk, R_REL), 256, 0, stream>>>(btot, offs, N, nchunk);
    fill2_kernel<<<dim3(NB, R_REL), 256, 0, stream>>>(bbuf, gcnt, offs, csr, NB, N, E);

    // node projections
    dim3 g1(nblk, R_REL);
    gemm_hs<<<g1, 256, 0, stream>>>(src_feats, Wcp, bc, attn_l, hsb, el, N);
    er_kernel<<<(N + 3) / 4, 256, 0, stream>>>(dst_feat, u, cc, er, N);

    // fused single-pass edge softmax + aggregation -> z
    gather_kernel<<<dim3((N + 3) / 4, R_REL), 256, 0, stream>>>(csr, offs, deg, el, er, hsb, b_gat, zbuf, N, E);

    // semantic attention + combine
    gemm_sem<<<g1, 256, 0, stream>>>(zbuf, W1p, b1_sem, w2_sem, wpart, N);
    reduce_sem<<<1, 256, 0, stream>>>(wpart, aw, nblk, N);
    combine<<<(N * 32 + 255) / 256, 256, 0, stream>>>(zbuf, aw, out, N);
}

// Round 9
// 266.169 us; speedup vs baseline: 11.8211x; 1.0674x over previous
//
#include <hip/hip_runtime.h>
#include <hip/hip_bf16.h>

#define R_REL 3
#define NODE_CHUNK 512
#define BCAP 6144

typedef __attribute__((ext_vector_type(8))) short bf16x8;
typedef __attribute__((ext_vector_type(4))) float f32x4;

static inline size_t align_up(size_t x, size_t a) { return (x + a - 1) & ~(a - 1); }

__device__ __forceinline__ float eluf(float x) {
    return x > 0.f ? x : (__expf(x) - 1.f);
}
__device__ __forceinline__ unsigned short f2bf(float f) {
    __hip_bfloat16 h = __float2bfloat16(f);
    return *reinterpret_cast<unsigned short*>(&h);
}
__device__ __forceinline__ unsigned pk2bf(float lo, float hi) {
    __hip_bfloat162 h = __float22bfloat162_rn(make_float2(lo, hi));
    return *reinterpret_cast<unsigned*>(&h);
}
__device__ __forceinline__ float bf2f(unsigned short h) {
    return __uint_as_float((unsigned)h << 16);
}

// ---------------- fused v+u weight prep ----------------

__global__ void vu_kernel(const float* __restrict__ W_gat, const float* __restrict__ attn_r,
                          const float* __restrict__ WT_dst, const float* __restrict__ bT_dst,
                          float* __restrict__ u, float* __restrict__ cc) {
    int r = blockIdx.x;
    int t = threadIdx.x;
    __shared__ float ar[128];
    __shared__ float vs[128];
    if (t < 128) ar[t] = attn_r[r * 128 + t];
    __syncthreads();
    if (t < 128) {
        const float* W = W_gat + (size_t)r * 128 * 128 + (size_t)t * 128;
        float s = 0.f;
        for (int j = 0; j < 128; ++j) s += W[j] * ar[j];
        vs[t] = s;
    }
    __syncthreads();
    const float* W = WT_dst + (size_t)t * 128;
    float s = 0.f;
    for (int i = 0; i < 128; ++i) s += W[i] * vs[i];
    u[r * 256 + t] = s;
    if (t == 0) {
        float c = 0.f;
        for (int i = 0; i < 128; ++i) c += bT_dst[i] * vs[i];
        cc[r] = c;
    }
}

__global__ void wc_kernel(const float* __restrict__ WT_src, const float* __restrict__ bT_src,
                          const float* __restrict__ W_gat, float* __restrict__ Wc,
                          float* __restrict__ bc) {
    int r = blockIdx.y;
    int k = blockIdx.x;  // 0..256
    int j = threadIdx.x; // 0..127
    __shared__ float as[128];
    const float* arow = (k < 256) ? (WT_src + ((size_t)r * 256 + k) * 128)
                                  : (bT_src + (size_t)r * 128);
    as[j] = arow[j];
    __syncthreads();
    const float* W = W_gat + (size_t)r * 128 * 128;
    float s = 0.f;
    for (int i = 0; i < 128; ++i) s += as[i] * W[(size_t)i * 128 + j];
    if (k < 256) Wc[((size_t)r * 256 + k) * 128 + j] = s;
    else         bc[(size_t)r * 128 + j] = s;
}

// pack fp32 [relstride rows...][K][128] matrix into per-lane MFMA B-fragment order
__global__ void pack_kernel(const float* __restrict__ S, unsigned short* __restrict__ P,
                            int relstride, int KS) {
    int r = blockIdx.y;
    int ks = blockIdx.x >> 3, cb = blockIdx.x & 7;
    int l = threadIdx.x;
    const float* Sr = S + (size_t)r * relstride;
    int col = cb * 16 + (l & 15);
    int kb = ks * 32 + (l >> 4) * 8;
    unsigned short v[8];
#pragma unroll
    for (int j = 0; j < 8; ++j) v[j] = f2bf(Sr[(size_t)(kb + j) * 128 + col]);
    unsigned short* dst = P + ((((size_t)r * KS + ks) * 8 + cb) * 64 + l) * 8;
    *(uint4*)dst = *(uint4*)v;
}

// ---------------- hs GEMM (MFMA): A row hoisted to regs, then pure B-load+MFMA loop ----

__global__ __launch_bounds__(256) void gemm_hs(
    const float* __restrict__ src, const unsigned short* __restrict__ Bpack,
    const float* __restrict__ bc, const float* __restrict__ attn_l,
    unsigned short* __restrict__ hsb, float* __restrict__ el, int N) {
    const int r = blockIdx.y;
    const int t = threadIdx.x;
    const int w = t >> 6, l = t & 63;
    const int rowbase = blockIdx.x * 64 + w * 16;
    const int arow_i = rowbase + (l & 15);
    const int kg = l >> 4;
    const float* A = src + (size_t)r * N * 256;
    const float* arow = A + (size_t)(arow_i < N ? arow_i : N - 1) * 256;

    // hoist: load this lane's entire A row slice (64 fp32) with all 16 loads in flight
    float4 araw[16];
#pragma unroll
    for (int ks = 0; ks < 8; ++ks) {
        araw[2 * ks]     = *(const float4*)(arow + ks * 32 + kg * 8);
        araw[2 * ks + 1] = *(const float4*)(arow + ks * 32 + kg * 8 + 4);
    }
    uint4 abf[8];
#pragma unroll
    for (int ks = 0; ks < 8; ++ks) {
        abf[ks].x = pk2bf(araw[2 * ks].x, araw[2 * ks].y);
        abf[ks].y = pk2bf(araw[2 * ks].z, araw[2 * ks].w);
        abf[ks].z = pk2bf(araw[2 * ks + 1].x, araw[2 * ks + 1].y);
        abf[ks].w = pk2bf(araw[2 * ks + 1].z, araw[2 * ks + 1].w);
    }

    const bf16x8* bp = (const bf16x8*)(Bpack + (size_t)r * 256 * 128);
    f32x4 acc[8] = {};
#pragma unroll
    for (int ks = 0; ks < 8; ++ks) {
        bf16x8 av = *(bf16x8*)&abf[ks];
#pragma unroll
        for (int cf = 0; cf < 8; ++cf) {
            bf16x8 bv = bp[(ks * 8 + cf) * 64 + l];
            acc[cf] = __builtin_amdgcn_mfma_f32_16x16x32_bf16(av, bv, acc[cf], 0, 0, 0);
        }
    }
    float bcv[8], alv[8];
#pragma unroll
    for (int cf = 0; cf < 8; ++cf) {
        int col = cf * 16 + (l & 15);
        bcv[cf] = bc[r * 128 + col];
        alv[cf] = attn_l[r * 128 + col];
    }
#pragma unroll
    for (int i = 0; i < 4; ++i) {
        int row = rowbase + (l >> 4) * 4 + i;
        float pe = 0.f;
        unsigned short hv[8];
#pragma unroll
        for (int cf = 0; cf < 8; ++cf) {
            float v = acc[cf][i] + bcv[cf];
            pe += v * alv[cf];
            hv[cf] = f2bf(v);
        }
        if (row < N) {
            unsigned short* hp = hsb + ((size_t)r * N + row) * 128 + (l & 15);
#pragma unroll
            for (int cf = 0; cf < 8; ++cf) hp[cf * 16] = hv[cf];
        }
        pe += __shfl_xor(pe, 1, 64);
        pe += __shfl_xor(pe, 2, 64);
        pe += __shfl_xor(pe, 4, 64);
        pe += __shfl_xor(pe, 8, 64);
        if ((l & 15) == 0 && row < N) el[(size_t)r * N + row] = pe;
    }
}

// ---------------- er: er[r][n] = dst_feat[n] . u[r] + cc[r] ----------------

__global__ void er_kernel(const float* __restrict__ dst_feat, const float* __restrict__ u,
                          const float* __restrict__ cc, float* __restrict__ er, int N) {
    __shared__ float us[3][256];
    for (int i = threadIdx.x; i < 3 * 256; i += 256) us[i / 256][i & 255] = u[i];
    __syncthreads();
    int wave = threadIdx.x >> 6, lane = threadIdx.x & 63;
    int n = blockIdx.x * 4 + wave;
    if (n >= N) return;
    float4 f = *(const float4*)(dst_feat + (size_t)n * 256 + lane * 4);
#pragma unroll
    for (int r = 0; r < R_REL; ++r) {
        float4 uv = *(float4*)&us[r][lane * 4];
        float s = f.x * uv.x + f.y * uv.y + f.z * uv.z + f.w * uv.w;
#pragma unroll
        for (int off = 32; off >= 1; off >>= 1) s += __shfl_xor(s, off, 64);
        if (lane == 0) er[(size_t)r * N + n] = s + cc[r];
    }
}

// ---------------- CSR build via 2-level bucket sort ----------------

__global__ __launch_bounds__(256) void bucket_kernel(
    const int* __restrict__ si, const int* __restrict__ di,
    int* __restrict__ gcnt, unsigned* __restrict__ bbuf, int NB, int E) {
    const int r = blockIdx.y;
    const int t = threadIdx.x;
    const int e0 = blockIdx.x * 1024;
    __shared__ int cnt[128];
    __shared__ int base[128];
    if (t < 128) cnt[t] = 0;
    __syncthreads();
    int bk[4], rank[4]; unsigned pack[4]; bool val[4];
#pragma unroll
    for (int j = 0; j < 4; ++j) {
        int e = e0 + j * 256 + t;
        val[j] = e < E;
        bk[j] = 0; rank[j] = 0; pack[j] = 0;
        if (val[j]) {
            size_t g = (size_t)r * E + e;
            int s = si[g], d = di[g];
            bk[j] = d >> 9;
            pack[j] = (unsigned)s | ((unsigned)d << 16);
            rank[j] = atomicAdd(&cnt[bk[j]], 1);
        }
    }
    __syncthreads();
    if (t < NB && cnt[t] > 0) base[t] = atomicAdd(&gcnt[r * NB + t], cnt[t]);
    __syncthreads();
#pragma unroll
    for (int j = 0; j < 4; ++j) {
        if (val[j])
            bbuf[((size_t)r * NB + bk[j]) * BCAP + base[bk[j]] + rank[j]] = pack[j];
    }
}

__global__ __launch_bounds__(256) void hist_kernel(
    const unsigned* __restrict__ bbuf, const int* __restrict__ gcnt,
    int* __restrict__ deg, int NB, int N) {
    const int r = blockIdx.y;
    const int b = blockIdx.x;
    const int t = threadIdx.x;
    __shared__ int hist[NODE_CHUNK];
    for (int i = t; i < NODE_CHUNK; i += 256) hist[i] = 0;
    __syncthreads();
    const int cnt = gcnt[r * NB + b];
    const unsigned* bb = bbuf + ((size_t)r * NB + b) * BCAP;
    for (int i = t; i < cnt; i += 256) {
        int dloc = (bb[i] >> 16) & (NODE_CHUNK - 1);
        atomicAdd(&hist[dloc], 1);
    }
    __syncthreads();
    for (int i = t; i < NODE_CHUNK; i += 256) {
        int idx = b * NODE_CHUNK + i;
        if (idx < N) deg[(size_t)r * N + idx] = hist[i];
    }
}

__global__ __launch_bounds__(1024) void scan1_kernel(const int* __restrict__ deg,
                                                     int* __restrict__ offs,
                                                     int* __restrict__ btot, int N, int nchunk) {
    const int r = blockIdx.y;
    const int idx = blockIdx.x * 1024 + threadIdx.x;
    const int lane = threadIdx.x & 63, wave = threadIdx.x >> 6;
    __shared__ int wsum[16];
    int v = (idx < N) ? deg[(size_t)r * N + idx] : 0;
    int x = v;
#pragma unroll
    for (int off = 1; off < 64; off <<= 1) {
        int y = __shfl_up(x, off, 64);
        if (lane >= off) x += y;
    }
    if (lane == 63) wsum[wave] = x;
    __syncthreads();
    if (wave == 0 && lane < 16) {
        int y = wsum[lane];
#pragma unroll
        for (int off = 1; off < 16; off <<= 1) {
            int z = __shfl_up(y, off, 64);
            if (lane >= off) y += z;
        }
        wsum[lane] = y;
    }
    __syncthreads();
    int woff = (wave > 0) ? wsum[wave - 1] : 0;
    if (idx < N) offs[(size_t)r * N + idx] = woff + x - v;
    if (threadIdx.x == 1023) btot[r * nchunk + blockIdx.x] = woff + x;
}

__global__ __launch_bounds__(256) void scan2_kernel(const int* __restrict__ btot,
                                                    int* __restrict__ offs, int N, int nchunk) {
    const int r = blockIdx.y;
    const int chunk = blockIdx.x;
    const int t = threadIdx.x;
    const int lane = t & 63, wave = t >> 6;
    __shared__ int red[4];
    int pre = 0;
    for (int i = t; i < chunk; i += 256) pre += btot[r * nchunk + i];
#pragma unroll
    for (int off = 32; off >= 1; off >>= 1) pre += __shfl_xor(pre, off, 64);
    if (lane == 0) red[wave] = pre;
    __syncthreads();
    int ptot = red[0] + red[1] + red[2] + red[3];
    for (int j = t; j < 1024; j += 256) {
        int idx = chunk * 1024 + j;
        if (idx < N) offs[(size_t)r * N + idx] += ptot;
    }
}

__global__ __launch_bounds__(256) void fill2_kernel(
    const unsigned* __restrict__ bbuf, const int* __restrict__ gcnt,
    const int* __restrict__ offs, unsigned short* __restrict__ csr, int NB, int N, int E) {
    const int r = blockIdx.y;
    const int b = blockIdx.x;
    const int t = threadIdx.x;
    __shared__ int curl[NODE_CHUNK];
    for (int i = t; i < NODE_CHUNK; i += 256) {
        int idx = b * NODE_CHUNK + i;
        curl[i] = (idx < N) ? offs[(size_t)r * N + idx] : 0;
    }
    __syncthreads();
    const int cnt = gcnt[r * NB + b];
    const unsigned* bb = bbuf + ((size_t)r * NB + b) * BCAP;
    unsigned short* csrr = csr + (size_t)r * E;
    for (int i = t; i < cnt; i += 256) {
        unsigned pk = bb[i];
        int dloc = (pk >> 16) & (NODE_CHUNK - 1);
        int pos = atomicAdd(&curl[dloc], 1);
        csrr[pos] = (unsigned short)(pk & 0xffffu);
    }
}

// ---------------- fused per-dst softmax + aggregation + bias + ELU -> z (bf16) ----------------
// One dst per 16-lane group (4 dst/wave): csr/el loads broadcast within the group,
// each lane owns 8 output columns end-to-end -> no shuffles, no cross-lane reductions.

__global__ __launch_bounds__(256) void gather_kernel(
    const unsigned short* __restrict__ csr, const int* __restrict__ offs,
    const int* __restrict__ deg, const float* __restrict__ el, const float* __restrict__ er,
    const unsigned short* __restrict__ hsb, const float* __restrict__ b_gat,
    unsigned short* __restrict__ z, int N, int E) {
    const int r = blockIdx.y;
    const int t = threadIdx.x;
    const int gid = t >> 4;   // group in block (16 groups)
    const int gl = t & 15;    // lane in group -> owns cols gl*8..gl*8+7
    const int d = blockIdx.x * 16 + gid;
    if (d >= N) return;
    const int beg = offs[(size_t)r * N + d];
    const int dg = deg[(size_t)r * N + d];
    float ac[8] = {0.f, 0.f, 0.f, 0.f, 0.f, 0.f, 0.f, 0.f};
    float ssum = 0.f;
    const float erd = er[(size_t)r * N + d];
    const float* elr = el + (size_t)r * N;
    const unsigned short* csrr = csr + (size_t)r * E;
    const unsigned short* hsr = hsb + (size_t)r * N * 128;
    for (int i = beg; i < beg + dg; ++i) {
        int src = csrr[i];                       // broadcast within group
        float e = elr[src] + erd;                // broadcast
        e = e > 0.f ? e : 0.2f * e;
        float p = __expf(e);
        ssum += p;
        uint4 hw = *(const uint4*)(hsr + (size_t)src * 128 + gl * 8);
        ac[0] += p * bf2f((unsigned short)(hw.x & 0xffffu));
        ac[1] += p * bf2f((unsigned short)(hw.x >> 16));
        ac[2] += p * bf2f((unsigned short)(hw.y & 0xffffu));
        ac[3] += p * bf2f((unsigned short)(hw.y >> 16));
        ac[4] += p * bf2f((unsigned short)(hw.z & 0xffffu));
        ac[5] += p * bf2f((unsigned short)(hw.z >> 16));
        ac[6] += p * bf2f((unsigned short)(hw.w & 0xffffu));
        ac[7] += p * bf2f((unsigned short)(hw.w >> 16));
    }
    float inv = (dg > 0) ? 1.f / ssum : 0.f;
    const float* bg = b_gat + r * 128 + gl * 8;
    uint4 ow;
    ow.x = pk2bf(eluf(ac[0] * inv + bg[0]), eluf(ac[1] * inv + bg[1]));
    ow.y = pk2bf(eluf(ac[2] * inv + bg[2]), eluf(ac[3] * inv + bg[3]));
    ow.z = pk2bf(eluf(ac[4] * inv + bg[4]), eluf(ac[5] * inv + bg[5]));
    ow.w = pk2bf(eluf(ac[6] * inv + bg[6]), eluf(ac[7] * inv + bg[7]));
    *(uint4*)(z + ((size_t)r * N + d) * 128 + gl * 8) = ow;
}

// ---------------- semantic attention GEMM (MFMA) -> per-block partial sums ----------------

__global__ __launch_bounds__(256) void gemm_sem(
    const unsigned short* __restrict__ z, const unsigned short* __restrict__ W1p,
    const float* __restrict__ b1, const float* __restrict__ w2,
    float* __restrict__ wpart, int N) {
    const int r = blockIdx.y;
    const int n0 = blockIdx.x * 64;
    const int t = threadIdx.x;
    const int w = t >> 6, l = t & 63;
    __shared__ unsigned short Alds[64 * 128];
    __shared__ float sred[4];
    const unsigned short* A = z + (size_t)r * N * 128;
#pragma unroll
    for (int i = 0; i < 4; ++i) {
        int cid = t + 256 * i;
        int row = cid >> 4, kc = cid & 15;
        uint4 v = make_uint4(0, 0, 0, 0);
        if (n0 + row < N) v = *(const uint4*)(A + (size_t)(n0 + row) * 128 + kc * 8);
        int off = ((row * 256) + kc * 16) ^ ((row & 7) << 4);
        *(uint4*)((char*)Alds + off) = v;
    }
    __syncthreads();

    const bf16x8* bp = (const bf16x8*)W1p;
    f32x4 acc[8] = {};
    const int arow = w * 16 + (l & 15);
#pragma unroll
    for (int ks = 0; ks < 4; ++ks) {
        int aoff = ((arow * 256) + ks * 64 + (l >> 4) * 16) ^ ((arow & 7) << 4);
        bf16x8 av = *(const bf16x8*)((char*)Alds + aoff);
#pragma unroll
        for (int cf = 0; cf < 8; ++cf) {
            bf16x8 bv = bp[(ks * 8 + cf) * 64 + l];
            acc[cf] = __builtin_amdgcn_mfma_f32_16x16x32_bf16(av, bv, acc[cf], 0, 0, 0);
        }
    }
    float b1v[8], w2v[8];
#pragma unroll
    for (int cf = 0; cf < 8; ++cf) {
        int col = cf * 16 + (l & 15);
        b1v[cf] = b1[col];
        w2v[cf] = w2[col];
    }
    float wloc = 0.f;
#pragma unroll
    for (int i = 0; i < 4; ++i) {
        int row = n0 + w * 16 + (l >> 4) * 4 + i;
        float s = 0.f;
#pragma unroll
        for (int cf = 0; cf < 8; ++cf) s += tanhf(acc[cf][i] + b1v[cf]) * w2v[cf];
        s += __shfl_xor(s, 1, 64);
        s += __shfl_xor(s, 2, 64);
        s += __shfl_xor(s, 4, 64);
        s += __shfl_xor(s, 8, 64);
        if ((l & 15) == 0 && row < N) wloc += s;
    }
    wloc += __shfl_xor(wloc, 16, 64);
    wloc += __shfl_xor(wloc, 32, 64);
    if (l == 0) sred[w] = wloc;
    __syncthreads();
    if (t == 0)
        wpart[(size_t)r * gridDim.x + blockIdx.x] = sred[0] + sred[1] + sred[2] + sred[3];
}

// ---------------- reduce partials + 3-way softmax -> aw ----------------

__global__ void reduce_sem(const float* __restrict__ wpart, float* __restrict__ aw,
                           int nblk, int N) {
    const int t = threadIdx.x, l = t & 63, w = t >> 6;
    __shared__ float sred[R_REL][4];
    float s[R_REL] = {0.f, 0.f, 0.f};
    for (int i = t; i < nblk; i += 256) {
#pragma unroll
        for (int r = 0; r < R_REL; ++r) s[r] += wpart[(size_t)r * nblk + i];
    }
#pragma unroll
    for (int r = 0; r < R_REL; ++r) {
#pragma unroll
        for (int off = 32; off >= 1; off >>= 1) s[r] += __shfl_xor(s[r], off, 64);
        if (l == 0) sred[r][w] = s[r];
    }
    __syncthreads();
    if (t == 0) {
        float w0 = (sred[0][0] + sred[0][1] + sred[0][2] + sred[0][3]) / (float)N;
        float w1 = (sred[1][0] + sred[1][1] + sred[1][2] + sred[1][3]) / (float)N;
        float w2 = (sred[2][0] + sred[2][1] + sred[2][2] + sred[2][3]) / (float)N;
        float m = fmaxf(w0, fmaxf(w1, w2));
        float e0 = __expf(w0 - m), e1 = __expf(w1 - m), e2 = __expf(w2 - m);
        float si = e0 + e1 + e2;
        aw[0] = e0 / si; aw[1] = e1 / si; aw[2] = e2 / si;
    }
}

__global__ void combine(const unsigned short* __restrict__ z, const float* __restrict__ aw,
                        float* __restrict__ out, int N) {
    int idx = blockIdx.x * 256 + threadIdx.x;
    if (idx >= N * 32) return;
    int n = idx >> 5, c4 = idx & 31;
    float a0 = aw[0], a1 = aw[1], a2 = aw[2];
    uint2 z0 = *(const uint2*)(z + ((size_t)0 * N + n) * 128 + c4 * 4);
    uint2 z1 = *(const uint2*)(z + ((size_t)1 * N + n) * 128 + c4 * 4);
    uint2 z2 = *(const uint2*)(z + ((size_t)2 * N + n) * 128 + c4 * 4);
    float4 o;
    o.x = a0 * bf2f((unsigned short)(z0.x & 0xffffu)) + a1 * bf2f((unsigned short)(z1.x & 0xffffu)) + a2 * bf2f((unsigned short)(z2.x & 0xffffu));
    o.y = a0 * bf2f((unsigned short)(z0.x >> 16))     + a1 * bf2f((unsigned short)(z1.x >> 16))     + a2 * bf2f((unsigned short)(z2.x >> 16));
    o.z = a0 * bf2f((unsigned short)(z0.y & 0xffffu)) + a1 * bf2f((unsigned short)(z1.y & 0xffffu)) + a2 * bf2f((unsigned short)(z2.y & 0xffffu));
    o.w = a0 * bf2f((unsigned short)(z0.y >> 16))     + a1 * bf2f((unsigned short)(z1.y >> 16))     + a2 * bf2f((unsigned short)(z2.y >> 16));
    *(float4*)(out + (size_t)idx * 4) = o;
}

// ---------------- launch ----------------

extern "C" void kernel_launch(void* const* d_in, const int* in_sizes, int n_in,
                              void* d_out, int out_size, void* d_ws, size_t ws_size,
                              hipStream_t stream) {
    const float* dst_feat = (const float*)d_in[0];
    const float* src_feats = (const float*)d_in[1];
    const int*   src_idx  = (const int*)d_in[2];
    const int*   dst_idx  = (const int*)d_in[3];
    const float* WT_dst   = (const float*)d_in[4];
    const float* bT_dst   = (const float*)d_in[5];
    const float* WT_src   = (const float*)d_in[6];
    const float* bT_src   = (const float*)d_in[7];
    const float* W_gat    = (const float*)d_in[8];
    const float* attn_l   = (const float*)d_in[9];
    const float* attn_r   = (const float*)d_in[10];
    const float* b_gat    = (const float*)d_in[11];
    const float* W1_sem   = (const float*)d_in[12];
    const float* b1_sem   = (const float*)d_in[13];
    const float* w2_sem   = (const float*)d_in[14];

    const int N = in_sizes[0] / 256;
    const int E = in_sizes[2] / R_REL;
    float* out = (float*)d_out;

    const int nblk = (N + 63) / 64;
    const int nchunk = (N + 1023) / 1024;
    const int NB = (N + NODE_CHUNK - 1) / NODE_CHUNK;

    char* ws = (char*)d_ws;
    size_t off = 0;
    auto alloc = [&](size_t bytes) { char* p = ws + off; off = align_up(off + bytes, 256); return p; };
    unsigned short* hsb   = (unsigned short*)alloc((size_t)R_REL * N * 128 * 2);
    unsigned short* zbuf  = (unsigned short*)alloc((size_t)R_REL * N * 128 * 2);
    float*    Wc    = (float*)alloc((size_t)R_REL * 256 * 128 * 4);
    unsigned short* Wcp   = (unsigned short*)alloc((size_t)R_REL * 256 * 128 * 2);
    unsigned short* W1p   = (unsigned short*)alloc((size_t)128 * 128 * 2);
    float*    bc    = (float*)alloc(R_REL * 128 * 4);
    float*    u     = (float*)alloc(R_REL * 256 * 4);
    float*    cc    = (float*)alloc(R_REL * 4);
    float*    el    = (float*)alloc((size_t)R_REL * N * 4);
    float*    er    = (float*)alloc((size_t)R_REL * N * 4);
    int*      deg   = (int*)alloc((size_t)R_REL * N * 4);
    int*      offs  = (int*)alloc((size_t)R_REL * N * 4);
    int*      btot  = (int*)alloc((size_t)R_REL * nchunk * 4);
    int*      gcnt  = (int*)alloc((size_t)R_REL * NB * 4);
    unsigned* bbuf  = (unsigned*)alloc((size_t)R_REL * NB * BCAP * 4);
    unsigned short* csr = (unsigned short*)alloc((size_t)R_REL * E * 2);
    float*    wpart = (float*)alloc((size_t)R_REL * nblk * 4);
    float*    aw    = (float*)alloc(R_REL * 4);

    hipMemsetAsync(gcnt, 0, (size_t)R_REL * NB * 4, stream);

    // weight prep
    vu_kernel<<<R_REL, 256, 0, stream>>>(W_gat, attn_r, WT_dst, bT_dst, u, cc);
    wc_kernel<<<dim3(257, R_REL), 128, 0, stream>>>(WT_src, bT_src, W_gat, Wc, bc);
    pack_kernel<<<dim3(64, R_REL), 64, 0, stream>>>(Wc, Wcp, 256 * 128, 8);
    pack_kernel<<<dim3(32, 1), 64, 0, stream>>>(W1_sem, W1p, 0, 4);

    // CSR build (2-level bucket sort)
    bucket_kernel<<<dim3((E + 1023) / 1024, R_REL), 256, 0, stream>>>(src_idx, dst_idx, gcnt, bbuf, NB, E);
    hist_kernel<<<dim3(NB, R_REL), 256, 0, stream>>>(bbuf, gcnt, deg, NB, N);
    scan1_kernel<<<dim3(nchunk, R_REL), 1024, 0, stream>>>(deg, offs, btot, N, nchunk);
    scan2_kernel<<<dim3(nchunk, R_REL), 256, 0, stream>>>(btot, offs, N, nchunk);
    fill2_kernel<<<dim3(NB, R_REL), 256, 0, stream>>>(bbuf, gcnt, offs, csr, NB, N, E);

    // node projections
    dim3 g1(nblk, R_REL);
    gemm_hs<<<g1, 256, 0, stream>>>(src_feats, Wcp, bc, attn_l, hsb, el, N);
    er_kernel<<<(N + 3) / 4, 256, 0, stream>>>(dst_feat, u, cc, er, N);

    // fused single-pass edge softmax + aggregation -> z
    gather_kernel<<<dim3((N + 15) / 16, R_REL), 256, 0, stream>>>(csr, offs, deg, el, er, hsb, b_gat, zbuf, N, E);

    // semantic attention + combine
    gemm_sem<<<g1, 256, 0, stream>>>(zbuf, W1p, b1_sem, w2_sem, wpart, N);
    reduce_sem<<<1, 256, 0, stream>>>(wpart, aw, nblk, N);
    combine<<<(N * 32 + 255) / 256, 256, 0, stream>>>(zbuf, aw, out, N);
}

// Round 10
// 251.993 us; speedup vs baseline: 12.4861x; 1.0563x over previous
//
#include <hip/hip_runtime.h>
#include <hip/hip_bf16.h>

#define R_REL 3
#define NODE_CHUNK 512
#define BCAP 6144

typedef __attribute__((ext_vector_type(8))) short bf16x8;
typedef __attribute__((ext_vector_type(4))) float f32x4;

static inline size_t align_up(size_t x, size_t a) { return (x + a - 1) & ~(a - 1); }

__device__ __forceinline__ float eluf(float x) {
    return x > 0.f ? x : (__expf(x) - 1.f);
}
__device__ __forceinline__ unsigned short f2bf(float f) {
    __hip_bfloat16 h = __float2bfloat16(f);
    return *reinterpret_cast<unsigned short*>(&h);
}
__device__ __forceinline__ unsigned pk2bf(float lo, float hi) {
    __hip_bfloat162 h = __float22bfloat162_rn(make_float2(lo, hi));
    return *reinterpret_cast<unsigned*>(&h);
}
__device__ __forceinline__ float bf2f(unsigned short h) {
    return __uint_as_float((unsigned)h << 16);
}

// ---------------- fused v+u weight prep ----------------

__global__ void vu_kernel(const float* __restrict__ W_gat, const float* __restrict__ attn_r,
                          const float* __restrict__ WT_dst, const float* __restrict__ bT_dst,
                          float* __restrict__ u, float* __restrict__ cc) {
    int r = blockIdx.x;
    int t = threadIdx.x;
    __shared__ float ar[128];
    __shared__ float vs[128];
    if (t < 128) ar[t] = attn_r[r * 128 + t];
    __syncthreads();
    if (t < 128) {
        const float* W = W_gat + (size_t)r * 128 * 128 + (size_t)t * 128;
        float s = 0.f;
        for (int j = 0; j < 128; ++j) s += W[j] * ar[j];
        vs[t] = s;
    }
    __syncthreads();
    const float* W = WT_dst + (size_t)t * 128;
    float s = 0.f;
    for (int i = 0; i < 128; ++i) s += W[i] * vs[i];
    u[r * 256 + t] = s;
    if (t == 0) {
        float c = 0.f;
        for (int i = 0; i < 128; ++i) c += bT_dst[i] * vs[i];
        cc[r] = c;
    }
}

__global__ void wc_kernel(const float* __restrict__ WT_src, const float* __restrict__ bT_src,
                          const float* __restrict__ W_gat, float* __restrict__ Wc,
                          float* __restrict__ bc) {
    int r = blockIdx.y;
    int k = blockIdx.x;  // 0..256
    int j = threadIdx.x; // 0..127
    __shared__ float as[128];
    const float* arow = (k < 256) ? (WT_src + ((size_t)r * 256 + k) * 128)
                                  : (bT_src + (size_t)r * 128);
    as[j] = arow[j];
    __syncthreads();
    const float* W = W_gat + (size_t)r * 128 * 128;
    float s = 0.f;
    for (int i = 0; i < 128; ++i) s += as[i] * W[(size_t)i * 128 + j];
    if (k < 256) Wc[((size_t)r * 256 + k) * 128 + j] = s;
    else         bc[(size_t)r * 128 + j] = s;
}

// pack fp32 [relstride rows...][K][128] matrix into per-lane MFMA B-fragment order
__global__ void pack_kernel(const float* __restrict__ S, unsigned short* __restrict__ P,
                            int relstride, int KS) {
    int r = blockIdx.y;
    int ks = blockIdx.x >> 3, cb = blockIdx.x & 7;
    int l = threadIdx.x;
    const float* Sr = S + (size_t)r * relstride;
    int col = cb * 16 + (l & 15);
    int kb = ks * 32 + (l >> 4) * 8;
    unsigned short v[8];
#pragma unroll
    for (int j = 0; j < 8; ++j) v[j] = f2bf(Sr[(size_t)(kb + j) * 128 + col]);
    unsigned short* dst = P + ((((size_t)r * KS + ks) * 8 + cb) * 64 + l) * 8;
    *(uint4*)dst = *(uint4*)v;
}

// ---------------- hs GEMM (MFMA): B-pack staged in LDS (evict-proof), 8 waves x 128 rows ----

__global__ __launch_bounds__(512) void gemm_hs(
    const float* __restrict__ src, const unsigned short* __restrict__ Bpack,
    const float* __restrict__ bc, const float* __restrict__ attn_l,
    unsigned short* __restrict__ hsb, float* __restrict__ el, int N) {
    const int r = blockIdx.y;
    const int t = threadIdx.x;
    const int w = t >> 6, l = t & 63;
    __shared__ unsigned short Blds[256 * 128];  // 64KB: full B-pack for this relation

    // stage B once per block (128 rows amortize it); linear copy, coalesced 16B chunks
    const unsigned short* bsrc = Bpack + (size_t)r * 256 * 128;
#pragma unroll
    for (int i = 0; i < 8; ++i) {
        int c = i * 512 + t;  // 4096 chunks of 16B
        *(uint4*)&Blds[(size_t)c * 8] = *(const uint4*)&bsrc[(size_t)c * 8];
    }
    __syncthreads();

    const int rowbase = blockIdx.x * 128 + w * 16;
    const int arow_i = rowbase + (l & 15);
    const int kg = l >> 4;
    const float* A = src + (size_t)r * N * 256;
    const float* arow = A + (size_t)(arow_i < N ? arow_i : N - 1) * 256;

    f32x4 acc[8] = {};
#pragma unroll
    for (int ks = 0; ks < 8; ++ks) {
        float4 a0 = *(const float4*)(arow + ks * 32 + kg * 8);
        float4 a1 = *(const float4*)(arow + ks * 32 + kg * 8 + 4);
        uint4 uv;
        uv.x = pk2bf(a0.x, a0.y);
        uv.y = pk2bf(a0.z, a0.w);
        uv.z = pk2bf(a1.x, a1.y);
        uv.w = pk2bf(a1.z, a1.w);
        bf16x8 av = *(bf16x8*)&uv;
#pragma unroll
        for (int cf = 0; cf < 8; ++cf) {
            bf16x8 bv = *(const bf16x8*)&Blds[((size_t)(ks * 8 + cf) * 64 + l) * 8];
            acc[cf] = __builtin_amdgcn_mfma_f32_16x16x32_bf16(av, bv, acc[cf], 0, 0, 0);
        }
    }
    float bcv[8], alv[8];
#pragma unroll
    for (int cf = 0; cf < 8; ++cf) {
        int col = cf * 16 + (l & 15);
        bcv[cf] = bc[r * 128 + col];
        alv[cf] = attn_l[r * 128 + col];
    }
#pragma unroll
    for (int i = 0; i < 4; ++i) {
        int row = rowbase + (l >> 4) * 4 + i;
        float pe = 0.f;
        unsigned short hv[8];
#pragma unroll
        for (int cf = 0; cf < 8; ++cf) {
            float v = acc[cf][i] + bcv[cf];
            pe += v * alv[cf];
            hv[cf] = f2bf(v);
        }
        if (row < N) {
            unsigned short* hp = hsb + ((size_t)r * N + row) * 128 + (l & 15);
#pragma unroll
            for (int cf = 0; cf < 8; ++cf) hp[cf * 16] = hv[cf];
        }
        pe += __shfl_xor(pe, 1, 64);
        pe += __shfl_xor(pe, 2, 64);
        pe += __shfl_xor(pe, 4, 64);
        pe += __shfl_xor(pe, 8, 64);
        if ((l & 15) == 0 && row < N) el[(size_t)r * N + row] = pe;
    }
}

// ---------------- er: er[r][n] = dst_feat[n] . u[r] + cc[r] ----------------

__global__ void er_kernel(const float* __restrict__ dst_feat, const float* __restrict__ u,
                          const float* __restrict__ cc, float* __restrict__ er, int N) {
    __shared__ float us[3][256];
    for (int i = threadIdx.x; i < 3 * 256; i += 256) us[i / 256][i & 255] = u[i];
    __syncthreads();
    int wave = threadIdx.x >> 6, lane = threadIdx.x & 63;
    int n = blockIdx.x * 4 + wave;
    if (n >= N) return;
    float4 f = *(const float4*)(dst_feat + (size_t)n * 256 + lane * 4);
#pragma unroll
    for (int r = 0; r < R_REL; ++r) {
        float4 uv = *(float4*)&us[r][lane * 4];
        float s = f.x * uv.x + f.y * uv.y + f.z * uv.z + f.w * uv.w;
#pragma unroll
        for (int off = 32; off >= 1; off >>= 1) s += __shfl_xor(s, off, 64);
        if (lane == 0) er[(size_t)r * N + n] = s + cc[r];
    }
}

// ---------------- CSR build via 2-level bucket sort ----------------

__global__ __launch_bounds__(256) void bucket_kernel(
    const int* __restrict__ si, const int* __restrict__ di,
    int* __restrict__ gcnt, unsigned* __restrict__ bbuf, int NB, int E) {
    const int r = blockIdx.y;
    const int t = threadIdx.x;
    const int e0 = blockIdx.x * 1024;
    __shared__ int cnt[128];
    __shared__ int base[128];
    if (t < 128) cnt[t] = 0;
    __syncthreads();
    int bk[4], rank[4]; unsigned pack[4]; bool val[4];
#pragma unroll
    for (int j = 0; j < 4; ++j) {
        int e = e0 + j * 256 + t;
        val[j] = e < E;
        bk[j] = 0; rank[j] = 0; pack[j] = 0;
        if (val[j]) {
            size_t g = (size_t)r * E + e;
            int s = si[g], d = di[g];
            bk[j] = d >> 9;
            pack[j] = (unsigned)s | ((unsigned)d << 16);
            rank[j] = atomicAdd(&cnt[bk[j]], 1);
        }
    }
    __syncthreads();
    if (t < NB && cnt[t] > 0) base[t] = atomicAdd(&gcnt[r * NB + t], cnt[t]);
    __syncthreads();
#pragma unroll
    for (int j = 0; j < 4; ++j) {
        if (val[j])
            bbuf[((size_t)r * NB + bk[j]) * BCAP + base[bk[j]] + rank[j]] = pack[j];
    }
}

__global__ __launch_bounds__(256) void hist_kernel(
    const unsigned* __restrict__ bbuf, const int* __restrict__ gcnt,
    int* __restrict__ deg, int NB, int N) {
    const int r = blockIdx.y;
    const int b = blockIdx.x;
    const int t = threadIdx.x;
    __shared__ int hist[NODE_CHUNK];
    for (int i = t; i < NODE_CHUNK; i += 256) hist[i] = 0;
    __syncthreads();
    const int cnt = gcnt[r * NB + b];
    const unsigned* bb = bbuf + ((size_t)r * NB + b) * BCAP;
    for (int i = t; i < cnt; i += 256) {
        int dloc = (bb[i] >> 16) & (NODE_CHUNK - 1);
        atomicAdd(&hist[dloc], 1);
    }
    __syncthreads();
    for (int i = t; i < NODE_CHUNK; i += 256) {
        int idx = b * NODE_CHUNK + i;
        if (idx < N) deg[(size_t)r * N + idx] = hist[i];
    }
}

__global__ __launch_bounds__(1024) void scan1_kernel(const int* __restrict__ deg,
                                                     int* __restrict__ offs,
                                                     int* __restrict__ btot, int N, int nchunk) {
    const int r = blockIdx.y;
    const int idx = blockIdx.x * 1024 + threadIdx.x;
    const int lane = threadIdx.x & 63, wave = threadIdx.x >> 6;
    __shared__ int wsum[16];
    int v = (idx < N) ? deg[(size_t)r * N + idx] : 0;
    int x = v;
#pragma unroll
    for (int off = 1; off < 64; off <<= 1) {
        int y = __shfl_up(x, off, 64);
        if (lane >= off) x += y;
    }
    if (lane == 63) wsum[wave] = x;
    __syncthreads();
    if (wave == 0 && lane < 16) {
        int y = wsum[lane];
#pragma unroll
        for (int off = 1; off < 16; off <<= 1) {
            int z = __shfl_up(y, off, 64);
            if (lane >= off) y += z;
        }
        wsum[lane] = y;
    }
    __syncthreads();
    int woff = (wave > 0) ? wsum[wave - 1] : 0;
    if (idx < N) offs[(size_t)r * N + idx] = woff + x - v;
    if (threadIdx.x == 1023) btot[r * nchunk + blockIdx.x] = woff + x;
}

__global__ __launch_bounds__(256) void scan2_kernel(const int* __restrict__ btot,
                                                    int* __restrict__ offs, int N, int nchunk) {
    const int r = blockIdx.y;
    const int chunk = blockIdx.x;
    const int t = threadIdx.x;
    const int lane = t & 63, wave = t >> 6;
    __shared__ int red[4];
    int pre = 0;
    for (int i = t; i < chunk; i += 256) pre += btot[r * nchunk + i];
#pragma unroll
    for (int off = 32; off >= 1; off >>= 1) pre += __shfl_xor(pre, off, 64);
    if (lane == 0) red[wave] = pre;
    __syncthreads();
    int ptot = red[0] + red[1] + red[2] + red[3];
    for (int j = t; j < 1024; j += 256) {
        int idx = chunk * 1024 + j;
        if (idx < N) offs[(size_t)r * N + idx] += ptot;
    }
}

__global__ __launch_bounds__(256) void fill2_kernel(
    const unsigned* __restrict__ bbuf, const int* __restrict__ gcnt,
    const int* __restrict__ offs, unsigned short* __restrict__ csr, int NB, int N, int E) {
    const int r = blockIdx.y;
    const int b = blockIdx.x;
    const int t = threadIdx.x;
    __shared__ int curl[NODE_CHUNK];
    for (int i = t; i < NODE_CHUNK; i += 256) {
        int idx = b * NODE_CHUNK + i;
        curl[i] = (idx < N) ? offs[(size_t)r * N + idx] : 0;
    }
    __syncthreads();
    const int cnt = gcnt[r * NB + b];
    const unsigned* bb = bbuf + ((size_t)r * NB + b) * BCAP;
    unsigned short* csrr = csr + (size_t)r * E;
    for (int i = t; i < cnt; i += 256) {
        unsigned pk = bb[i];
        int dloc = (pk >> 16) & (NODE_CHUNK - 1);
        int pos = atomicAdd(&curl[dloc], 1);
        csrr[pos] = (unsigned short)(pk & 0xffffu);
    }
}

// ---------------- fused per-dst softmax + aggregation + bias + ELU -> z (bf16) ----------------
// One dst per 16-lane group (4 dst/wave): csr/el loads broadcast within the group,
// each lane owns 8 output columns end-to-end -> no shuffles, no cross-lane reductions.

__global__ __launch_bounds__(256) void gather_kernel(
    const unsigned short* __restrict__ csr, const int* __restrict__ offs,
    const int* __restrict__ deg, const float* __restrict__ el, const float* __restrict__ er,
    const unsigned short* __restrict__ hsb, const float* __restrict__ b_gat,
    unsigned short* __restrict__ z, int N, int E) {
    const int r = blockIdx.y;
    const int t = threadIdx.x;
    const int gid = t >> 4;   // group in block (16 groups)
    const int gl = t & 15;    // lane in group -> owns cols gl*8..gl*8+7
    const int d = blockIdx.x * 16 + gid;
    if (d >= N) return;
    const int beg = offs[(size_t)r * N + d];
    const int dg = deg[(size_t)r * N + d];
    float ac[8] = {0.f, 0.f, 0.f, 0.f, 0.f, 0.f, 0.f, 0.f};
    float ssum = 0.f;
    const float erd = er[(size_t)r * N + d];
    const float* elr = el + (size_t)r * N;
    const unsigned short* csrr = csr + (size_t)r * E;
    const unsigned short* hsr = hsb + (size_t)r * N * 128;
    for (int i = beg; i < beg + dg; ++i) {
        int src = csrr[i];                       // broadcast within group
        float e = elr[src] + erd;                // broadcast
        e = e > 0.f ? e : 0.2f * e;
        float p = __expf(e);
        ssum += p;
        uint4 hw = *(const uint4*)(hsr + (size_t)src * 128 + gl * 8);
        ac[0] += p * bf2f((unsigned short)(hw.x & 0xffffu));
        ac[1] += p * bf2f((unsigned short)(hw.x >> 16));
        ac[2] += p * bf2f((unsigned short)(hw.y & 0xffffu));
        ac[3] += p * bf2f((unsigned short)(hw.y >> 16));
        ac[4] += p * bf2f((unsigned short)(hw.z & 0xffffu));
        ac[5] += p * bf2f((unsigned short)(hw.z >> 16));
        ac[6] += p * bf2f((unsigned short)(hw.w & 0xffffu));
        ac[7] += p * bf2f((unsigned short)(hw.w >> 16));
    }
    float inv = (dg > 0) ? 1.f / ssum : 0.f;
    const float* bg = b_gat + r * 128 + gl * 8;
    uint4 ow;
    ow.x = pk2bf(eluf(ac[0] * inv + bg[0]), eluf(ac[1] * inv + bg[1]));
    ow.y = pk2bf(eluf(ac[2] * inv + bg[2]), eluf(ac[3] * inv + bg[3]));
    ow.z = pk2bf(eluf(ac[4] * inv + bg[4]), eluf(ac[5] * inv + bg[5]));
    ow.w = pk2bf(eluf(ac[6] * inv + bg[6]), eluf(ac[7] * inv + bg[7]));
    *(uint4*)(z + ((size_t)r * N + d) * 128 + gl * 8) = ow;
}

// ---------------- semantic attention GEMM (MFMA) -> per-block partial sums ----------------

__global__ __launch_bounds__(256) void gemm_sem(
    const unsigned short* __restrict__ z, const unsigned short* __restrict__ W1p,
    const float* __restrict__ b1, const float* __restrict__ w2,
    float* __restrict__ wpart, int N) {
    const int r = blockIdx.y;
    const int n0 = blockIdx.x * 64;
    const int t = threadIdx.x;
    const int w = t >> 6, l = t & 63;
    __shared__ unsigned short Alds[64 * 128];
    __shared__ float sred[4];
    const unsigned short* A = z + (size_t)r * N * 128;
#pragma unroll
    for (int i = 0; i < 4; ++i) {
        int cid = t + 256 * i;
        int row = cid >> 4, kc = cid & 15;
        uint4 v = make_uint4(0, 0, 0, 0);
        if (n0 + row < N) v = *(const uint4*)(A + (size_t)(n0 + row) * 128 + kc * 8);
        int off = ((row * 256) + kc * 16) ^ ((row & 7) << 4);
        *(uint4*)((char*)Alds + off) = v;
    }
    __syncthreads();

    const bf16x8* bp = (const bf16x8*)W1p;
    f32x4 acc[8] = {};
    const int arow = w * 16 + (l & 15);
#pragma unroll
    for (int ks = 0; ks < 4; ++ks) {
        int aoff = ((arow * 256) + ks * 64 + (l >> 4) * 16) ^ ((arow & 7) << 4);
        bf16x8 av = *(const bf16x8*)((char*)Alds + aoff);
#pragma unroll
        for (int cf = 0; cf < 8; ++cf) {
            bf16x8 bv = bp[(ks * 8 + cf) * 64 + l];
            acc[cf] = __builtin_amdgcn_mfma_f32_16x16x32_bf16(av, bv, acc[cf], 0, 0, 0);
        }
    }
    float b1v[8], w2v[8];
#pragma unroll
    for (int cf = 0; cf < 8; ++cf) {
        int col = cf * 16 + (l & 15);
        b1v[cf] = b1[col];
        w2v[cf] = w2[col];
    }
    float wloc = 0.f;
#pragma unroll
    for (int i = 0; i < 4; ++i) {
        int row = n0 + w * 16 + (l >> 4) * 4 + i;
        float s = 0.f;
#pragma unroll
        for (int cf = 0; cf < 8; ++cf) s += tanhf(acc[cf][i] + b1v[cf]) * w2v[cf];
        s += __shfl_xor(s, 1, 64);
        s += __shfl_xor(s, 2, 64);
        s += __shfl_xor(s, 4, 64);
        s += __shfl_xor(s, 8, 64);
        if ((l & 15) == 0 && row < N) wloc += s;
    }
    wloc += __shfl_xor(wloc, 16, 64);
    wloc += __shfl_xor(wloc, 32, 64);
    if (l == 0) sred[w] = wloc;
    __syncthreads();
    if (t == 0)
        wpart[(size_t)r * gridDim.x + blockIdx.x] = sred[0] + sred[1] + sred[2] + sred[3];
}

// ---------------- reduce partials + 3-way softmax -> aw ----------------

__global__ void reduce_sem(const float* __restrict__ wpart, float* __restrict__ aw,
                           int nblk, int N) {
    const int t = threadIdx.x, l = t & 63, w = t >> 6;
    __shared__ float sred[R_REL][4];
    float s[R_REL] = {0.f, 0.f, 0.f};
    for (int i = t; i < nblk; i += 256) {
#pragma unroll
        for (int r = 0; r < R_REL; ++r) s[r] += wpart[(size_t)r * nblk + i];
    }
#pragma unroll
    for (int r = 0; r < R_REL; ++r) {
#pragma unroll
        for (int off = 32; off >= 1; off >>= 1) s[r] += __shfl_xor(s[r], off, 64);
        if (l == 0) sred[r][w] = s[r];
    }
    __syncthreads();
    if (t == 0) {
        float w0 = (sred[0][0] + sred[0][1] + sred[0][2] + sred[0][3]) / (float)N;
        float w1 = (sred[1][0] + sred[1][1] + sred[1][2] + sred[1][3]) / (float)N;
        float w2 = (sred[2][0] + sred[2][1] + sred[2][2] + sred[2][3]) / (float)N;
        float m = fmaxf(w0, fmaxf(w1, w2));
        float e0 = __expf(w0 - m), e1 = __expf(w1 - m), e2 = __expf(w2 - m);
        float si = e0 + e1 + e2;
        aw[0] = e0 / si; aw[1] = e1 / si; aw[2] = e2 / si;
    }
}

__global__ void combine(const unsigned short* __restrict__ z, const float* __restrict__ aw,
                        float* __restrict__ out, int N) {
    int idx = blockIdx.x * 256 + threadIdx.x;
    if (idx >= N * 32) return;
    int n = idx >> 5, c4 = idx & 31;
    float a0 = aw[0], a1 = aw[1], a2 = aw[2];
    uint2 z0 = *(const uint2*)(z + ((size_t)0 * N + n) * 128 + c4 * 4);
    uint2 z1 = *(const uint2*)(z + ((size_t)1 * N + n) * 128 + c4 * 4);
    uint2 z2 = *(const uint2*)(z + ((size_t)2 * N + n) * 128 + c4 * 4);
    float4 o;
    o.x = a0 * bf2f((unsigned short)(z0.x & 0xffffu)) + a1 * bf2f((unsigned short)(z1.x & 0xffffu)) + a2 * bf2f((unsigned short)(z2.x & 0xffffu));
    o.y = a0 * bf2f((unsigned short)(z0.x >> 16))     + a1 * bf2f((unsigned short)(z1.x >> 16))     + a2 * bf2f((unsigned short)(z2.x >> 16));
    o.z = a0 * bf2f((unsigned short)(z0.y & 0xffffu)) + a1 * bf2f((unsigned short)(z1.y & 0xffffu)) + a2 * bf2f((unsigned short)(z2.y & 0xffffu));
    o.w = a0 * bf2f((unsigned short)(z0.y >> 16))     + a1 * bf2f((unsigned short)(z1.y >> 16))     + a2 * bf2f((unsigned short)(z2.y >> 16));
    *(float4*)(out + (size_t)idx * 4) = o;
}

// ---------------- launch ----------------

extern "C" void kernel_launch(void* const* d_in, const int* in_sizes, int n_in,
                              void* d_out, int out_size, void* d_ws, size_t ws_size,
                              hipStream_t stream) {
    const float* dst_feat = (const float*)d_in[0];
    const float* src_feats = (const float*)d_in[1];
    const int*   src_idx  = (const int*)d_in[2];
    const int*   dst_idx  = (const int*)d_in[3];
    const float* WT_dst   = (const float*)d_in[4];
    const float* bT_dst   = (const float*)d_in[5];
    const float* WT_src   = (const float*)d_in[6];
    const float* bT_src   = (const float*)d_in[7];
    const float* W_gat    = (const float*)d_in[8];
    const float* attn_l   = (const float*)d_in[9];
    const float* attn_r   = (const float*)d_in[10];
    const float* b_gat    = (const float*)d_in[11];
    const float* W1_sem   = (const float*)d_in[12];
    const float* b1_sem   = (const float*)d_in[13];
    const float* w2_sem   = (const float*)d_in[14];

    const int N = in_sizes[0] / 256;
    const int E = in_sizes[2] / R_REL;
    float* out = (float*)d_out;

    const int nblk = (N + 63) / 64;
    const int nblk_hs = (N + 127) / 128;
    const int nchunk = (N + 1023) / 1024;
    const int NB = (N + NODE_CHUNK - 1) / NODE_CHUNK;

    char* ws = (char*)d_ws;
    size_t off = 0;
    auto alloc = [&](size_t bytes) { char* p = ws + off; off = align_up(off + bytes, 256); return p; };
    unsigned short* hsb   = (unsigned short*)alloc((size_t)R_REL * N * 128 * 2);
    unsigned short* zbuf  = (unsigned short*)alloc((size_t)R_REL * N * 128 * 2);
    float*    Wc    = (float*)alloc((size_t)R_REL * 256 * 128 * 4);
    unsigned short* Wcp   = (unsigned short*)alloc((size_t)R_REL * 256 * 128 * 2);
    unsigned short* W1p   = (unsigned short*)alloc((size_t)128 * 128 * 2);
    float*    bc    = (float*)alloc(R_REL * 128 * 4);
    float*    u     = (float*)alloc(R_REL * 256 * 4);
    float*    cc    = (float*)alloc(R_REL * 4);
    float*    el    = (float*)alloc((size_t)R_REL * N * 4);
    float*    er    = (float*)alloc((size_t)R_REL * N * 4);
    int*      deg   = (int*)alloc((size_t)R_REL * N * 4);
    int*      offs  = (int*)alloc((size_t)R_REL * N * 4);
    int*      btot  = (int*)alloc((size_t)R_REL * nchunk * 4);
    int*      gcnt  = (int*)alloc((size_t)R_REL * NB * 4);
    unsigned* bbuf  = (unsigned*)alloc((size_t)R_REL * NB * BCAP * 4);
    unsigned short* csr = (unsigned short*)alloc((size_t)R_REL * E * 2);
    float*    wpart = (float*)alloc((size_t)R_REL * nblk * 4);
    float*    aw    = (float*)alloc(R_REL * 4);

    hipMemsetAsync(gcnt, 0, (size_t)R_REL * NB * 4, stream);

    // weight prep
    vu_kernel<<<R_REL, 256, 0, stream>>>(W_gat, attn_r, WT_dst, bT_dst, u, cc);
    wc_kernel<<<dim3(257, R_REL), 128, 0, stream>>>(WT_src, bT_src, W_gat, Wc, bc);
    pack_kernel<<<dim3(64, R_REL), 64, 0, stream>>>(Wc, Wcp, 256 * 128, 8);
    pack_kernel<<<dim3(32, 1), 64, 0, stream>>>(W1_sem, W1p, 0, 4);

    // CSR build (2-level bucket sort)
    bucket_kernel<<<dim3((E + 1023) / 1024, R_REL), 256, 0, stream>>>(src_idx, dst_idx, gcnt, bbuf, NB, E);
    hist_kernel<<<dim3(NB, R_REL), 256, 0, stream>>>(bbuf, gcnt, deg, NB, N);
    scan1_kernel<<<dim3(nchunk, R_REL), 1024, 0, stream>>>(deg, offs, btot, N, nchunk);
    scan2_kernel<<<dim3(nchunk, R_REL), 256, 0, stream>>>(btot, offs, N, nchunk);
    fill2_kernel<<<dim3(NB, R_REL), 256, 0, stream>>>(bbuf, gcnt, offs, csr, NB, N, E);

    // node projections
    gemm_hs<<<dim3(nblk_hs, R_REL), 512, 0, stream>>>(src_feats, Wcp, bc, attn_l, hsb, el, N);
    er_kernel<<<(N + 3) / 4, 256, 0, stream>>>(dst_feat, u, cc, er, N);

    // fused single-pass edge softmax + aggregation -> z
    gather_kernel<<<dim3((N + 15) / 16, R_REL), 256, 0, stream>>>(csr, offs, deg, el, er, hsb, b_gat, zbuf, N, E);

    // semantic attention + combine
    gemm_sem<<<dim3(nblk, R_REL), 256, 0, stream>>>(zbuf, W1p, b1_sem, w2_sem, wpart, N);
    reduce_sem<<<1, 256, 0, stream>>>(wpart, aw, nblk, N);
    combine<<<(N * 32 + 255) / 256, 256, 0, stream>>>(zbuf, aw, out, N);
}

// Round 11
// 247.436 us; speedup vs baseline: 12.7160x; 1.0184x over previous
//
#include <hip/hip_runtime.h>
#include <hip/hip_bf16.h>

#define R_REL 3
#define NODE_CHUNK 512
#define BCAP 6144

typedef __attribute__((ext_vector_type(8))) short bf16x8;
typedef __attribute__((ext_vector_type(4))) float f32x4;

static inline size_t align_up(size_t x, size_t a) { return (x + a - 1) & ~(a - 1); }

__device__ __forceinline__ float eluf(float x) {
    return x > 0.f ? x : (__expf(x) - 1.f);
}
__device__ __forceinline__ unsigned short f2bf(float f) {
    __hip_bfloat16 h = __float2bfloat16(f);
    return *reinterpret_cast<unsigned short*>(&h);
}
__device__ __forceinline__ unsigned pk2bf(float lo, float hi) {
    __hip_bfloat162 h = __float22bfloat162_rn(make_float2(lo, hi));
    return *reinterpret_cast<unsigned*>(&h);
}
__device__ __forceinline__ float bf2f(unsigned short h) {
    return __uint_as_float((unsigned)h << 16);
}

// ---------------- fused v+u weight prep ----------------

__global__ void vu_kernel(const float* __restrict__ W_gat, const float* __restrict__ attn_r,
                          const float* __restrict__ WT_dst, const float* __restrict__ bT_dst,
                          float* __restrict__ u, float* __restrict__ cc) {
    int r = blockIdx.x;
    int t = threadIdx.x;
    __shared__ float ar[128];
    __shared__ float vs[128];
    if (t < 128) ar[t] = attn_r[r * 128 + t];
    __syncthreads();
    if (t < 128) {
        const float* W = W_gat + (size_t)r * 128 * 128 + (size_t)t * 128;
        float s = 0.f;
        for (int j = 0; j < 128; ++j) s += W[j] * ar[j];
        vs[t] = s;
    }
    __syncthreads();
    const float* W = WT_dst + (size_t)t * 128;
    float s = 0.f;
    for (int i = 0; i < 128; ++i) s += W[i] * vs[i];
    u[r * 256 + t] = s;
    if (t == 0) {
        float c = 0.f;
        for (int i = 0; i < 128; ++i) c += bT_dst[i] * vs[i];
        cc[r] = c;
    }
}

__global__ void wc_kernel(const float* __restrict__ WT_src, const float* __restrict__ bT_src,
                          const float* __restrict__ W_gat, float* __restrict__ Wc,
                          float* __restrict__ bc) {
    int r = blockIdx.y;
    int k = blockIdx.x;  // 0..256
    int j = threadIdx.x; // 0..127
    __shared__ float as[128];
    const float* arow = (k < 256) ? (WT_src + ((size_t)r * 256 + k) * 128)
                                  : (bT_src + (size_t)r * 128);
    as[j] = arow[j];
    __syncthreads();
    const float* W = W_gat + (size_t)r * 128 * 128;
    float s = 0.f;
    for (int i = 0; i < 128; ++i) s += as[i] * W[(size_t)i * 128 + j];
    if (k < 256) Wc[((size_t)r * 256 + k) * 128 + j] = s;
    else         bc[(size_t)r * 128 + j] = s;
}

// pack fp32 [relstride rows...][K][128] matrix into per-lane MFMA B-fragment order
__global__ void pack_kernel(const float* __restrict__ S, unsigned short* __restrict__ P,
                            int relstride, int KS) {
    int r = blockIdx.y;
    int ks = blockIdx.x >> 3, cb = blockIdx.x & 7;
    int l = threadIdx.x;
    const float* Sr = S + (size_t)r * relstride;
    int col = cb * 16 + (l & 15);
    int kb = ks * 32 + (l >> 4) * 8;
    unsigned short v[8];
#pragma unroll
    for (int j = 0; j < 8; ++j) v[j] = f2bf(Sr[(size_t)(kb + j) * 128 + col]);
    unsigned short* dst = P + ((((size_t)r * KS + ks) * 8 + cb) * 64 + l) * 8;
    *(uint4*)dst = *(uint4*)v;
}

// ---------------- hs GEMM (MFMA): B-pack staged in LDS (evict-proof), 8 waves x 128 rows ----

__global__ __launch_bounds__(512) void gemm_hs(
    const float* __restrict__ src, const unsigned short* __restrict__ Bpack,
    const float* __restrict__ bc, const float* __restrict__ attn_l,
    unsigned short* __restrict__ hsb, float* __restrict__ el, int N) {
    const int r = blockIdx.y;
    const int t = threadIdx.x;
    const int w = t >> 6, l = t & 63;
    __shared__ unsigned short Blds[256 * 128];  // 64KB: full B-pack for this relation

    const unsigned short* bsrc = Bpack + (size_t)r * 256 * 128;
#pragma unroll
    for (int i = 0; i < 8; ++i) {
        int c = i * 512 + t;  // 4096 chunks of 16B
        *(uint4*)&Blds[(size_t)c * 8] = *(const uint4*)&bsrc[(size_t)c * 8];
    }
    __syncthreads();

    const int rowbase = blockIdx.x * 128 + w * 16;
    const int arow_i = rowbase + (l & 15);
    const int kg = l >> 4;
    const float* A = src + (size_t)r * N * 256;
    const float* arow = A + (size_t)(arow_i < N ? arow_i : N - 1) * 256;

    f32x4 acc[8] = {};
#pragma unroll
    for (int ks = 0; ks < 8; ++ks) {
        float4 a0 = *(const float4*)(arow + ks * 32 + kg * 8);
        float4 a1 = *(const float4*)(arow + ks * 32 + kg * 8 + 4);
        uint4 uv;
        uv.x = pk2bf(a0.x, a0.y);
        uv.y = pk2bf(a0.z, a0.w);
        uv.z = pk2bf(a1.x, a1.y);
        uv.w = pk2bf(a1.z, a1.w);
        bf16x8 av = *(bf16x8*)&uv;
#pragma unroll
        for (int cf = 0; cf < 8; ++cf) {
            bf16x8 bv = *(const bf16x8*)&Blds[((size_t)(ks * 8 + cf) * 64 + l) * 8];
            acc[cf] = __builtin_amdgcn_mfma_f32_16x16x32_bf16(av, bv, acc[cf], 0, 0, 0);
        }
    }
    float bcv[8], alv[8];
#pragma unroll
    for (int cf = 0; cf < 8; ++cf) {
        int col = cf * 16 + (l & 15);
        bcv[cf] = bc[r * 128 + col];
        alv[cf] = attn_l[r * 128 + col];
    }
#pragma unroll
    for (int i = 0; i < 4; ++i) {
        int row = rowbase + (l >> 4) * 4 + i;
        float pe = 0.f;
        unsigned short hv[8];
#pragma unroll
        for (int cf = 0; cf < 8; ++cf) {
            float v = acc[cf][i] + bcv[cf];
            pe += v * alv[cf];
            hv[cf] = f2bf(v);
        }
        if (row < N) {
            unsigned short* hp = hsb + ((size_t)r * N + row) * 128 + (l & 15);
#pragma unroll
            for (int cf = 0; cf < 8; ++cf) hp[cf * 16] = hv[cf];
        }
        pe += __shfl_xor(pe, 1, 64);
        pe += __shfl_xor(pe, 2, 64);
        pe += __shfl_xor(pe, 4, 64);
        pe += __shfl_xor(pe, 8, 64);
        if ((l & 15) == 0 && row < N) el[(size_t)r * N + row] = pe;
    }
}

// ---------------- er: er[r][n] = dst_feat[n] . u[r] + cc[r] ----------------

__global__ void er_kernel(const float* __restrict__ dst_feat, const float* __restrict__ u,
                          const float* __restrict__ cc, float* __restrict__ er, int N) {
    __shared__ float us[3][256];
    for (int i = threadIdx.x; i < 3 * 256; i += 256) us[i / 256][i & 255] = u[i];
    __syncthreads();
    int wave = threadIdx.x >> 6, lane = threadIdx.x & 63;
    int n = blockIdx.x * 4 + wave;
    if (n >= N) return;
    float4 f = *(const float4*)(dst_feat + (size_t)n * 256 + lane * 4);
#pragma unroll
    for (int r = 0; r < R_REL; ++r) {
        float4 uv = *(float4*)&us[r][lane * 4];
        float s = f.x * uv.x + f.y * uv.y + f.z * uv.z + f.w * uv.w;
#pragma unroll
        for (int off = 32; off >= 1; off >>= 1) s += __shfl_xor(s, off, 64);
        if (lane == 0) er[(size_t)r * N + n] = s + cc[r];
    }
}

// ---------------- CSR build via 2-level bucket sort ----------------

__global__ __launch_bounds__(256) void bucket_kernel(
    const int* __restrict__ si, const int* __restrict__ di,
    int* __restrict__ gcnt, unsigned* __restrict__ bbuf, int NB, int E) {
    const int r = blockIdx.y;
    const int t = threadIdx.x;
    const int e0 = blockIdx.x * 1024;
    __shared__ int cnt[128];
    __shared__ int base[128];
    if (t < 128) cnt[t] = 0;
    __syncthreads();
    int bk[4], rank[4]; unsigned pack[4]; bool val[4];
#pragma unroll
    for (int j = 0; j < 4; ++j) {
        int e = e0 + j * 256 + t;
        val[j] = e < E;
        bk[j] = 0; rank[j] = 0; pack[j] = 0;
        if (val[j]) {
            size_t g = (size_t)r * E + e;
            int s = si[g], d = di[g];
            bk[j] = d >> 9;
            pack[j] = (unsigned)s | ((unsigned)d << 16);
            rank[j] = atomicAdd(&cnt[bk[j]], 1);
        }
    }
    __syncthreads();
    if (t < NB && cnt[t] > 0) base[t] = atomicAdd(&gcnt[r * NB + t], cnt[t]);
    __syncthreads();
#pragma unroll
    for (int j = 0; j < 4; ++j) {
        if (val[j])
            bbuf[((size_t)r * NB + bk[j]) * BCAP + base[bk[j]] + rank[j]] = pack[j];
    }
}

__global__ __launch_bounds__(256) void hist_kernel(
    const unsigned* __restrict__ bbuf, const int* __restrict__ gcnt,
    int* __restrict__ deg, int NB, int N) {
    const int r = blockIdx.y;
    const int b = blockIdx.x;
    const int t = threadIdx.x;
    __shared__ int hist[NODE_CHUNK];
    for (int i = t; i < NODE_CHUNK; i += 256) hist[i] = 0;
    __syncthreads();
    const int cnt = gcnt[r * NB + b];
    const unsigned* bb = bbuf + ((size_t)r * NB + b) * BCAP;
    for (int i = t; i < cnt; i += 256) {
        int dloc = (bb[i] >> 16) & (NODE_CHUNK - 1);
        atomicAdd(&hist[dloc], 1);
    }
    __syncthreads();
    for (int i = t; i < NODE_CHUNK; i += 256) {
        int idx = b * NODE_CHUNK + i;
        if (idx < N) deg[(size_t)r * N + idx] = hist[i];
    }
}

__global__ __launch_bounds__(1024) void scan1_kernel(const int* __restrict__ deg,
                                                     int* __restrict__ offs,
                                                     int* __restrict__ btot, int N, int nchunk) {
    const int r = blockIdx.y;
    const int idx = blockIdx.x * 1024 + threadIdx.x;
    const int lane = threadIdx.x & 63, wave = threadIdx.x >> 6;
    __shared__ int wsum[16];
    int v = (idx < N) ? deg[(size_t)r * N + idx] : 0;
    int x = v;
#pragma unroll
    for (int off = 1; off < 64; off <<= 1) {
        int y = __shfl_up(x, off, 64);
        if (lane >= off) x += y;
    }
    if (lane == 63) wsum[wave] = x;
    __syncthreads();
    if (wave == 0 && lane < 16) {
        int y = wsum[lane];
#pragma unroll
        for (int off = 1; off < 16; off <<= 1) {
            int z = __shfl_up(y, off, 64);
            if (lane >= off) y += z;
        }
        wsum[lane] = y;
    }
    __syncthreads();
    int woff = (wave > 0) ? wsum[wave - 1] : 0;
    if (idx < N) offs[(size_t)r * N + idx] = woff + x - v;
    if (threadIdx.x == 1023) btot[r * nchunk + blockIdx.x] = woff + x;
}

__global__ __launch_bounds__(256) void scan2_kernel(const int* __restrict__ btot,
                                                    int* __restrict__ offs, int N, int nchunk) {
    const int r = blockIdx.y;
    const int chunk = blockIdx.x;
    const int t = threadIdx.x;
    const int lane = t & 63, wave = t >> 6;
    __shared__ int red[4];
    int pre = 0;
    for (int i = t; i < chunk; i += 256) pre += btot[r * nchunk + i];
#pragma unroll
    for (int off = 32; off >= 1; off >>= 1) pre += __shfl_xor(pre, off, 64);
    if (lane == 0) red[wave] = pre;
    __syncthreads();
    int ptot = red[0] + red[1] + red[2] + red[3];
    for (int j = t; j < 1024; j += 256) {
        int idx = chunk * 1024 + j;
        if (idx < N) offs[(size_t)r * N + idx] += ptot;
    }
}

// pass 2b: per-bucket fill; computes per-edge softmax weight p = exp(lrelu(el+er))
// and stores packed {src, p} pairs (no separate csr / no el gather in the hot gather loop)
__global__ __launch_bounds__(256) void fill2p_kernel(
    const unsigned* __restrict__ bbuf, const int* __restrict__ gcnt,
    const int* __restrict__ offs, const float* __restrict__ el, const float* __restrict__ er,
    uint2* __restrict__ epair, int NB, int N, int E) {
    const int r = blockIdx.y;
    const int b = blockIdx.x;
    const int t = threadIdx.x;
    __shared__ int curl[NODE_CHUNK];
    __shared__ float erl[NODE_CHUNK];
    for (int i = t; i < NODE_CHUNK; i += 256) {
        int idx = b * NODE_CHUNK + i;
        curl[i] = (idx < N) ? offs[(size_t)r * N + idx] : 0;
        erl[i]  = (idx < N) ? er[(size_t)r * N + idx] : 0.f;
    }
    __syncthreads();
    const int cnt = gcnt[r * NB + b];
    const unsigned* bb = bbuf + ((size_t)r * NB + b) * BCAP;
    const float* elr = el + (size_t)r * N;
    uint2* epr = epair + (size_t)r * E;
    for (int i = t; i < cnt; i += 256) {
        unsigned pk = bb[i];
        int src = pk & 0xffffu;
        int dloc = (pk >> 16) & (NODE_CHUNK - 1);
        float e = elr[src] + erl[dloc];
        e = e > 0.f ? e : 0.2f * e;
        float p = __expf(e);
        int pos = atomicAdd(&curl[dloc], 1);
        epr[pos] = make_uint2((unsigned)src, __float_as_uint(p));
    }
}

// ---------------- fused per-dst aggregation + bias + ELU -> z (bf16) ----------------
// One dst per 16-lane group; inner loop: 8B broadcast pair load -> hs row load.
// 4x unrolled: 4 independent row loads in flight per group.

__global__ __launch_bounds__(256) void gather_kernel(
    const uint2* __restrict__ epair, const int* __restrict__ offs,
    const int* __restrict__ deg, const unsigned short* __restrict__ hsb,
    const float* __restrict__ b_gat, unsigned short* __restrict__ z, int N, int E) {
    const int r = blockIdx.y;
    const int t = threadIdx.x;
    const int gid = t >> 4;
    const int gl = t & 15;
    const int d = blockIdx.x * 16 + gid;
    if (d >= N) return;
    const int beg = offs[(size_t)r * N + d];
    const int dg = deg[(size_t)r * N + d];
    float ac[8] = {0.f, 0.f, 0.f, 0.f, 0.f, 0.f, 0.f, 0.f};
    float ssum = 0.f;
    const uint2* epr = epair + (size_t)r * E;
    const unsigned short* hsr = hsb + (size_t)r * N * 128;
    int i = beg;
    const int end = beg + dg;
    for (; i + 3 < end; i += 4) {
        uint2 v0 = epr[i], v1 = epr[i + 1], v2 = epr[i + 2], v3 = epr[i + 3];
        uint4 h0 = *(const uint4*)(hsr + (size_t)v0.x * 128 + gl * 8);
        uint4 h1 = *(const uint4*)(hsr + (size_t)v1.x * 128 + gl * 8);
        uint4 h2 = *(const uint4*)(hsr + (size_t)v2.x * 128 + gl * 8);
        uint4 h3 = *(const uint4*)(hsr + (size_t)v3.x * 128 + gl * 8);
        float p0 = __uint_as_float(v0.y), p1 = __uint_as_float(v1.y);
        float p2 = __uint_as_float(v2.y), p3 = __uint_as_float(v3.y);
        ssum += p0 + p1 + p2 + p3;
        ac[0] += p0 * bf2f((unsigned short)(h0.x & 0xffffu)) + p1 * bf2f((unsigned short)(h1.x & 0xffffu))
               + p2 * bf2f((unsigned short)(h2.x & 0xffffu)) + p3 * bf2f((unsigned short)(h3.x & 0xffffu));
        ac[1] += p0 * bf2f((unsigned short)(h0.x >> 16)) + p1 * bf2f((unsigned short)(h1.x >> 16))
               + p2 * bf2f((unsigned short)(h2.x >> 16)) + p3 * bf2f((unsigned short)(h3.x >> 16));
        ac[2] += p0 * bf2f((unsigned short)(h0.y & 0xffffu)) + p1 * bf2f((unsigned short)(h1.y & 0xffffu))
               + p2 * bf2f((unsigned short)(h2.y & 0xffffu)) + p3 * bf2f((unsigned short)(h3.y & 0xffffu));
        ac[3] += p0 * bf2f((unsigned short)(h0.y >> 16)) + p1 * bf2f((unsigned short)(h1.y >> 16))
               + p2 * bf2f((unsigned short)(h2.y >> 16)) + p3 * bf2f((unsigned short)(h3.y >> 16));
        ac[4] += p0 * bf2f((unsigned short)(h0.z & 0xffffu)) + p1 * bf2f((unsigned short)(h1.z & 0xffffu))
               + p2 * bf2f((unsigned short)(h2.z & 0xffffu)) + p3 * bf2f((unsigned short)(h3.z & 0xffffu));
        ac[5] += p0 * bf2f((unsigned short)(h0.z >> 16)) + p1 * bf2f((unsigned short)(h1.z >> 16))
               + p2 * bf2f((unsigned short)(h2.z >> 16)) + p3 * bf2f((unsigned short)(h3.z >> 16));
        ac[6] += p0 * bf2f((unsigned short)(h0.w & 0xffffu)) + p1 * bf2f((unsigned short)(h1.w & 0xffffu))
               + p2 * bf2f((unsigned short)(h2.w & 0xffffu)) + p3 * bf2f((unsigned short)(h3.w & 0xffffu));
        ac[7] += p0 * bf2f((unsigned short)(h0.w >> 16)) + p1 * bf2f((unsigned short)(h1.w >> 16))
               + p2 * bf2f((unsigned short)(h2.w >> 16)) + p3 * bf2f((unsigned short)(h3.w >> 16));
    }
    for (; i < end; ++i) {
        uint2 v = epr[i];
        float p = __uint_as_float(v.y);
        ssum += p;
        uint4 hw = *(const uint4*)(hsr + (size_t)v.x * 128 + gl * 8);
        ac[0] += p * bf2f((unsigned short)(hw.x & 0xffffu));
        ac[1] += p * bf2f((unsigned short)(hw.x >> 16));
        ac[2] += p * bf2f((unsigned short)(hw.y & 0xffffu));
        ac[3] += p * bf2f((unsigned short)(hw.y >> 16));
        ac[4] += p * bf2f((unsigned short)(hw.z & 0xffffu));
        ac[5] += p * bf2f((unsigned short)(hw.z >> 16));
        ac[6] += p * bf2f((unsigned short)(hw.w & 0xffffu));
        ac[7] += p * bf2f((unsigned short)(hw.w >> 16));
    }
    float inv = (dg > 0) ? 1.f / ssum : 0.f;
    const float* bg = b_gat + r * 128 + gl * 8;
    uint4 ow;
    ow.x = pk2bf(eluf(ac[0] * inv + bg[0]), eluf(ac[1] * inv + bg[1]));
    ow.y = pk2bf(eluf(ac[2] * inv + bg[2]), eluf(ac[3] * inv + bg[3]));
    ow.z = pk2bf(eluf(ac[4] * inv + bg[4]), eluf(ac[5] * inv + bg[5]));
    ow.w = pk2bf(eluf(ac[6] * inv + bg[6]), eluf(ac[7] * inv + bg[7]));
    *(uint4*)(z + ((size_t)r * N + d) * 128 + gl * 8) = ow;
}

// ---------------- semantic attention GEMM (MFMA) -> per-block partial sums ----------------

__global__ __launch_bounds__(256) void gemm_sem(
    const unsigned short* __restrict__ z, const unsigned short* __restrict__ W1p,
    const float* __restrict__ b1, const float* __restrict__ w2,
    float* __restrict__ wpart, int N) {
    const int r = blockIdx.y;
    const int n0 = blockIdx.x * 64;
    const int t = threadIdx.x;
    const int w = t >> 6, l = t & 63;
    __shared__ unsigned short Alds[64 * 128];
    __shared__ float sred[4];
    const unsigned short* A = z + (size_t)r * N * 128;
#pragma unroll
    for (int i = 0; i < 4; ++i) {
        int cid = t + 256 * i;
        int row = cid >> 4, kc = cid & 15;
        uint4 v = make_uint4(0, 0, 0, 0);
        if (n0 + row < N) v = *(const uint4*)(A + (size_t)(n0 + row) * 128 + kc * 8);
        int off = ((row * 256) + kc * 16) ^ ((row & 7) << 4);
        *(uint4*)((char*)Alds + off) = v;
    }
    __syncthreads();

    const bf16x8* bp = (const bf16x8*)W1p;
    f32x4 acc[8] = {};
    const int arow = w * 16 + (l & 15);
#pragma unroll
    for (int ks = 0; ks < 4; ++ks) {
        int aoff = ((arow * 256) + ks * 64 + (l >> 4) * 16) ^ ((arow & 7) << 4);
        bf16x8 av = *(const bf16x8*)((char*)Alds + aoff);
#pragma unroll
        for (int cf = 0; cf < 8; ++cf) {
            bf16x8 bv = bp[(ks * 8 + cf) * 64 + l];
            acc[cf] = __builtin_amdgcn_mfma_f32_16x16x32_bf16(av, bv, acc[cf], 0, 0, 0);
        }
    }
    float b1v[8], w2v[8];
#pragma unroll
    for (int cf = 0; cf < 8; ++cf) {
        int col = cf * 16 + (l & 15);
        b1v[cf] = b1[col];
        w2v[cf] = w2[col];
    }
    float wloc = 0.f;
#pragma unroll
    for (int i = 0; i < 4; ++i) {
        int row = n0 + w * 16 + (l >> 4) * 4 + i;
        float s = 0.f;
#pragma unroll
        for (int cf = 0; cf < 8; ++cf) s += tanhf(acc[cf][i] + b1v[cf]) * w2v[cf];
        s += __shfl_xor(s, 1, 64);
        s += __shfl_xor(s, 2, 64);
        s += __shfl_xor(s, 4, 64);
        s += __shfl_xor(s, 8, 64);
        if ((l & 15) == 0 && row < N) wloc += s;
    }
    wloc += __shfl_xor(wloc, 16, 64);
    wloc += __shfl_xor(wloc, 32, 64);
    if (l == 0) sred[w] = wloc;
    __syncthreads();
    if (t == 0)
        wpart[(size_t)r * gridDim.x + blockIdx.x] = sred[0] + sred[1] + sred[2] + sred[3];
}

// ---------------- reduce partials + 3-way softmax -> aw ----------------

__global__ void reduce_sem(const float* __restrict__ wpart, float* __restrict__ aw,
                           int nblk, int N) {
    const int t = threadIdx.x, l = t & 63, w = t >> 6;
    __shared__ float sred[R_REL][4];
    float s[R_REL] = {0.f, 0.f, 0.f};
    for (int i = t; i < nblk; i += 256) {
#pragma unroll
        for (int r = 0; r < R_REL; ++r) s[r] += wpart[(size_t)r * nblk + i];
    }
#pragma unroll
    for (int r = 0; r < R_REL; ++r) {
#pragma unroll
        for (int off = 32; off >= 1; off >>= 1) s[r] += __shfl_xor(s[r], off, 64);
        if (l == 0) sred[r][w] = s[r];
    }
    __syncthreads();
    if (t == 0) {
        float w0 = (sred[0][0] + sred[0][1] + sred[0][2] + sred[0][3]) / (float)N;
        float w1 = (sred[1][0] + sred[1][1] + sred[1][2] + sred[1][3]) / (float)N;
        float w2 = (sred[2][0] + sred[2][1] + sred[2][2] + sred[2][3]) / (float)N;
        float m = fmaxf(w0, fmaxf(w1, w2));
        float e0 = __expf(w0 - m), e1 = __expf(w1 - m), e2 = __expf(w2 - m);
        float si = e0 + e1 + e2;
        aw[0] = e0 / si; aw[1] = e1 / si; aw[2] = e2 / si;
    }
}

__global__ void combine(const unsigned short* __restrict__ z, const float* __restrict__ aw,
                        float* __restrict__ out, int N) {
    int idx = blockIdx.x * 256 + threadIdx.x;
    if (idx >= N * 32) return;
    int n = idx >> 5, c4 = idx & 31;
    float a0 = aw[0], a1 = aw[1], a2 = aw[2];
    uint2 z0 = *(const uint2*)(z + ((size_t)0 * N + n) * 128 + c4 * 4);
    uint2 z1 = *(const uint2*)(z + ((size_t)1 * N + n) * 128 + c4 * 4);
    uint2 z2 = *(const uint2*)(z + ((size_t)2 * N + n) * 128 + c4 * 4);
    float4 o;
    o.x = a0 * bf2f((unsigned short)(z0.x & 0xffffu)) + a1 * bf2f((unsigned short)(z1.x & 0xffffu)) + a2 * bf2f((unsigned short)(z2.x & 0xffffu));
    o.y = a0 * bf2f((unsigned short)(z0.x >> 16))     + a1 * bf2f((unsigned short)(z1.x >> 16))     + a2 * bf2f((unsigned short)(z2.x >> 16));
    o.z = a0 * bf2f((unsigned short)(z0.y & 0xffffu)) + a1 * bf2f((unsigned short)(z1.y & 0xffffu)) + a2 * bf2f((unsigned short)(z2.y & 0xffffu));
    o.w = a0 * bf2f((unsigned short)(z0.y >> 16))     + a1 * bf2f((unsigned short)(z1.y >> 16))     + a2 * bf2f((unsigned short)(z2.y >> 16));
    *(float4*)(out + (size_t)idx * 4) = o;
}

// ---------------- launch ----------------

extern "C" void kernel_launch(void* const* d_in, const int* in_sizes, int n_in,
                              void* d_out, int out_size, void* d_ws, size_t ws_size,
                              hipStream_t stream) {
    const float* dst_feat = (const float*)d_in[0];
    const float* src_feats = (const float*)d_in[1];
    const int*   src_idx  = (const int*)d_in[2];
    const int*   dst_idx  = (const int*)d_in[3];
    const float* WT_dst   = (const float*)d_in[4];
    const float* bT_dst   = (const float*)d_in[5];
    const float* WT_src   = (const float*)d_in[6];
    const float* bT_src   = (const float*)d_in[7];
    const float* W_gat    = (const float*)d_in[8];
    const float* attn_l   = (const float*)d_in[9];
    const float* attn_r   = (const float*)d_in[10];
    const float* b_gat    = (const float*)d_in[11];
    const float* W1_sem   = (const float*)d_in[12];
    const float* b1_sem   = (const float*)d_in[13];
    const float* w2_sem   = (const float*)d_in[14];

    const int N = in_sizes[0] / 256;
    const int E = in_sizes[2] / R_REL;
    float* out = (float*)d_out;

    const int nblk = (N + 63) / 64;
    const int nblk_hs = (N + 127) / 128;
    const int nchunk = (N + 1023) / 1024;
    const int NB = (N + NODE_CHUNK - 1) / NODE_CHUNK;

    char* ws = (char*)d_ws;
    size_t off = 0;
    auto alloc = [&](size_t bytes) { char* p = ws + off; off = align_up(off + bytes, 256); return p; };
    unsigned short* hsb   = (unsigned short*)alloc((size_t)R_REL * N * 128 * 2);
    unsigned short* zbuf  = (unsigned short*)alloc((size_t)R_REL * N * 128 * 2);
    float*    Wc    = (float*)alloc((size_t)R_REL * 256 * 128 * 4);
    unsigned short* Wcp   = (unsigned short*)alloc((size_t)R_REL * 256 * 128 * 2);
    unsigned short* W1p   = (unsigned short*)alloc((size_t)128 * 128 * 2);
    float*    bc    = (float*)alloc(R_REL * 128 * 4);
    float*    u     = (float*)alloc(R_REL * 256 * 4);
    float*    cc    = (float*)alloc(R_REL * 4);
    float*    el    = (float*)alloc((size_t)R_REL * N * 4);
    float*    er    = (float*)alloc((size_t)R_REL * N * 4);
    int*      deg   = (int*)alloc((size_t)R_REL * N * 4);
    int*      offs  = (int*)alloc((size_t)R_REL * N * 4);
    int*      btot  = (int*)alloc((size_t)R_REL * nchunk * 4);
    int*      gcnt  = (int*)alloc((size_t)R_REL * NB * 4);
    unsigned* bbuf  = (unsigned*)alloc((size_t)R_REL * NB * BCAP * 4);
    uint2*    epair = (uint2*)alloc((size_t)R_REL * E * 8);
    float*    wpart = (float*)alloc((size_t)R_REL * nblk * 4);
    float*    aw    = (float*)alloc(R_REL * 4);

    hipMemsetAsync(gcnt, 0, (size_t)R_REL * NB * 4, stream);

    // weight prep
    vu_kernel<<<R_REL, 256, 0, stream>>>(W_gat, attn_r, WT_dst, bT_dst, u, cc);
    wc_kernel<<<dim3(257, R_REL), 128, 0, stream>>>(WT_src, bT_src, W_gat, Wc, bc);
    pack_kernel<<<dim3(64, R_REL), 64, 0, stream>>>(Wc, Wcp, 256 * 128, 8);
    pack_kernel<<<dim3(32, 1), 64, 0, stream>>>(W1_sem, W1p, 0, 4);

    // node projections (before fill2p, which consumes el/er)
    gemm_hs<<<dim3(nblk_hs, R_REL), 512, 0, stream>>>(src_feats, Wcp, bc, attn_l, hsb, el, N);
    er_kernel<<<(N + 3) / 4, 256, 0, stream>>>(dst_feat, u, cc, er, N);

    // CSR build (2-level bucket sort) + per-edge softmax weights
    bucket_kernel<<<dim3((E + 1023) / 1024, R_REL), 256, 0, stream>>>(src_idx, dst_idx, gcnt, bbuf, NB, E);
    hist_kernel<<<dim3(NB, R_REL), 256, 0, stream>>>(bbuf, gcnt, deg, NB, N);
    scan1_kernel<<<dim3(nchunk, R_REL), 1024, 0, stream>>>(deg, offs, btot, N, nchunk);
    scan2_kernel<<<dim3(nchunk, R_REL), 256, 0, stream>>>(btot, offs, N, nchunk);
    fill2p_kernel<<<dim3(NB, R_REL), 256, 0, stream>>>(bbuf, gcnt, offs, el, er, epair, NB, N, E);

    // fused aggregation -> z
    gather_kernel<<<dim3((N + 15) / 16, R_REL), 256, 0, stream>>>(epair, offs, deg, hsb, b_gat, zbuf, N, E);

    // semantic attention + combine
    gemm_sem<<<dim3(nblk, R_REL), 256, 0, stream>>>(zbuf, W1p, b1_sem, w2_sem, wpart, N);
    reduce_sem<<<1, 256, 0, stream>>>(wpart, aw, nblk, N);
    combine<<<(N * 32 + 255) / 256, 256, 0, stream>>>(zbuf, aw, out, N);
}

// Round 12
// 245.696 us; speedup vs baseline: 12.8061x; 1.0071x over previous
//
#include <hip/hip_runtime.h>
#include <hip/hip_bf16.h>

#define R_REL 3
#define NODE_CHUNK 512
#define BCAP 6144

typedef __attribute__((ext_vector_type(8))) short bf16x8;
typedef __attribute__((ext_vector_type(4))) float f32x4;

static inline size_t align_up(size_t x, size_t a) { return (x + a - 1) & ~(a - 1); }

__device__ __forceinline__ float eluf(float x) {
    return x > 0.f ? x : (__expf(x) - 1.f);
}
__device__ __forceinline__ unsigned short f2bf(float f) {
    __hip_bfloat16 h = __float2bfloat16(f);
    return *reinterpret_cast<unsigned short*>(&h);
}
__device__ __forceinline__ unsigned pk2bf(float lo, float hi) {
    __hip_bfloat162 h = __float22bfloat162_rn(make_float2(lo, hi));
    return *reinterpret_cast<unsigned*>(&h);
}
__device__ __forceinline__ float bf2f(unsigned short h) {
    return __uint_as_float((unsigned)h << 16);
}

// ---------------- fused v+u weight prep ----------------

__global__ void vu_kernel(const float* __restrict__ W_gat, const float* __restrict__ attn_r,
                          const float* __restrict__ WT_dst, const float* __restrict__ bT_dst,
                          float* __restrict__ u, float* __restrict__ cc) {
    int r = blockIdx.x;
    int t = threadIdx.x;
    __shared__ float ar[128];
    __shared__ float vs[128];
    if (t < 128) ar[t] = attn_r[r * 128 + t];
    __syncthreads();
    if (t < 128) {
        const float* W = W_gat + (size_t)r * 128 * 128 + (size_t)t * 128;
        float s = 0.f;
        for (int j = 0; j < 128; ++j) s += W[j] * ar[j];
        vs[t] = s;
    }
    __syncthreads();
    const float* W = WT_dst + (size_t)t * 128;
    float s = 0.f;
    for (int i = 0; i < 128; ++i) s += W[i] * vs[i];
    u[r * 256 + t] = s;
    if (t == 0) {
        float c = 0.f;
        for (int i = 0; i < 128; ++i) c += bT_dst[i] * vs[i];
        cc[r] = c;
    }
}

__global__ void wc_kernel(const float* __restrict__ WT_src, const float* __restrict__ bT_src,
                          const float* __restrict__ W_gat, float* __restrict__ Wc,
                          float* __restrict__ bc) {
    int r = blockIdx.y;
    int k = blockIdx.x;  // 0..256
    int j = threadIdx.x; // 0..127
    __shared__ float as[128];
    const float* arow = (k < 256) ? (WT_src + ((size_t)r * 256 + k) * 128)
                                  : (bT_src + (size_t)r * 128);
    as[j] = arow[j];
    __syncthreads();
    const float* W = W_gat + (size_t)r * 128 * 128;
    float s = 0.f;
    for (int i = 0; i < 128; ++i) s += as[i] * W[(size_t)i * 128 + j];
    if (k < 256) Wc[((size_t)r * 256 + k) * 128 + j] = s;
    else         bc[(size_t)r * 128 + j] = s;
}

// pack fp32 [relstride rows...][K][128] matrix into per-lane MFMA B-fragment order
__global__ void pack_kernel(const float* __restrict__ S, unsigned short* __restrict__ P,
                            int relstride, int KS) {
    int r = blockIdx.y;
    int ks = blockIdx.x >> 3, cb = blockIdx.x & 7;
    int l = threadIdx.x;
    const float* Sr = S + (size_t)r * relstride;
    int col = cb * 16 + (l & 15);
    int kb = ks * 32 + (l >> 4) * 8;
    unsigned short v[8];
#pragma unroll
    for (int j = 0; j < 8; ++j) v[j] = f2bf(Sr[(size_t)(kb + j) * 128 + col]);
    unsigned short* dst = P + ((((size_t)r * KS + ks) * 8 + cb) * 64 + l) * 8;
    *(uint4*)dst = *(uint4*)v;
}

// ---------------- hs GEMM (MFMA): B-pack in LDS, 16 waves x 256 rows (higher occupancy) ----

__global__ __launch_bounds__(1024) void gemm_hs(
    const float* __restrict__ src, const unsigned short* __restrict__ Bpack,
    const float* __restrict__ bc, const float* __restrict__ attn_l,
    unsigned short* __restrict__ hsb, float* __restrict__ el, int N) {
    const int r = blockIdx.y;
    const int t = threadIdx.x;
    const int w = t >> 6, l = t & 63;
    __shared__ unsigned short Blds[256 * 128];  // 64KB: full B-pack for this relation

    const unsigned short* bsrc = Bpack + (size_t)r * 256 * 128;
#pragma unroll
    for (int i = 0; i < 4; ++i) {
        int c = i * 1024 + t;  // 4096 chunks of 16B
        *(uint4*)&Blds[(size_t)c * 8] = *(const uint4*)&bsrc[(size_t)c * 8];
    }
    __syncthreads();

    const int rowbase = blockIdx.x * 256 + w * 16;
    const int arow_i = rowbase + (l & 15);
    const int kg = l >> 4;
    const float* A = src + (size_t)r * N * 256;
    const float* arow = A + (size_t)(arow_i < N ? arow_i : N - 1) * 256;

    f32x4 acc[8] = {};
#pragma unroll
    for (int ks = 0; ks < 8; ++ks) {
        float4 a0 = *(const float4*)(arow + ks * 32 + kg * 8);
        float4 a1 = *(const float4*)(arow + ks * 32 + kg * 8 + 4);
        uint4 uv;
        uv.x = pk2bf(a0.x, a0.y);
        uv.y = pk2bf(a0.z, a0.w);
        uv.z = pk2bf(a1.x, a1.y);
        uv.w = pk2bf(a1.z, a1.w);
        bf16x8 av = *(bf16x8*)&uv;
#pragma unroll
        for (int cf = 0; cf < 8; ++cf) {
            bf16x8 bv = *(const bf16x8*)&Blds[((size_t)(ks * 8 + cf) * 64 + l) * 8];
            acc[cf] = __builtin_amdgcn_mfma_f32_16x16x32_bf16(av, bv, acc[cf], 0, 0, 0);
        }
    }
    float bcv[8], alv[8];
#pragma unroll
    for (int cf = 0; cf < 8; ++cf) {
        int col = cf * 16 + (l & 15);
        bcv[cf] = bc[r * 128 + col];
        alv[cf] = attn_l[r * 128 + col];
    }
#pragma unroll
    for (int i = 0; i < 4; ++i) {
        int row = rowbase + (l >> 4) * 4 + i;
        float pe = 0.f;
        unsigned short hv[8];
#pragma unroll
        for (int cf = 0; cf < 8; ++cf) {
            float v = acc[cf][i] + bcv[cf];
            pe += v * alv[cf];
            hv[cf] = f2bf(v);
        }
        if (row < N) {
            unsigned short* hp = hsb + ((size_t)r * N + row) * 128 + (l & 15);
#pragma unroll
            for (int cf = 0; cf < 8; ++cf) hp[cf * 16] = hv[cf];
        }
        pe += __shfl_xor(pe, 1, 64);
        pe += __shfl_xor(pe, 2, 64);
        pe += __shfl_xor(pe, 4, 64);
        pe += __shfl_xor(pe, 8, 64);
        if ((l & 15) == 0 && row < N) el[(size_t)r * N + row] = pe;
    }
}

// ---------------- er: er[r][n] = dst_feat[n] . u[r] + cc[r] ----------------

__global__ void er_kernel(const float* __restrict__ dst_feat, const float* __restrict__ u,
                          const float* __restrict__ cc, float* __restrict__ er, int N) {
    __shared__ float us[3][256];
    for (int i = threadIdx.x; i < 3 * 256; i += 256) us[i / 256][i & 255] = u[i];
    __syncthreads();
    int wave = threadIdx.x >> 6, lane = threadIdx.x & 63;
    int n = blockIdx.x * 4 + wave;
    if (n >= N) return;
    float4 f = *(const float4*)(dst_feat + (size_t)n * 256 + lane * 4);
#pragma unroll
    for (int r = 0; r < R_REL; ++r) {
        float4 uv = *(float4*)&us[r][lane * 4];
        float s = f.x * uv.x + f.y * uv.y + f.z * uv.z + f.w * uv.w;
#pragma unroll
        for (int off = 32; off >= 1; off >>= 1) s += __shfl_xor(s, off, 64);
        if (lane == 0) er[(size_t)r * N + n] = s + cc[r];
    }
}

// ---------------- CSR build via 2-level bucket sort ----------------

__global__ __launch_bounds__(256) void bucket_kernel(
    const int* __restrict__ si, const int* __restrict__ di,
    int* __restrict__ gcnt, unsigned* __restrict__ bbuf, int NB, int E) {
    const int r = blockIdx.y;
    const int t = threadIdx.x;
    const int e0 = blockIdx.x * 1024;
    __shared__ int cnt[128];
    __shared__ int base[128];
    if (t < 128) cnt[t] = 0;
    __syncthreads();
    int bk[4], rank[4]; unsigned pack[4]; bool val[4];
#pragma unroll
    for (int j = 0; j < 4; ++j) {
        int e = e0 + j * 256 + t;
        val[j] = e < E;
        bk[j] = 0; rank[j] = 0; pack[j] = 0;
        if (val[j]) {
            size_t g = (size_t)r * E + e;
            int s = si[g], d = di[g];
            bk[j] = d >> 9;
            pack[j] = (unsigned)s | ((unsigned)d << 16);
            rank[j] = atomicAdd(&cnt[bk[j]], 1);
        }
    }
    __syncthreads();
    if (t < NB && cnt[t] > 0) base[t] = atomicAdd(&gcnt[r * NB + t], cnt[t]);
    __syncthreads();
#pragma unroll
    for (int j = 0; j < 4; ++j) {
        if (val[j])
            bbuf[((size_t)r * NB + bk[j]) * BCAP + base[bk[j]] + rank[j]] = pack[j];
    }
}

__global__ __launch_bounds__(256) void hist_kernel(
    const unsigned* __restrict__ bbuf, const int* __restrict__ gcnt,
    int* __restrict__ deg, int NB, int N) {
    const int r = blockIdx.y;
    const int b = blockIdx.x;
    const int t = threadIdx.x;
    __shared__ int hist[NODE_CHUNK];
    for (int i = t; i < NODE_CHUNK; i += 256) hist[i] = 0;
    __syncthreads();
    const int cnt = gcnt[r * NB + b];
    const unsigned* bb = bbuf + ((size_t)r * NB + b) * BCAP;
    for (int i = t; i < cnt; i += 256) {
        int dloc = (bb[i] >> 16) & (NODE_CHUNK - 1);
        atomicAdd(&hist[dloc], 1);
    }
    __syncthreads();
    for (int i = t; i < NODE_CHUNK; i += 256) {
        int idx = b * NODE_CHUNK + i;
        if (idx < N) deg[(size_t)r * N + idx] = hist[i];
    }
}

// chunk-local exclusive scan; offs stays chunk-local, btot = per-chunk totals
__global__ __launch_bounds__(1024) void scan1_kernel(const int* __restrict__ deg,
                                                     int* __restrict__ offs,
                                                     int* __restrict__ btot, int N, int nchunk) {
    const int r = blockIdx.y;
    const int idx = blockIdx.x * 1024 + threadIdx.x;
    const int lane = threadIdx.x & 63, wave = threadIdx.x >> 6;
    __shared__ int wsum[16];
    int v = (idx < N) ? deg[(size_t)r * N + idx] : 0;
    int x = v;
#pragma unroll
    for (int off = 1; off < 64; off <<= 1) {
        int y = __shfl_up(x, off, 64);
        if (lane >= off) x += y;
    }
    if (lane == 63) wsum[wave] = x;
    __syncthreads();
    if (wave == 0 && lane < 16) {
        int y = wsum[lane];
#pragma unroll
        for (int off = 1; off < 16; off <<= 1) {
            int z = __shfl_up(y, off, 64);
            if (lane >= off) y += z;
        }
        wsum[lane] = y;
    }
    __syncthreads();
    int woff = (wave > 0) ? wsum[wave - 1] : 0;
    if (idx < N) offs[(size_t)r * N + idx] = woff + x - v;
    if (threadIdx.x == 1023) btot[r * nchunk + blockIdx.x] = woff + x;
}

// tiny: exclusive-scan btot -> cpre (per relation), serial per thread (nchunk ~49)
__global__ void cscan_kernel(const int* __restrict__ btot, int* __restrict__ cpre, int nchunk) {
    int r = threadIdx.x;
    if (r >= R_REL) return;
    int acc = 0;
    for (int i = 0; i < nchunk; ++i) {
        cpre[r * nchunk + i] = acc;
        acc += btot[r * nchunk + i];
    }
}

// pass 2b: per-bucket fill; computes per-edge softmax weight p = exp(lrelu(el+er))
// bucket b lies entirely inside chunk b>>1 (512 | 1024) -> one cpre per bucket
__global__ __launch_bounds__(256) void fill2p_kernel(
    const unsigned* __restrict__ bbuf, const int* __restrict__ gcnt,
    const int* __restrict__ offs, const int* __restrict__ cpre,
    const float* __restrict__ el, const float* __restrict__ er,
    uint2* __restrict__ epair, int NB, int nchunk, int N, int E) {
    const int r = blockIdx.y;
    const int b = blockIdx.x;
    const int t = threadIdx.x;
    __shared__ int curl[NODE_CHUNK];
    __shared__ float erl[NODE_CHUNK];
    const int cp = cpre[r * nchunk + (b >> 1)];
    for (int i = t; i < NODE_CHUNK; i += 256) {
        int idx = b * NODE_CHUNK + i;
        curl[i] = (idx < N) ? offs[(size_t)r * N + idx] + cp : 0;
        erl[i]  = (idx < N) ? er[(size_t)r * N + idx] : 0.f;
    }
    __syncthreads();
    const int cnt = gcnt[r * NB + b];
    const unsigned* bb = bbuf + ((size_t)r * NB + b) * BCAP;
    const float* elr = el + (size_t)r * N;
    uint2* epr = epair + (size_t)r * E;
    for (int i = t; i < cnt; i += 256) {
        unsigned pk = bb[i];
        int src = pk & 0xffffu;
        int dloc = (pk >> 16) & (NODE_CHUNK - 1);
        float e = elr[src] + erl[dloc];
        e = e > 0.f ? e : 0.2f * e;
        float p = __expf(e);
        int pos = atomicAdd(&curl[dloc], 1);
        epr[pos] = make_uint2((unsigned)src, __float_as_uint(p));
    }
}

// ---------------- fused per-dst aggregation + bias + ELU -> z (bf16) ----------------

__global__ __launch_bounds__(256) void gather_kernel(
    const uint2* __restrict__ epair, const int* __restrict__ offs,
    const int* __restrict__ cpre, const int* __restrict__ deg,
    const unsigned short* __restrict__ hsb, const float* __restrict__ b_gat,
    unsigned short* __restrict__ z, int N, int E, int nchunk) {
    const int r = blockIdx.y;
    const int t = threadIdx.x;
    const int gid = t >> 4;
    const int gl = t & 15;
    const int d = blockIdx.x * 16 + gid;
    if (d >= N) return;
    const int beg = offs[(size_t)r * N + d] + cpre[r * nchunk + (d >> 10)];
    const int dg = deg[(size_t)r * N + d];
    float ac[8] = {0.f, 0.f, 0.f, 0.f, 0.f, 0.f, 0.f, 0.f};
    float ssum = 0.f;
    const uint2* epr = epair + (size_t)r * E;
    const unsigned short* hsr = hsb + (size_t)r * N * 128;
    int i = beg;
    const int end = beg + dg;
    for (; i + 3 < end; i += 4) {
        uint2 v0 = epr[i], v1 = epr[i + 1], v2 = epr[i + 2], v3 = epr[i + 3];
        uint4 h0 = *(const uint4*)(hsr + (size_t)v0.x * 128 + gl * 8);
        uint4 h1 = *(const uint4*)(hsr + (size_t)v1.x * 128 + gl * 8);
        uint4 h2 = *(const uint4*)(hsr + (size_t)v2.x * 128 + gl * 8);
        uint4 h3 = *(const uint4*)(hsr + (size_t)v3.x * 128 + gl * 8);
        float p0 = __uint_as_float(v0.y), p1 = __uint_as_float(v1.y);
        float p2 = __uint_as_float(v2.y), p3 = __uint_as_float(v3.y);
        ssum += p0 + p1 + p2 + p3;
        ac[0] += p0 * bf2f((unsigned short)(h0.x & 0xffffu)) + p1 * bf2f((unsigned short)(h1.x & 0xffffu))
               + p2 * bf2f((unsigned short)(h2.x & 0xffffu)) + p3 * bf2f((unsigned short)(h3.x & 0xffffu));
        ac[1] += p0 * bf2f((unsigned short)(h0.x >> 16)) + p1 * bf2f((unsigned short)(h1.x >> 16))
               + p2 * bf2f((unsigned short)(h2.x >> 16)) + p3 * bf2f((unsigned short)(h3.x >> 16));
        ac[2] += p0 * bf2f((unsigned short)(h0.y & 0xffffu)) + p1 * bf2f((unsigned short)(h1.y & 0xffffu))
               + p2 * bf2f((unsigned short)(h2.y & 0xffffu)) + p3 * bf2f((unsigned short)(h3.y & 0xffffu));
        ac[3] += p0 * bf2f((unsigned short)(h0.y >> 16)) + p1 * bf2f((unsigned short)(h1.y >> 16))
               + p2 * bf2f((unsigned short)(h2.y >> 16)) + p3 * bf2f((unsigned short)(h3.y >> 16));
        ac[4] += p0 * bf2f((unsigned short)(h0.z & 0xffffu)) + p1 * bf2f((unsigned short)(h1.z & 0xffffu))
               + p2 * bf2f((unsigned short)(h2.z & 0xffffu)) + p3 * bf2f((unsigned short)(h3.z & 0xffffu));
        ac[5] += p0 * bf2f((unsigned short)(h0.z >> 16)) + p1 * bf2f((unsigned short)(h1.z >> 16))
               + p2 * bf2f((unsigned short)(h2.z >> 16)) + p3 * bf2f((unsigned short)(h3.z >> 16));
        ac[6] += p0 * bf2f((unsigned short)(h0.w & 0xffffu)) + p1 * bf2f((unsigned short)(h1.w & 0xffffu))
               + p2 * bf2f((unsigned short)(h2.w & 0xffffu)) + p3 * bf2f((unsigned short)(h3.w & 0xffffu));
        ac[7] += p0 * bf2f((unsigned short)(h0.w >> 16)) + p1 * bf2f((unsigned short)(h1.w >> 16))
               + p2 * bf2f((unsigned short)(h2.w >> 16)) + p3 * bf2f((unsigned short)(h3.w >> 16));
    }
    for (; i < end; ++i) {
        uint2 v = epr[i];
        float p = __uint_as_float(v.y);
        ssum += p;
        uint4 hw = *(const uint4*)(hsr + (size_t)v.x * 128 + gl * 8);
        ac[0] += p * bf2f((unsigned short)(hw.x & 0xffffu));
        ac[1] += p * bf2f((unsigned short)(hw.x >> 16));
        ac[2] += p * bf2f((unsigned short)(hw.y & 0xffffu));
        ac[3] += p * bf2f((unsigned short)(hw.y >> 16));
        ac[4] += p * bf2f((unsigned short)(hw.z & 0xffffu));
        ac[5] += p * bf2f((unsigned short)(hw.z >> 16));
        ac[6] += p * bf2f((unsigned short)(hw.w & 0xffffu));
        ac[7] += p * bf2f((unsigned short)(hw.w >> 16));
    }
    float inv = (dg > 0) ? 1.f / ssum : 0.f;
    const float* bg = b_gat + r * 128 + gl * 8;
    uint4 ow;
    ow.x = pk2bf(eluf(ac[0] * inv + bg[0]), eluf(ac[1] * inv + bg[1]));
    ow.y = pk2bf(eluf(ac[2] * inv + bg[2]), eluf(ac[3] * inv + bg[3]));
    ow.z = pk2bf(eluf(ac[4] * inv + bg[4]), eluf(ac[5] * inv + bg[5]));
    ow.w = pk2bf(eluf(ac[6] * inv + bg[6]), eluf(ac[7] * inv + bg[7]));
    *(uint4*)(z + ((size_t)r * N + d) * 128 + gl * 8) = ow;
}

// ---------------- semantic attention GEMM (MFMA) -> per-block partial sums ----------------

__global__ __launch_bounds__(256) void gemm_sem(
    const unsigned short* __restrict__ z, const unsigned short* __restrict__ W1p,
    const float* __restrict__ b1, const float* __restrict__ w2,
    float* __restrict__ wpart, int N) {
    const int r = blockIdx.y;
    const int n0 = blockIdx.x * 64;
    const int t = threadIdx.x;
    const int w = t >> 6, l = t & 63;
    __shared__ unsigned short Alds[64 * 128];
    __shared__ float sred[4];
    const unsigned short* A = z + (size_t)r * N * 128;
#pragma unroll
    for (int i = 0; i < 4; ++i) {
        int cid = t + 256 * i;
        int row = cid >> 4, kc = cid & 15;
        uint4 v = make_uint4(0, 0, 0, 0);
        if (n0 + row < N) v = *(const uint4*)(A + (size_t)(n0 + row) * 128 + kc * 8);
        int off = ((row * 256) + kc * 16) ^ ((row & 7) << 4);
        *(uint4*)((char*)Alds + off) = v;
    }
    __syncthreads();

    const bf16x8* bp = (const bf16x8*)W1p;
    f32x4 acc[8] = {};
    const int arow = w * 16 + (l & 15);
#pragma unroll
    for (int ks = 0; ks < 4; ++ks) {
        int aoff = ((arow * 256) + ks * 64 + (l >> 4) * 16) ^ ((arow & 7) << 4);
        bf16x8 av = *(const bf16x8*)((char*)Alds + aoff);
#pragma unroll
        for (int cf = 0; cf < 8; ++cf) {
            bf16x8 bv = bp[(ks * 8 + cf) * 64 + l];
            acc[cf] = __builtin_amdgcn_mfma_f32_16x16x32_bf16(av, bv, acc[cf], 0, 0, 0);
        }
    }
    float b1v[8], w2v[8];
#pragma unroll
    for (int cf = 0; cf < 8; ++cf) {
        int col = cf * 16 + (l & 15);
        b1v[cf] = b1[col];
        w2v[cf] = w2[col];
    }
    float wloc = 0.f;
#pragma unroll
    for (int i = 0; i < 4; ++i) {
        int row = n0 + w * 16 + (l >> 4) * 4 + i;
        float s = 0.f;
#pragma unroll
        for (int cf = 0; cf < 8; ++cf) s += tanhf(acc[cf][i] + b1v[cf]) * w2v[cf];
        s += __shfl_xor(s, 1, 64);
        s += __shfl_xor(s, 2, 64);
        s += __shfl_xor(s, 4, 64);
        s += __shfl_xor(s, 8, 64);
        if ((l & 15) == 0 && row < N) wloc += s;
    }
    wloc += __shfl_xor(wloc, 16, 64);
    wloc += __shfl_xor(wloc, 32, 64);
    if (l == 0) sred[w] = wloc;
    __syncthreads();
    if (t == 0)
        wpart[(size_t)r * gridDim.x + blockIdx.x] = sred[0] + sred[1] + sred[2] + sred[3];
}

// ---------------- reduce partials + 3-way softmax -> aw ----------------

__global__ void reduce_sem(const float* __restrict__ wpart, float* __restrict__ aw,
                           int nblk, int N) {
    const int t = threadIdx.x, l = t & 63, w = t >> 6;
    __shared__ float sred[R_REL][4];
    float s[R_REL] = {0.f, 0.f, 0.f};
    for (int i = t; i < nblk; i += 256) {
#pragma unroll
        for (int r = 0; r < R_REL; ++r) s[r] += wpart[(size_t)r * nblk + i];
    }
#pragma unroll
    for (int r = 0; r < R_REL; ++r) {
#pragma unroll
        for (int off = 32; off >= 1; off >>= 1) s[r] += __shfl_xor(s[r], off, 64);
        if (l == 0) sred[r][w] = s[r];
    }
    __syncthreads();
    if (t == 0) {
        float w0 = (sred[0][0] + sred[0][1] + sred[0][2] + sred[0][3]) / (float)N;
        float w1 = (sred[1][0] + sred[1][1] + sred[1][2] + sred[1][3]) / (float)N;
        float w2 = (sred[2][0] + sred[2][1] + sred[2][2] + sred[2][3]) / (float)N;
        float m = fmaxf(w0, fmaxf(w1, w2));
        float e0 = __expf(w0 - m), e1 = __expf(w1 - m), e2 = __expf(w2 - m);
        float si = e0 + e1 + e2;
        aw[0] = e0 / si; aw[1] = e1 / si; aw[2] = e2 / si;
    }
}

__global__ void combine(const unsigned short* __restrict__ z, const float* __restrict__ aw,
                        float* __restrict__ out, int N) {
    int idx = blockIdx.x * 256 + threadIdx.x;
    if (idx >= N * 32) return;
    int n = idx >> 5, c4 = idx & 31;
    float a0 = aw[0], a1 = aw[1], a2 = aw[2];
    uint2 z0 = *(const uint2*)(z + ((size_t)0 * N + n) * 128 + c4 * 4);
    uint2 z1 = *(const uint2*)(z + ((size_t)1 * N + n) * 128 + c4 * 4);
    uint2 z2 = *(const uint2*)(z + ((size_t)2 * N + n) * 128 + c4 * 4);
    float4 o;
    o.x = a0 * bf2f((unsigned short)(z0.x & 0xffffu)) + a1 * bf2f((unsigned short)(z1.x & 0xffffu)) + a2 * bf2f((unsigned short)(z2.x & 0xffffu));
    o.y = a0 * bf2f((unsigned short)(z0.x >> 16))     + a1 * bf2f((unsigned short)(z1.x >> 16))     + a2 * bf2f((unsigned short)(z2.x >> 16));
    o.z = a0 * bf2f((unsigned short)(z0.y & 0xffffu)) + a1 * bf2f((unsigned short)(z1.y & 0xffffu)) + a2 * bf2f((unsigned short)(z2.y & 0xffffu));
    o.w = a0 * bf2f((unsigned short)(z0.y >> 16))     + a1 * bf2f((unsigned short)(z1.y >> 16))     + a2 * bf2f((unsigned short)(z2.y >> 16));
    *(float4*)(out + (size_t)idx * 4) = o;
}

// ---------------- launch ----------------

extern "C" void kernel_launch(void* const* d_in, const int* in_sizes, int n_in,
                              void* d_out, int out_size, void* d_ws, size_t ws_size,
                              hipStream_t stream) {
    const float* dst_feat = (const float*)d_in[0];
    const float* src_feats = (const float*)d_in[1];
    const int*   src_idx  = (const int*)d_in[2];
    const int*   dst_idx  = (const int*)d_in[3];
    const float* WT_dst   = (const float*)d_in[4];
    const float* bT_dst   = (const float*)d_in[5];
    const float* WT_src   = (const float*)d_in[6];
    const float* bT_src   = (const float*)d_in[7];
    const float* W_gat    = (const float*)d_in[8];
    const float* attn_l   = (const float*)d_in[9];
    const float* attn_r   = (const float*)d_in[10];
    const float* b_gat    = (const float*)d_in[11];
    const float* W1_sem   = (const float*)d_in[12];
    const float* b1_sem   = (const float*)d_in[13];
    const float* w2_sem   = (const float*)d_in[14];

    const int N = in_sizes[0] / 256;
    const int E = in_sizes[2] / R_REL;
    float* out = (float*)d_out;

    const int nblk = (N + 63) / 64;
    const int nblk_hs = (N + 255) / 256;
    const int nchunk = (N + 1023) / 1024;
    const int NB = (N + NODE_CHUNK - 1) / NODE_CHUNK;

    char* ws = (char*)d_ws;
    size_t off = 0;
    auto alloc = [&](size_t bytes) { char* p = ws + off; off = align_up(off + bytes, 256); return p; };
    unsigned short* hsb   = (unsigned short*)alloc((size_t)R_REL * N * 128 * 2);
    unsigned short* zbuf  = (unsigned short*)alloc((size_t)R_REL * N * 128 * 2);
    float*    Wc    = (float*)alloc((size_t)R_REL * 256 * 128 * 4);
    unsigned short* Wcp   = (unsigned short*)alloc((size_t)R_REL * 256 * 128 * 2);
    unsigned short* W1p   = (unsigned short*)alloc((size_t)128 * 128 * 2);
    float*    bc    = (float*)alloc(R_REL * 128 * 4);
    float*    u     = (float*)alloc(R_REL * 256 * 4);
    float*    cc    = (float*)alloc(R_REL * 4);
    float*    el    = (float*)alloc((size_t)R_REL * N * 4);
    float*    er    = (float*)alloc((size_t)R_REL * N * 4);
    int*      deg   = (int*)alloc((size_t)R_REL * N * 4);
    int*      offs  = (int*)alloc((size_t)R_REL * N * 4);
    int*      btot  = (int*)alloc((size_t)R_REL * nchunk * 4);
    int*      cpre  = (int*)alloc((size_t)R_REL * nchunk * 4);
    int*      gcnt  = (int*)alloc((size_t)R_REL * NB * 4);
    unsigned* bbuf  = (unsigned*)alloc((size_t)R_REL * NB * BCAP * 4);
    uint2*    epair = (uint2*)alloc((size_t)R_REL * E * 8);
    float*    wpart = (float*)alloc((size_t)R_REL * nblk * 4);
    float*    aw    = (float*)alloc(R_REL * 4);

    hipMemsetAsync(gcnt, 0, (size_t)R_REL * NB * 4, stream);

    // weight prep
    vu_kernel<<<R_REL, 256, 0, stream>>>(W_gat, attn_r, WT_dst, bT_dst, u, cc);
    wc_kernel<<<dim3(257, R_REL), 128, 0, stream>>>(WT_src, bT_src, W_gat, Wc, bc);
    pack_kernel<<<dim3(64, R_REL), 64, 0, stream>>>(Wc, Wcp, 256 * 128, 8);
    pack_kernel<<<dim3(32, 1), 64, 0, stream>>>(W1_sem, W1p, 0, 4);

    // node projections (before fill2p, which consumes el/er)
    gemm_hs<<<dim3(nblk_hs, R_REL), 1024, 0, stream>>>(src_feats, Wcp, bc, attn_l, hsb, el, N);
    er_kernel<<<(N + 3) / 4, 256, 0, stream>>>(dst_feat, u, cc, er, N);

    // CSR build (2-level bucket sort) + per-edge softmax weights
    bucket_kernel<<<dim3((E + 1023) / 1024, R_REL), 256, 0, stream>>>(src_idx, dst_idx, gcnt, bbuf, NB, E);
    hist_kernel<<<dim3(NB, R_REL), 256, 0, stream>>>(bbuf, gcnt, deg, NB, N);
    scan1_kernel<<<dim3(nchunk, R_REL), 1024, 0, stream>>>(deg, offs, btot, N, nchunk);
    cscan_kernel<<<1, 64, 0, stream>>>(btot, cpre, nchunk);
    fill2p_kernel<<<dim3(NB, R_REL), 256, 0, stream>>>(bbuf, gcnt, offs, cpre, el, er, epair, NB, nchunk, N, E);

    // fused aggregation -> z
    gather_kernel<<<dim3((N + 15) / 16, R_REL), 256, 0, stream>>>(epair, offs, cpre, deg, hsb, b_gat, zbuf, N, E, nchunk);

    // semantic attention + combine
    gemm_sem<<<dim3(nblk, R_REL), 256, 0, stream>>>(zbuf, W1p, b1_sem, w2_sem, wpart, N);
    reduce_sem<<<1, 256, 0, stream>>>(wpart, aw, nblk, N);
    combine<<<(N * 32 + 255) / 256, 256, 0, stream>>>(zbuf, aw, out, N);
}

// Round 13
// 244.298 us; speedup vs baseline: 12.8794x; 1.0057x over previous
//
#include <hip/hip_runtime.h>
#include <hip/hip_bf16.h>

#define R_REL 3
#define NODE_CHUNK 512
#define BCAP 6144

typedef __attribute__((ext_vector_type(8))) short bf16x8;
typedef __attribute__((ext_vector_type(4))) float f32x4;

static inline size_t align_up(size_t x, size_t a) { return (x + a - 1) & ~(a - 1); }

__device__ __forceinline__ float eluf(float x) {
    return x > 0.f ? x : (__expf(x) - 1.f);
}
__device__ __forceinline__ unsigned short f2bf(float f) {
    __hip_bfloat16 h = __float2bfloat16(f);
    return *reinterpret_cast<unsigned short*>(&h);
}
__device__ __forceinline__ unsigned pk2bf(float lo, float hi) {
    __hip_bfloat162 h = __float22bfloat162_rn(make_float2(lo, hi));
    return *reinterpret_cast<unsigned*>(&h);
}
__device__ __forceinline__ float bf2f(unsigned short h) {
    return __uint_as_float((unsigned)h << 16);
}

// ---------------- fused v+u weight prep ----------------

__global__ void vu_kernel(const float* __restrict__ W_gat, const float* __restrict__ attn_r,
                          const float* __restrict__ WT_dst, const float* __restrict__ bT_dst,
                          float* __restrict__ u, float* __restrict__ cc) {
    int r = blockIdx.x;
    int t = threadIdx.x;
    __shared__ float ar[128];
    __shared__ float vs[128];
    if (t < 128) ar[t] = attn_r[r * 128 + t];
    __syncthreads();
    if (t < 128) {
        const float* W = W_gat + (size_t)r * 128 * 128 + (size_t)t * 128;
        float s = 0.f;
        for (int j = 0; j < 128; ++j) s += W[j] * ar[j];
        vs[t] = s;
    }
    __syncthreads();
    const float* W = WT_dst + (size_t)t * 128;
    float s = 0.f;
    for (int i = 0; i < 128; ++i) s += W[i] * vs[i];
    u[r * 256 + t] = s;
    if (t == 0) {
        float c = 0.f;
        for (int i = 0; i < 128; ++i) c += bT_dst[i] * vs[i];
        cc[r] = c;
    }
}

__global__ void wc_kernel(const float* __restrict__ WT_src, const float* __restrict__ bT_src,
                          const float* __restrict__ W_gat, float* __restrict__ Wc,
                          float* __restrict__ bc) {
    int r = blockIdx.y;
    int k = blockIdx.x;  // 0..256
    int j = threadIdx.x; // 0..127
    __shared__ float as[128];
    const float* arow = (k < 256) ? (WT_src + ((size_t)r * 256 + k) * 128)
                                  : (bT_src + (size_t)r * 128);
    as[j] = arow[j];
    __syncthreads();
    const float* W = W_gat + (size_t)r * 128 * 128;
    float s = 0.f;
    for (int i = 0; i < 128; ++i) s += as[i] * W[(size_t)i * 128 + j];
    if (k < 256) Wc[((size_t)r * 256 + k) * 128 + j] = s;
    else         bc[(size_t)r * 128 + j] = s;
}

// pack fp32 [relstride rows...][K][128] matrix into per-lane MFMA B-fragment order
__global__ void pack_kernel(const float* __restrict__ S, unsigned short* __restrict__ P,
                            int relstride, int KS) {
    int r = blockIdx.y;
    int ks = blockIdx.x >> 3, cb = blockIdx.x & 7;
    int l = threadIdx.x;
    const float* Sr = S + (size_t)r * relstride;
    int col = cb * 16 + (l & 15);
    int kb = ks * 32 + (l >> 4) * 8;
    unsigned short v[8];
#pragma unroll
    for (int j = 0; j < 8; ++j) v[j] = f2bf(Sr[(size_t)(kb + j) * 128 + col]);
    unsigned short* dst = P + ((((size_t)r * KS + ks) * 8 + cb) * 64 + l) * 8;
    *(uint4*)dst = *(uint4*)v;
}

// ---------------- hs GEMM (MFMA): B-pack in LDS, 16 waves x 256 rows ----------------

__global__ __launch_bounds__(1024) void gemm_hs(
    const float* __restrict__ src, const unsigned short* __restrict__ Bpack,
    const float* __restrict__ bc, const float* __restrict__ attn_l,
    unsigned short* __restrict__ hsb, float* __restrict__ el, int N) {
    const int r = blockIdx.y;
    const int t = threadIdx.x;
    const int w = t >> 6, l = t & 63;
    __shared__ unsigned short Blds[256 * 128];  // 64KB

    const unsigned short* bsrc = Bpack + (size_t)r * 256 * 128;
#pragma unroll
    for (int i = 0; i < 4; ++i) {
        int c = i * 1024 + t;
        *(uint4*)&Blds[(size_t)c * 8] = *(const uint4*)&bsrc[(size_t)c * 8];
    }
    __syncthreads();

    const int rowbase = blockIdx.x * 256 + w * 16;
    const int arow_i = rowbase + (l & 15);
    const int kg = l >> 4;
    const float* A = src + (size_t)r * N * 256;
    const float* arow = A + (size_t)(arow_i < N ? arow_i : N - 1) * 256;

    f32x4 acc[8] = {};
#pragma unroll
    for (int ks = 0; ks < 8; ++ks) {
        float4 a0 = *(const float4*)(arow + ks * 32 + kg * 8);
        float4 a1 = *(const float4*)(arow + ks * 32 + kg * 8 + 4);
        uint4 uv;
        uv.x = pk2bf(a0.x, a0.y);
        uv.y = pk2bf(a0.z, a0.w);
        uv.z = pk2bf(a1.x, a1.y);
        uv.w = pk2bf(a1.z, a1.w);
        bf16x8 av = *(bf16x8*)&uv;
#pragma unroll
        for (int cf = 0; cf < 8; ++cf) {
            bf16x8 bv = *(const bf16x8*)&Blds[((size_t)(ks * 8 + cf) * 64 + l) * 8];
            acc[cf] = __builtin_amdgcn_mfma_f32_16x16x32_bf16(av, bv, acc[cf], 0, 0, 0);
        }
    }
    float bcv[8], alv[8];
#pragma unroll
    for (int cf = 0; cf < 8; ++cf) {
        int col = cf * 16 + (l & 15);
        bcv[cf] = bc[r * 128 + col];
        alv[cf] = attn_l[r * 128 + col];
    }
#pragma unroll
    for (int i = 0; i < 4; ++i) {
        int row = rowbase + (l >> 4) * 4 + i;
        float pe = 0.f;
        unsigned short hv[8];
#pragma unroll
        for (int cf = 0; cf < 8; ++cf) {
            float v = acc[cf][i] + bcv[cf];
            pe += v * alv[cf];
            hv[cf] = f2bf(v);
        }
        if (row < N) {
            unsigned short* hp = hsb + ((size_t)r * N + row) * 128 + (l & 15);
#pragma unroll
            for (int cf = 0; cf < 8; ++cf) hp[cf * 16] = hv[cf];
        }
        pe += __shfl_xor(pe, 1, 64);
        pe += __shfl_xor(pe, 2, 64);
        pe += __shfl_xor(pe, 4, 64);
        pe += __shfl_xor(pe, 8, 64);
        if ((l & 15) == 0 && row < N) el[(size_t)r * N + row] = pe;
    }
}

// ---------------- er: er[r][n] = dst_feat[n] . u[r] + cc[r] ----------------

__global__ void er_kernel(const float* __restrict__ dst_feat, const float* __restrict__ u,
                          const float* __restrict__ cc, float* __restrict__ er, int N) {
    __shared__ float us[3][256];
    for (int i = threadIdx.x; i < 3 * 256; i += 256) us[i / 256][i & 255] = u[i];
    __syncthreads();
    int wave = threadIdx.x >> 6, lane = threadIdx.x & 63;
    int n = blockIdx.x * 4 + wave;
    if (n >= N) return;
    float4 f = *(const float4*)(dst_feat + (size_t)n * 256 + lane * 4);
#pragma unroll
    for (int r = 0; r < R_REL; ++r) {
        float4 uv = *(float4*)&us[r][lane * 4];
        float s = f.x * uv.x + f.y * uv.y + f.z * uv.z + f.w * uv.w;
#pragma unroll
        for (int off = 32; off >= 1; off >>= 1) s += __shfl_xor(s, off, 64);
        if (lane == 0) er[(size_t)r * N + n] = s + cc[r];
    }
}

// ---------------- CSR build via 2-level bucket sort ----------------

__global__ __launch_bounds__(256) void bucket_kernel(
    const int* __restrict__ si, const int* __restrict__ di,
    int* __restrict__ gcnt, unsigned* __restrict__ bbuf, int NB, int E) {
    const int r = blockIdx.y;
    const int t = threadIdx.x;
    const int e0 = blockIdx.x * 1024;
    __shared__ int cnt[128];
    __shared__ int base[128];
    if (t < 128) cnt[t] = 0;
    __syncthreads();
    int bk[4], rank[4]; unsigned pack[4]; bool val[4];
#pragma unroll
    for (int j = 0; j < 4; ++j) {
        int e = e0 + j * 256 + t;
        val[j] = e < E;
        bk[j] = 0; rank[j] = 0; pack[j] = 0;
        if (val[j]) {
            size_t g = (size_t)r * E + e;
            int s = si[g], d = di[g];
            bk[j] = d >> 9;
            pack[j] = (unsigned)s | ((unsigned)d << 16);
            rank[j] = atomicAdd(&cnt[bk[j]], 1);
        }
    }
    __syncthreads();
    if (t < NB && cnt[t] > 0) base[t] = atomicAdd(&gcnt[r * NB + t], cnt[t]);
    __syncthreads();
#pragma unroll
    for (int j = 0; j < 4; ++j) {
        if (val[j])
            bbuf[((size_t)r * NB + bk[j]) * BCAP + base[bk[j]] + rank[j]] = pack[j];
    }
}

// tiny: exclusive-scan gcnt -> bbase (per relation), serial (NB ~98)
__global__ void bscan_kernel(const int* __restrict__ gcnt, int* __restrict__ bbase, int NB) {
    int r = threadIdx.x;
    if (r >= R_REL) return;
    int acc = 0;
    for (int i = 0; i < NB; ++i) {
        bbase[r * NB + i] = acc;
        acc += gcnt[r * NB + i];
    }
}

// fused per-bucket: LDS histogram -> LDS excl scan -> write offs/deg (absolute, coalesced)
// -> place edges with LDS cursors + per-edge softmax weight p = exp(lrelu(el+er))
__global__ __launch_bounds__(256) void fill3_kernel(
    const unsigned* __restrict__ bbuf, const int* __restrict__ gcnt,
    const int* __restrict__ bbase, const float* __restrict__ el, const float* __restrict__ er,
    int* __restrict__ offs, int* __restrict__ deg, uint2* __restrict__ epair,
    int NB, int N, int E) {
    const int r = blockIdx.y;
    const int b = blockIdx.x;
    const int t = threadIdx.x;
    const int lane = t & 63, wave = t >> 6;
    __shared__ int hist[NODE_CHUNK];
    __shared__ int curl[NODE_CHUNK];
    __shared__ float erl[NODE_CHUNK];
    __shared__ int wsum[4];
    __shared__ int wpre[4];

    for (int i = t; i < NODE_CHUNK; i += 256) hist[i] = 0;
    {
        int idx0 = b * NODE_CHUNK + t;
        int idx1 = idx0 + 256;
        erl[t]       = (idx0 < N) ? er[(size_t)r * N + idx0] : 0.f;
        erl[t + 256] = (idx1 < N) ? er[(size_t)r * N + idx1] : 0.f;
    }
    __syncthreads();

    const int cnt = gcnt[r * NB + b];
    const int bb0 = bbase[r * NB + b];
    const unsigned* bb = bbuf + ((size_t)r * NB + b) * BCAP;

    // pass 1: histogram
    for (int i = t; i < cnt; i += 256) {
        int dloc = (bb[i] >> 16) & (NODE_CHUNK - 1);
        atomicAdd(&hist[dloc], 1);
    }
    __syncthreads();

    // excl scan of hist[512] -> curl (each thread owns elems 2t, 2t+1)
    int a0 = hist[2 * t], a1 = hist[2 * t + 1];
    int s = a0 + a1;
    int x = s;
#pragma unroll
    for (int off = 1; off < 64; off <<= 1) {
        int y = __shfl_up(x, off, 64);
        if (lane >= off) x += y;
    }
    if (lane == 63) wsum[wave] = x;
    __syncthreads();
    if (t == 0) {
        int acc = 0;
#pragma unroll
        for (int w2 = 0; w2 < 4; ++w2) { wpre[w2] = acc; acc += wsum[w2]; }
    }
    __syncthreads();
    int excl = wpre[wave] + x - s;
    curl[2 * t] = excl;
    curl[2 * t + 1] = excl + a0;
    // write absolute offs/deg (coalesced pairs)
    {
        int idx0 = b * NODE_CHUNK + 2 * t;
        if (idx0 < N) { offs[(size_t)r * N + idx0] = bb0 + excl; deg[(size_t)r * N + idx0] = a0; }
        int idx1 = idx0 + 1;
        if (idx1 < N) { offs[(size_t)r * N + idx1] = bb0 + excl + a0; deg[(size_t)r * N + idx1] = a1; }
    }
    __syncthreads();

    // pass 2: place edges + weights
    const float* elr = el + (size_t)r * N;
    uint2* epr = epair + (size_t)r * E;
    for (int i = t; i < cnt; i += 256) {
        unsigned pk = bb[i];
        int src = pk & 0xffffu;
        int dloc = (pk >> 16) & (NODE_CHUNK - 1);
        float e = elr[src] + erl[dloc];
        e = e > 0.f ? e : 0.2f * e;
        float p = __expf(e);
        int pos = bb0 + atomicAdd(&curl[dloc], 1);
        epr[pos] = make_uint2((unsigned)src, __float_as_uint(p));
    }
}

// ---------------- fused per-dst aggregation + bias + ELU -> z (bf16) ----------------

__global__ __launch_bounds__(256) void gather_kernel(
    const uint2* __restrict__ epair, const int* __restrict__ offs,
    const int* __restrict__ deg, const unsigned short* __restrict__ hsb,
    const float* __restrict__ b_gat, unsigned short* __restrict__ z, int N, int E) {
    const int r = blockIdx.y;
    const int t = threadIdx.x;
    const int gid = t >> 4;
    const int gl = t & 15;
    const int d = blockIdx.x * 16 + gid;
    if (d >= N) return;
    const int beg = offs[(size_t)r * N + d];
    const int dg = deg[(size_t)r * N + d];
    float ac[8] = {0.f, 0.f, 0.f, 0.f, 0.f, 0.f, 0.f, 0.f};
    float ssum = 0.f;
    const uint2* epr = epair + (size_t)r * E;
    const unsigned short* hsr = hsb + (size_t)r * N * 128;
    int i = beg;
    const int end = beg + dg;
    for (; i + 3 < end; i += 4) {
        uint2 v0 = epr[i], v1 = epr[i + 1], v2 = epr[i + 2], v3 = epr[i + 3];
        uint4 h0 = *(const uint4*)(hsr + (size_t)v0.x * 128 + gl * 8);
        uint4 h1 = *(const uint4*)(hsr + (size_t)v1.x * 128 + gl * 8);
        uint4 h2 = *(const uint4*)(hsr + (size_t)v2.x * 128 + gl * 8);
        uint4 h3 = *(const uint4*)(hsr + (size_t)v3.x * 128 + gl * 8);
        float p0 = __uint_as_float(v0.y), p1 = __uint_as_float(v1.y);
        float p2 = __uint_as_float(v2.y), p3 = __uint_as_float(v3.y);
        ssum += p0 + p1 + p2 + p3;
        ac[0] += p0 * bf2f((unsigned short)(h0.x & 0xffffu)) + p1 * bf2f((unsigned short)(h1.x & 0xffffu))
               + p2 * bf2f((unsigned short)(h2.x & 0xffffu)) + p3 * bf2f((unsigned short)(h3.x & 0xffffu));
        ac[1] += p0 * bf2f((unsigned short)(h0.x >> 16)) + p1 * bf2f((unsigned short)(h1.x >> 16))
               + p2 * bf2f((unsigned short)(h2.x >> 16)) + p3 * bf2f((unsigned short)(h3.x >> 16));
        ac[2] += p0 * bf2f((unsigned short)(h0.y & 0xffffu)) + p1 * bf2f((unsigned short)(h1.y & 0xffffu))
               + p2 * bf2f((unsigned short)(h2.y & 0xffffu)) + p3 * bf2f((unsigned short)(h3.y & 0xffffu));
        ac[3] += p0 * bf2f((unsigned short)(h0.y >> 16)) + p1 * bf2f((unsigned short)(h1.y >> 16))
               + p2 * bf2f((unsigned short)(h2.y >> 16)) + p3 * bf2f((unsigned short)(h3.y >> 16));
        ac[4] += p0 * bf2f((unsigned short)(h0.z & 0xffffu)) + p1 * bf2f((unsigned short)(h1.z & 0xffffu))
               + p2 * bf2f((unsigned short)(h2.z & 0xffffu)) + p3 * bf2f((unsigned short)(h3.z & 0xffffu));
        ac[5] += p0 * bf2f((unsigned short)(h0.z >> 16)) + p1 * bf2f((unsigned short)(h1.z >> 16))
               + p2 * bf2f((unsigned short)(h2.z >> 16)) + p3 * bf2f((unsigned short)(h3.z >> 16));
        ac[6] += p0 * bf2f((unsigned short)(h0.w & 0xffffu)) + p1 * bf2f((unsigned short)(h1.w & 0xffffu))
               + p2 * bf2f((unsigned short)(h2.w & 0xffffu)) + p3 * bf2f((unsigned short)(h3.w & 0xffffu));
        ac[7] += p0 * bf2f((unsigned short)(h0.w >> 16)) + p1 * bf2f((unsigned short)(h1.w >> 16))
               + p2 * bf2f((unsigned short)(h2.w >> 16)) + p3 * bf2f((unsigned short)(h3.w >> 16));
    }
    for (; i < end; ++i) {
        uint2 v = epr[i];
        float p = __uint_as_float(v.y);
        ssum += p;
        uint4 hw = *(const uint4*)(hsr + (size_t)v.x * 128 + gl * 8);
        ac[0] += p * bf2f((unsigned short)(hw.x & 0xffffu));
        ac[1] += p * bf2f((unsigned short)(hw.x >> 16));
        ac[2] += p * bf2f((unsigned short)(hw.y & 0xffffu));
        ac[3] += p * bf2f((unsigned short)(hw.y >> 16));
        ac[4] += p * bf2f((unsigned short)(hw.z & 0xffffu));
        ac[5] += p * bf2f((unsigned short)(hw.z >> 16));
        ac[6] += p * bf2f((unsigned short)(hw.w & 0xffffu));
        ac[7] += p * bf2f((unsigned short)(hw.w >> 16));
    }
    float inv = (dg > 0) ? 1.f / ssum : 0.f;
    const float* bg = b_gat + r * 128 + gl * 8;
    uint4 ow;
    ow.x = pk2bf(eluf(ac[0] * inv + bg[0]), eluf(ac[1] * inv + bg[1]));
    ow.y = pk2bf(eluf(ac[2] * inv + bg[2]), eluf(ac[3] * inv + bg[3]));
    ow.z = pk2bf(eluf(ac[4] * inv + bg[4]), eluf(ac[5] * inv + bg[5]));
    ow.w = pk2bf(eluf(ac[6] * inv + bg[6]), eluf(ac[7] * inv + bg[7]));
    *(uint4*)(z + ((size_t)r * N + d) * 128 + gl * 8) = ow;
}

// ---------------- semantic attention GEMM (MFMA) -> per-block partial sums ----------------

__global__ __launch_bounds__(256) void gemm_sem(
    const unsigned short* __restrict__ z, const unsigned short* __restrict__ W1p,
    const float* __restrict__ b1, const float* __restrict__ w2,
    float* __restrict__ wpart, int N) {
    const int r = blockIdx.y;
    const int n0 = blockIdx.x * 64;
    const int t = threadIdx.x;
    const int w = t >> 6, l = t & 63;
    __shared__ unsigned short Alds[64 * 128];
    __shared__ float sred[4];
    const unsigned short* A = z + (size_t)r * N * 128;
#pragma unroll
    for (int i = 0; i < 4; ++i) {
        int cid = t + 256 * i;
        int row = cid >> 4, kc = cid & 15;
        uint4 v = make_uint4(0, 0, 0, 0);
        if (n0 + row < N) v = *(const uint4*)(A + (size_t)(n0 + row) * 128 + kc * 8);
        int off = ((row * 256) + kc * 16) ^ ((row & 7) << 4);
        *(uint4*)((char*)Alds + off) = v;
    }
    __syncthreads();

    const bf16x8* bp = (const bf16x8*)W1p;
    f32x4 acc[8] = {};
    const int arow = w * 16 + (l & 15);
#pragma unroll
    for (int ks = 0; ks < 4; ++ks) {
        int aoff = ((arow * 256) + ks * 64 + (l >> 4) * 16) ^ ((arow & 7) << 4);
        bf16x8 av = *(const bf16x8*)((char*)Alds + aoff);
#pragma unroll
        for (int cf = 0; cf < 8; ++cf) {
            bf16x8 bv = bp[(ks * 8 + cf) * 64 + l];
            acc[cf] = __builtin_amdgcn_mfma_f32_16x16x32_bf16(av, bv, acc[cf], 0, 0, 0);
        }
    }
    float b1v[8], w2v[8];
#pragma unroll
    for (int cf = 0; cf < 8; ++cf) {
        int col = cf * 16 + (l & 15);
        b1v[cf] = b1[col];
        w2v[cf] = w2[col];
    }
    float wloc = 0.f;
#pragma unroll
    for (int i = 0; i < 4; ++i) {
        int row = n0 + w * 16 + (l >> 4) * 4 + i;
        float s = 0.f;
#pragma unroll
        for (int cf = 0; cf < 8; ++cf) s += tanhf(acc[cf][i] + b1v[cf]) * w2v[cf];
        s += __shfl_xor(s, 1, 64);
        s += __shfl_xor(s, 2, 64);
        s += __shfl_xor(s, 4, 64);
        s += __shfl_xor(s, 8, 64);
        if ((l & 15) == 0 && row < N) wloc += s;
    }
    wloc += __shfl_xor(wloc, 16, 64);
    wloc += __shfl_xor(wloc, 32, 64);
    if (l == 0) sred[w] = wloc;
    __syncthreads();
    if (t == 0)
        wpart[(size_t)r * gridDim.x + blockIdx.x] = sred[0] + sred[1] + sred[2] + sred[3];
}

// ---------------- reduce partials + 3-way softmax -> aw ----------------

__global__ void reduce_sem(const float* __restrict__ wpart, float* __restrict__ aw,
                           int nblk, int N) {
    const int t = threadIdx.x, l = t & 63, w = t >> 6;
    __shared__ float sred[R_REL][4];
    float s[R_REL] = {0.f, 0.f, 0.f};
    for (int i = t; i < nblk; i += 256) {
#pragma unroll
        for (int r = 0; r < R_REL; ++r) s[r] += wpart[(size_t)r * nblk + i];
    }
#pragma unroll
    for (int r = 0; r < R_REL; ++r) {
#pragma unroll
        for (int off = 32; off >= 1; off >>= 1) s[r] += __shfl_xor(s[r], off, 64);
        if (l == 0) sred[r][w] = s[r];
    }
    __syncthreads();
    if (t == 0) {
        float w0 = (sred[0][0] + sred[0][1] + sred[0][2] + sred[0][3]) / (float)N;
        float w1 = (sred[1][0] + sred[1][1] + sred[1][2] + sred[1][3]) / (float)N;
        float w2 = (sred[2][0] + sred[2][1] + sred[2][2] + sred[2][3]) / (float)N;
        float m = fmaxf(w0, fmaxf(w1, w2));
        float e0 = __expf(w0 - m), e1 = __expf(w1 - m), e2 = __expf(w2 - m);
        float si = e0 + e1 + e2;
        aw[0] = e0 / si; aw[1] = e1 / si; aw[2] = e2 / si;
    }
}

__global__ void combine(const unsigned short* __restrict__ z, const float* __restrict__ aw,
                        float* __restrict__ out, int N) {
    int idx = blockIdx.x * 256 + threadIdx.x;
    if (idx >= N * 32) return;
    int n = idx >> 5, c4 = idx & 31;
    float a0 = aw[0], a1 = aw[1], a2 = aw[2];
    uint2 z0 = *(const uint2*)(z + ((size_t)0 * N + n) * 128 + c4 * 4);
    uint2 z1 = *(const uint2*)(z + ((size_t)1 * N + n) * 128 + c4 * 4);
    uint2 z2 = *(const uint2*)(z + ((size_t)2 * N + n) * 128 + c4 * 4);
    float4 o;
    o.x = a0 * bf2f((unsigned short)(z0.x & 0xffffu)) + a1 * bf2f((unsigned short)(z1.x & 0xffffu)) + a2 * bf2f((unsigned short)(z2.x & 0xffffu));
    o.y = a0 * bf2f((unsigned short)(z0.x >> 16))     + a1 * bf2f((unsigned short)(z1.x >> 16))     + a2 * bf2f((unsigned short)(z2.x >> 16));
    o.z = a0 * bf2f((unsigned short)(z0.y & 0xffffu)) + a1 * bf2f((unsigned short)(z1.y & 0xffffu)) + a2 * bf2f((unsigned short)(z2.y & 0xffffu));
    o.w = a0 * bf2f((unsigned short)(z0.y >> 16))     + a1 * bf2f((unsigned short)(z1.y >> 16))     + a2 * bf2f((unsigned short)(z2.y >> 16));
    *(float4*)(out + (size_t)idx * 4) = o;
}

// ---------------- launch ----------------

extern "C" void kernel_launch(void* const* d_in, const int* in_sizes, int n_in,
                              void* d_out, int out_size, void* d_ws, size_t ws_size,
                              hipStream_t stream) {
    const float* dst_feat = (const float*)d_in[0];
    const float* src_feats = (const float*)d_in[1];
    const int*   src_idx  = (const int*)d_in[2];
    const int*   dst_idx  = (const int*)d_in[3];
    const float* WT_dst   = (const float*)d_in[4];
    const float* bT_dst   = (const float*)d_in[5];
    const float* WT_src   = (const float*)d_in[6];
    const float* bT_src   = (const float*)d_in[7];
    const float* W_gat    = (const float*)d_in[8];
    const float* attn_l   = (const float*)d_in[9];
    const float* attn_r   = (const float*)d_in[10];
    const float* b_gat    = (const float*)d_in[11];
    const float* W1_sem   = (const float*)d_in[12];
    const float* b1_sem   = (const float*)d_in[13];
    const float* w2_sem   = (const float*)d_in[14];

    const int N = in_sizes[0] / 256;
    const int E = in_sizes[2] / R_REL;
    float* out = (float*)d_out;

    const int nblk = (N + 63) / 64;
    const int nblk_hs = (N + 255) / 256;
    const int NB = (N + NODE_CHUNK - 1) / NODE_CHUNK;

    char* ws = (char*)d_ws;
    size_t off = 0;
    auto alloc = [&](size_t bytes) { char* p = ws + off; off = align_up(off + bytes, 256); return p; };
    unsigned short* hsb   = (unsigned short*)alloc((size_t)R_REL * N * 128 * 2);
    unsigned short* zbuf  = (unsigned short*)alloc((size_t)R_REL * N * 128 * 2);
    float*    Wc    = (float*)alloc((size_t)R_REL * 256 * 128 * 4);
    unsigned short* Wcp   = (unsigned short*)alloc((size_t)R_REL * 256 * 128 * 2);
    unsigned short* W1p   = (unsigned short*)alloc((size_t)128 * 128 * 2);
    float*    bc    = (float*)alloc(R_REL * 128 * 4);
    float*    u     = (float*)alloc(R_REL * 256 * 4);
    float*    cc    = (float*)alloc(R_REL * 4);
    float*    el    = (float*)alloc((size_t)R_REL * N * 4);
    float*    er    = (float*)alloc((size_t)R_REL * N * 4);
    int*      deg   = (int*)alloc((size_t)R_REL * N * 4);
    int*      offs  = (int*)alloc((size_t)R_REL * N * 4);
    int*      gcnt  = (int*)alloc((size_t)R_REL * NB * 4);
    int*      bbase = (int*)alloc((size_t)R_REL * NB * 4);
    unsigned* bbuf  = (unsigned*)alloc((size_t)R_REL * NB * BCAP * 4);
    uint2*    epair = (uint2*)alloc((size_t)R_REL * E * 8);
    float*    wpart = (float*)alloc((size_t)R_REL * nblk * 4);
    float*    aw    = (float*)alloc(R_REL * 4);

    hipMemsetAsync(gcnt, 0, (size_t)R_REL * NB * 4, stream);

    // weight prep
    vu_kernel<<<R_REL, 256, 0, stream>>>(W_gat, attn_r, WT_dst, bT_dst, u, cc);
    wc_kernel<<<dim3(257, R_REL), 128, 0, stream>>>(WT_src, bT_src, W_gat, Wc, bc);
    pack_kernel<<<dim3(64, R_REL), 64, 0, stream>>>(Wc, Wcp, 256 * 128, 8);
    pack_kernel<<<dim3(32, 1), 64, 0, stream>>>(W1_sem, W1p, 0, 4);

    // node projections (before fill3, which consumes el/er)
    gemm_hs<<<dim3(nblk_hs, R_REL), 1024, 0, stream>>>(src_feats, Wcp, bc, attn_l, hsb, el, N);
    er_kernel<<<(N + 3) / 4, 256, 0, stream>>>(dst_feat, u, cc, er, N);

    // CSR build (bucket sort + fused hist/scan/place)
    bucket_kernel<<<dim3((E + 1023) / 1024, R_REL), 256, 0, stream>>>(src_idx, dst_idx, gcnt, bbuf, NB, E);
    bscan_kernel<<<1, 64, 0, stream>>>(gcnt, bbase, NB);
    fill3_kernel<<<dim3(NB, R_REL), 256, 0, stream>>>(bbuf, gcnt, bbase, el, er, offs, deg, epair, NB, N, E);

    // fused aggregation -> z
    gather_kernel<<<dim3((N + 15) / 16, R_REL), 256, 0, stream>>>(epair, offs, deg, hsb, b_gat, zbuf, N, E);

    // semantic attention + combine
    gemm_sem<<<dim3(nblk, R_REL), 256, 0, stream>>>(zbuf, W1p, b1_sem, w2_sem, wpart, N);
    reduce_sem<<<1, 256, 0, stream>>>(wpart, aw, nblk, N);
    combine<<<(N * 32 + 255) / 256, 256, 0, stream>>>(zbuf, aw, out, N);
}

// Round 14
// 244.013 us; speedup vs baseline: 12.8944x; 1.0012x over previous
//
#include <hip/hip_runtime.h>
#include <hip/hip_bf16.h>

#define R_REL 3
#define NODE_CHUNK 512
#define BCAP 6144

typedef __attribute__((ext_vector_type(8))) short bf16x8;
typedef __attribute__((ext_vector_type(4))) float f32x4;

static inline size_t align_up(size_t x, size_t a) { return (x + a - 1) & ~(a - 1); }

__device__ __forceinline__ float eluf(float x) {
    return x > 0.f ? x : (__expf(x) - 1.f);
}
__device__ __forceinline__ unsigned short f2bf(float f) {
    __hip_bfloat16 h = __float2bfloat16(f);
    return *reinterpret_cast<unsigned short*>(&h);
}
__device__ __forceinline__ unsigned pk2bf(float lo, float hi) {
    __hip_bfloat162 h = __float22bfloat162_rn(make_float2(lo, hi));
    return *reinterpret_cast<unsigned*>(&h);
}
__device__ __forceinline__ float bf2f(unsigned short h) {
    return __uint_as_float((unsigned)h << 16);
}

// ---------------- fused v+u weight prep ----------------

__global__ void vu_kernel(const float* __restrict__ W_gat, const float* __restrict__ attn_r,
                          const float* __restrict__ WT_dst, const float* __restrict__ bT_dst,
                          float* __restrict__ u, float* __restrict__ cc) {
    int r = blockIdx.x;
    int t = threadIdx.x;
    __shared__ float ar[128];
    __shared__ float vs[128];
    if (t < 128) ar[t] = attn_r[r * 128 + t];
    __syncthreads();
    if (t < 128) {
        const float* W = W_gat + (size_t)r * 128 * 128 + (size_t)t * 128;
        float s = 0.f;
        for (int j = 0; j < 128; ++j) s += W[j] * ar[j];
        vs[t] = s;
    }
    __syncthreads();
    const float* W = WT_dst + (size_t)t * 128;
    float s = 0.f;
    for (int i = 0; i < 128; ++i) s += W[i] * vs[i];
    u[r * 256 + t] = s;
    if (t == 0) {
        float c = 0.f;
        for (int i = 0; i < 128; ++i) c += bT_dst[i] * vs[i];
        cc[r] = c;
    }
}

__global__ void wc_kernel(const float* __restrict__ WT_src, const float* __restrict__ bT_src,
                          const float* __restrict__ W_gat, float* __restrict__ Wc,
                          float* __restrict__ bc) {
    int r = blockIdx.y;
    int k = blockIdx.x;  // 0..256
    int j = threadIdx.x; // 0..127
    __shared__ float as[128];
    const float* arow = (k < 256) ? (WT_src + ((size_t)r * 256 + k) * 128)
                                  : (bT_src + (size_t)r * 128);
    as[j] = arow[j];
    __syncthreads();
    const float* W = W_gat + (size_t)r * 128 * 128;
    float s = 0.f;
    for (int i = 0; i < 128; ++i) s += as[i] * W[(size_t)i * 128 + j];
    if (k < 256) Wc[((size_t)r * 256 + k) * 128 + j] = s;
    else         bc[(size_t)r * 128 + j] = s;
}

// pack fp32 [relstride rows...][K][128] matrix into per-lane MFMA B-fragment order
__global__ void pack_kernel(const float* __restrict__ S, unsigned short* __restrict__ P,
                            int relstride, int KS) {
    int r = blockIdx.y;
    int ks = blockIdx.x >> 3, cb = blockIdx.x & 7;
    int l = threadIdx.x;
    const float* Sr = S + (size_t)r * relstride;
    int col = cb * 16 + (l & 15);
    int kb = ks * 32 + (l >> 4) * 8;
    unsigned short v[8];
#pragma unroll
    for (int j = 0; j < 8; ++j) v[j] = f2bf(Sr[(size_t)(kb + j) * 128 + col]);
    unsigned short* dst = P + ((((size_t)r * KS + ks) * 8 + cb) * 64 + l) * 8;
    *(uint4*)dst = *(uint4*)v;
}

// ---------------- hs GEMM (MFMA): B half-staged in 32KB LDS, 8 waves x 128 rows ----------------
// 32KB LDS -> 4 blocks/CU (vs 2 at 64KB): 2x wave residency to hide the A-stream.

__global__ __launch_bounds__(512) void gemm_hs(
    const float* __restrict__ src, const unsigned short* __restrict__ Bpack,
    const float* __restrict__ bc, const float* __restrict__ attn_l,
    unsigned short* __restrict__ hsb, float* __restrict__ el, int N) {
    const int r = blockIdx.y;
    const int t = threadIdx.x;
    const int w = t >> 6, l = t & 63;
    __shared__ unsigned short Blds[128 * 128];  // 32KB: half of the B-pack

    const unsigned short* bsrc = Bpack + (size_t)r * 256 * 128;
    const int rowbase = blockIdx.x * 128 + w * 16;
    const int arow_i = rowbase + (l & 15);
    const int kg = l >> 4;
    const float* A = src + (size_t)r * N * 256;
    const float* arow = A + (size_t)(arow_i < N ? arow_i : N - 1) * 256;

    f32x4 acc[8] = {};
#pragma unroll
    for (int half = 0; half < 2; ++half) {
        const unsigned short* hsrc = bsrc + half * 128 * 128;
        __syncthreads();  // protect Blds before overwrite (phase boundary)
#pragma unroll
        for (int i = 0; i < 4; ++i) {
            int c = i * 512 + t;  // 2048 chunks of 16B
            *(uint4*)&Blds[(size_t)c * 8] = *(const uint4*)&hsrc[(size_t)c * 8];
        }
        __syncthreads();
#pragma unroll
        for (int ks2 = 0; ks2 < 4; ++ks2) {
            const int ks = half * 4 + ks2;
            float4 a0 = *(const float4*)(arow + ks * 32 + kg * 8);
            float4 a1 = *(const float4*)(arow + ks * 32 + kg * 8 + 4);
            uint4 uv;
            uv.x = pk2bf(a0.x, a0.y);
            uv.y = pk2bf(a0.z, a0.w);
            uv.z = pk2bf(a1.x, a1.y);
            uv.w = pk2bf(a1.z, a1.w);
            bf16x8 av = *(bf16x8*)&uv;
#pragma unroll
            for (int cf = 0; cf < 8; ++cf) {
                bf16x8 bv = *(const bf16x8*)&Blds[((size_t)(ks2 * 8 + cf) * 64 + l) * 8];
                acc[cf] = __builtin_amdgcn_mfma_f32_16x16x32_bf16(av, bv, acc[cf], 0, 0, 0);
            }
        }
    }
    float bcv[8], alv[8];
#pragma unroll
    for (int cf = 0; cf < 8; ++cf) {
        int col = cf * 16 + (l & 15);
        bcv[cf] = bc[r * 128 + col];
        alv[cf] = attn_l[r * 128 + col];
    }
#pragma unroll
    for (int i = 0; i < 4; ++i) {
        int row = rowbase + (l >> 4) * 4 + i;
        float pe = 0.f;
        unsigned short hv[8];
#pragma unroll
        for (int cf = 0; cf < 8; ++cf) {
            float v = acc[cf][i] + bcv[cf];
            pe += v * alv[cf];
            hv[cf] = f2bf(v);
        }
        if (row < N) {
            unsigned short* hp = hsb + ((size_t)r * N + row) * 128 + (l & 15);
#pragma unroll
            for (int cf = 0; cf < 8; ++cf) hp[cf * 16] = hv[cf];
        }
        pe += __shfl_xor(pe, 1, 64);
        pe += __shfl_xor(pe, 2, 64);
        pe += __shfl_xor(pe, 4, 64);
        pe += __shfl_xor(pe, 8, 64);
        if ((l & 15) == 0 && row < N) el[(size_t)r * N + row] = pe;
    }
}

// ---------------- er: er[r][n] = dst_feat[n] . u[r] + cc[r] ----------------

__global__ void er_kernel(const float* __restrict__ dst_feat, const float* __restrict__ u,
                          const float* __restrict__ cc, float* __restrict__ er, int N) {
    __shared__ float us[3][256];
    for (int i = threadIdx.x; i < 3 * 256; i += 256) us[i / 256][i & 255] = u[i];
    __syncthreads();
    int wave = threadIdx.x >> 6, lane = threadIdx.x & 63;
    int n = blockIdx.x * 4 + wave;
    if (n >= N) return;
    float4 f = *(const float4*)(dst_feat + (size_t)n * 256 + lane * 4);
#pragma unroll
    for (int r = 0; r < R_REL; ++r) {
        float4 uv = *(float4*)&us[r][lane * 4];
        float s = f.x * uv.x + f.y * uv.y + f.z * uv.z + f.w * uv.w;
#pragma unroll
        for (int off = 32; off >= 1; off >>= 1) s += __shfl_xor(s, off, 64);
        if (lane == 0) er[(size_t)r * N + n] = s + cc[r];
    }
}

// ---------------- CSR build via 2-level bucket sort ----------------

__global__ __launch_bounds__(256) void bucket_kernel(
    const int* __restrict__ si, const int* __restrict__ di,
    int* __restrict__ gcnt, unsigned* __restrict__ bbuf, int NB, int E) {
    const int r = blockIdx.y;
    const int t = threadIdx.x;
    const int e0 = blockIdx.x * 1024;
    __shared__ int cnt[128];
    __shared__ int base[128];
    if (t < 128) cnt[t] = 0;
    __syncthreads();
    int bk[4], rank[4]; unsigned pack[4]; bool val[4];
#pragma unroll
    for (int j = 0; j < 4; ++j) {
        int e = e0 + j * 256 + t;
        val[j] = e < E;
        bk[j] = 0; rank[j] = 0; pack[j] = 0;
        if (val[j]) {
            size_t g = (size_t)r * E + e;
            int s = si[g], d = di[g];
            bk[j] = d >> 9;
            pack[j] = (unsigned)s | ((unsigned)d << 16);
            rank[j] = atomicAdd(&cnt[bk[j]], 1);
        }
    }
    __syncthreads();
    if (t < NB && cnt[t] > 0) base[t] = atomicAdd(&gcnt[r * NB + t], cnt[t]);
    __syncthreads();
#pragma unroll
    for (int j = 0; j < 4; ++j) {
        if (val[j])
            bbuf[((size_t)r * NB + bk[j]) * BCAP + base[bk[j]] + rank[j]] = pack[j];
    }
}

// tiny: exclusive-scan gcnt -> bbase (per relation), serial (NB ~98)
__global__ void bscan_kernel(const int* __restrict__ gcnt, int* __restrict__ bbase, int NB) {
    int r = threadIdx.x;
    if (r >= R_REL) return;
    int acc = 0;
    for (int i = 0; i < NB; ++i) {
        bbase[r * NB + i] = acc;
        acc += gcnt[r * NB + i];
    }
}

// fused per-bucket: LDS histogram -> LDS excl scan -> write offs/deg -> place edges + weights
__global__ __launch_bounds__(256) void fill3_kernel(
    const unsigned* __restrict__ bbuf, const int* __restrict__ gcnt,
    const int* __restrict__ bbase, const float* __restrict__ el, const float* __restrict__ er,
    int* __restrict__ offs, int* __restrict__ deg, uint2* __restrict__ epair,
    int NB, int N, int E) {
    const int r = blockIdx.y;
    const int b = blockIdx.x;
    const int t = threadIdx.x;
    const int lane = t & 63, wave = t >> 6;
    __shared__ int hist[NODE_CHUNK];
    __shared__ int curl[NODE_CHUNK];
    __shared__ float erl[NODE_CHUNK];
    __shared__ int wsum[4];
    __shared__ int wpre[4];

    for (int i = t; i < NODE_CHUNK; i += 256) hist[i] = 0;
    {
        int idx0 = b * NODE_CHUNK + t;
        int idx1 = idx0 + 256;
        erl[t]       = (idx0 < N) ? er[(size_t)r * N + idx0] : 0.f;
        erl[t + 256] = (idx1 < N) ? er[(size_t)r * N + idx1] : 0.f;
    }
    __syncthreads();

    const int cnt = gcnt[r * NB + b];
    const int bb0 = bbase[r * NB + b];
    const unsigned* bb = bbuf + ((size_t)r * NB + b) * BCAP;

    for (int i = t; i < cnt; i += 256) {
        int dloc = (bb[i] >> 16) & (NODE_CHUNK - 1);
        atomicAdd(&hist[dloc], 1);
    }
    __syncthreads();

    int a0 = hist[2 * t], a1 = hist[2 * t + 1];
    int s = a0 + a1;
    int x = s;
#pragma unroll
    for (int off = 1; off < 64; off <<= 1) {
        int y = __shfl_up(x, off, 64);
        if (lane >= off) x += y;
    }
    if (lane == 63) wsum[wave] = x;
    __syncthreads();
    if (t == 0) {
        int acc = 0;
#pragma unroll
        for (int w2 = 0; w2 < 4; ++w2) { wpre[w2] = acc; acc += wsum[w2]; }
    }
    __syncthreads();
    int excl = wpre[wave] + x - s;
    curl[2 * t] = excl;
    curl[2 * t + 1] = excl + a0;
    {
        int idx0 = b * NODE_CHUNK + 2 * t;
        if (idx0 < N) { offs[(size_t)r * N + idx0] = bb0 + excl; deg[(size_t)r * N + idx0] = a0; }
        int idx1 = idx0 + 1;
        if (idx1 < N) { offs[(size_t)r * N + idx1] = bb0 + excl + a0; deg[(size_t)r * N + idx1] = a1; }
    }
    __syncthreads();

    const float* elr = el + (size_t)r * N;
    uint2* epr = epair + (size_t)r * E;
    for (int i = t; i < cnt; i += 256) {
        unsigned pk = bb[i];
        int src = pk & 0xffffu;
        int dloc = (pk >> 16) & (NODE_CHUNK - 1);
        float e = elr[src] + erl[dloc];
        e = e > 0.f ? e : 0.2f * e;
        float p = __expf(e);
        int pos = bb0 + atomicAdd(&curl[dloc], 1);
        epr[pos] = make_uint2((unsigned)src, __float_as_uint(p));
    }
}

// ---------------- fused per-dst aggregation + bias + ELU -> z (bf16) ----------------
// One dst per 16-lane group; 8/4/1 unroll cascade => up to 8 hs rows in flight per group.

__global__ __launch_bounds__(256) void gather_kernel(
    const uint2* __restrict__ epair, const int* __restrict__ offs,
    const int* __restrict__ deg, const unsigned short* __restrict__ hsb,
    const float* __restrict__ b_gat, unsigned short* __restrict__ z, int N, int E) {
    const int r = blockIdx.y;
    const int t = threadIdx.x;
    const int gid = t >> 4;
    const int gl = t & 15;
    const int d = blockIdx.x * 16 + gid;
    if (d >= N) return;
    const int beg = offs[(size_t)r * N + d];
    const int dg = deg[(size_t)r * N + d];
    float ac[8] = {0.f, 0.f, 0.f, 0.f, 0.f, 0.f, 0.f, 0.f};
    float ssum = 0.f;
    const uint2* epr = epair + (size_t)r * E;
    const unsigned short* hsr = hsb + (size_t)r * N * 128;
    int i = beg;
    const int end = beg + dg;

#define ACC_ONE(hw, p)                                                        \
    do {                                                                      \
        ac[0] += (p) * bf2f((unsigned short)((hw).x & 0xffffu));              \
        ac[1] += (p) * bf2f((unsigned short)((hw).x >> 16));                  \
        ac[2] += (p) * bf2f((unsigned short)((hw).y & 0xffffu));              \
        ac[3] += (p) * bf2f((unsigned short)((hw).y >> 16));                  \
        ac[4] += (p) * bf2f((unsigned short)((hw).z & 0xffffu));              \
        ac[5] += (p) * bf2f((unsigned short)((hw).z >> 16));                  \
        ac[6] += (p) * bf2f((unsigned short)((hw).w & 0xffffu));              \
        ac[7] += (p) * bf2f((unsigned short)((hw).w >> 16));                  \
    } while (0)

    for (; i + 7 < end; i += 8) {
        uint2 v[8]; uint4 h[8];
#pragma unroll
        for (int j = 0; j < 8; ++j) v[j] = epr[i + j];
#pragma unroll
        for (int j = 0; j < 8; ++j) h[j] = *(const uint4*)(hsr + (size_t)v[j].x * 128 + gl * 8);
#pragma unroll
        for (int j = 0; j < 8; ++j) {
            float p = __uint_as_float(v[j].y);
            ssum += p;
            ACC_ONE(h[j], p);
        }
    }
    for (; i + 3 < end; i += 4) {
        uint2 v[4]; uint4 h[4];
#pragma unroll
        for (int j = 0; j < 4; ++j) v[j] = epr[i + j];
#pragma unroll
        for (int j = 0; j < 4; ++j) h[j] = *(const uint4*)(hsr + (size_t)v[j].x * 128 + gl * 8);
#pragma unroll
        for (int j = 0; j < 4; ++j) {
            float p = __uint_as_float(v[j].y);
            ssum += p;
            ACC_ONE(h[j], p);
        }
    }
    for (; i < end; ++i) {
        uint2 v = epr[i];
        float p = __uint_as_float(v.y);
        ssum += p;
        uint4 hw = *(const uint4*)(hsr + (size_t)v.x * 128 + gl * 8);
        ACC_ONE(hw, p);
    }
#undef ACC_ONE

    float inv = (dg > 0) ? 1.f / ssum : 0.f;
    const float* bg = b_gat + r * 128 + gl * 8;
    uint4 ow;
    ow.x = pk2bf(eluf(ac[0] * inv + bg[0]), eluf(ac[1] * inv + bg[1]));
    ow.y = pk2bf(eluf(ac[2] * inv + bg[2]), eluf(ac[3] * inv + bg[3]));
    ow.z = pk2bf(eluf(ac[4] * inv + bg[4]), eluf(ac[5] * inv + bg[5]));
    ow.w = pk2bf(eluf(ac[6] * inv + bg[6]), eluf(ac[7] * inv + bg[7]));
    *(uint4*)(z + ((size_t)r * N + d) * 128 + gl * 8) = ow;
}

// ---------------- semantic attention GEMM (MFMA) -> per-block partial sums ----------------

__global__ __launch_bounds__(256) void gemm_sem(
    const unsigned short* __restrict__ z, const unsigned short* __restrict__ W1p,
    const float* __restrict__ b1, const float* __restrict__ w2,
    float* __restrict__ wpart, int N) {
    const int r = blockIdx.y;
    const int n0 = blockIdx.x * 64;
    const int t = threadIdx.x;
    const int w = t >> 6, l = t & 63;
    __shared__ unsigned short Alds[64 * 128];
    __shared__ float sred[4];
    const unsigned short* A = z + (size_t)r * N * 128;
#pragma unroll
    for (int i = 0; i < 4; ++i) {
        int cid = t + 256 * i;
        int row = cid >> 4, kc = cid & 15;
        uint4 v = make_uint4(0, 0, 0, 0);
        if (n0 + row < N) v = *(const uint4*)(A + (size_t)(n0 + row) * 128 + kc * 8);
        int off = ((row * 256) + kc * 16) ^ ((row & 7) << 4);
        *(uint4*)((char*)Alds + off) = v;
    }
    __syncthreads();

    const bf16x8* bp = (const bf16x8*)W1p;
    f32x4 acc[8] = {};
    const int arow = w * 16 + (l & 15);
#pragma unroll
    for (int ks = 0; ks < 4; ++ks) {
        int aoff = ((arow * 256) + ks * 64 + (l >> 4) * 16) ^ ((arow & 7) << 4);
        bf16x8 av = *(const bf16x8*)((char*)Alds + aoff);
#pragma unroll
        for (int cf = 0; cf < 8; ++cf) {
            bf16x8 bv = bp[(ks * 8 + cf) * 64 + l];
            acc[cf] = __builtin_amdgcn_mfma_f32_16x16x32_bf16(av, bv, acc[cf], 0, 0, 0);
        }
    }
    float b1v[8], w2v[8];
#pragma unroll
    for (int cf = 0; cf < 8; ++cf) {
        int col = cf * 16 + (l & 15);
        b1v[cf] = b1[col];
        w2v[cf] = w2[col];
    }
    float wloc = 0.f;
#pragma unroll
    for (int i = 0; i < 4; ++i) {
        int row = n0 + w * 16 + (l >> 4) * 4 + i;
        float s = 0.f;
#pragma unroll
        for (int cf = 0; cf < 8; ++cf) s += tanhf(acc[cf][i] + b1v[cf]) * w2v[cf];
        s += __shfl_xor(s, 1, 64);
        s += __shfl_xor(s, 2, 64);
        s += __shfl_xor(s, 4, 64);
        s += __shfl_xor(s, 8, 64);
        if ((l & 15) == 0 && row < N) wloc += s;
    }
    wloc += __shfl_xor(wloc, 16, 64);
    wloc += __shfl_xor(wloc, 32, 64);
    if (l == 0) sred[w] = wloc;
    __syncthreads();
    if (t == 0)
        wpart[(size_t)r * gridDim.x + blockIdx.x] = sred[0] + sred[1] + sred[2] + sred[3];
}

// ---------------- reduce partials + 3-way softmax -> aw ----------------

__global__ void reduce_sem(const float* __restrict__ wpart, float* __restrict__ aw,
                           int nblk, int N) {
    const int t = threadIdx.x, l = t & 63, w = t >> 6;
    __shared__ float sred[R_REL][4];
    float s[R_REL] = {0.f, 0.f, 0.f};
    for (int i = t; i < nblk; i += 256) {
#pragma unroll
        for (int r = 0; r < R_REL; ++r) s[r] += wpart[(size_t)r * nblk + i];
    }
#pragma unroll
    for (int r = 0; r < R_REL; ++r) {
#pragma unroll
        for (int off = 32; off >= 1; off >>= 1) s[r] += __shfl_xor(s[r], off, 64);
        if (l == 0) sred[r][w] = s[r];
    }
    __syncthreads();
    if (t == 0) {
        float w0 = (sred[0][0] + sred[0][1] + sred[0][2] + sred[0][3]) / (float)N;
        float w1 = (sred[1][0] + sred[1][1] + sred[1][2] + sred[1][3]) / (float)N;
        float w2 = (sred[2][0] + sred[2][1] + sred[2][2] + sred[2][3]) / (float)N;
        float m = fmaxf(w0, fmaxf(w1, w2));
        float e0 = __expf(w0 - m), e1 = __expf(w1 - m), e2 = __expf(w2 - m);
        float si = e0 + e1 + e2;
        aw[0] = e0 / si; aw[1] = e1 / si; aw[2] = e2 / si;
    }
}

__global__ void combine(const unsigned short* __restrict__ z, const float* __restrict__ aw,
                        float* __restrict__ out, int N) {
    int idx = blockIdx.x * 256 + threadIdx.x;
    if (idx >= N * 32) return;
    int n = idx >> 5, c4 = idx & 31;
    float a0 = aw[0], a1 = aw[1], a2 = aw[2];
    uint2 z0 = *(const uint2*)(z + ((size_t)0 * N + n) * 128 + c4 * 4);
    uint2 z1 = *(const uint2*)(z + ((size_t)1 * N + n) * 128 + c4 * 4);
    uint2 z2 = *(const uint2*)(z + ((size_t)2 * N + n) * 128 + c4 * 4);
    float4 o;
    o.x = a0 * bf2f((unsigned short)(z0.x & 0xffffu)) + a1 * bf2f((unsigned short)(z1.x & 0xffffu)) + a2 * bf2f((unsigned short)(z2.x & 0xffffu));
    o.y = a0 * bf2f((unsigned short)(z0.x >> 16))     + a1 * bf2f((unsigned short)(z1.x >> 16))     + a2 * bf2f((unsigned short)(z2.x >> 16));
    o.z = a0 * bf2f((unsigned short)(z0.y & 0xffffu)) + a1 * bf2f((unsigned short)(z1.y & 0xffffu)) + a2 * bf2f((unsigned short)(z2.y & 0xffffu));
    o.w = a0 * bf2f((unsigned short)(z0.y >> 16))     + a1 * bf2f((unsigned short)(z1.y >> 16))     + a2 * bf2f((unsigned short)(z2.y >> 16));
    *(float4*)(out + (size_t)idx * 4) = o;
}

// ---------------- launch ----------------

extern "C" void kernel_launch(void* const* d_in, const int* in_sizes, int n_in,
                              void* d_out, int out_size, void* d_ws, size_t ws_size,
                              hipStream_t stream) {
    const float* dst_feat = (const float*)d_in[0];
    const float* src_feats = (const float*)d_in[1];
    const int*   src_idx  = (const int*)d_in[2];
    const int*   dst_idx  = (const int*)d_in[3];
    const float* WT_dst   = (const float*)d_in[4];
    const float* bT_dst   = (const float*)d_in[5];
    const float* WT_src   = (const float*)d_in[6];
    const float* bT_src   = (const float*)d_in[7];
    const float* W_gat    = (const float*)d_in[8];
    const float* attn_l   = (const float*)d_in[9];
    const float* attn_r   = (const float*)d_in[10];
    const float* b_gat    = (const float*)d_in[11];
    const float* W1_sem   = (const float*)d_in[12];
    const float* b1_sem   = (const float*)d_in[13];
    const float* w2_sem   = (const float*)d_in[14];

    const int N = in_sizes[0] / 256;
    const int E = in_sizes[2] / R_REL;
    float* out = (float*)d_out;

    const int nblk = (N + 63) / 64;
    const int nblk_hs = (N + 127) / 128;
    const int NB = (N + NODE_CHUNK - 1) / NODE_CHUNK;

    char* ws = (char*)d_ws;
    size_t off = 0;
    auto alloc = [&](size_t bytes) { char* p = ws + off; off = align_up(off + bytes, 256); return p; };
    unsigned short* hsb   = (unsigned short*)alloc((size_t)R_REL * N * 128 * 2);
    unsigned short* zbuf  = (unsigned short*)alloc((size_t)R_REL * N * 128 * 2);
    float*    Wc    = (float*)alloc((size_t)R_REL * 256 * 128 * 4);
    unsigned short* Wcp   = (unsigned short*)alloc((size_t)R_REL * 256 * 128 * 2);
    unsigned short* W1p   = (unsigned short*)alloc((size_t)128 * 128 * 2);
    float*    bc    = (float*)alloc(R_REL * 128 * 4);
    float*    u     = (float*)alloc(R_REL * 256 * 4);
    float*    cc    = (float*)alloc(R_REL * 4);
    float*    el    = (float*)alloc((size_t)R_REL * N * 4);
    float*    er    = (float*)alloc((size_t)R_REL * N * 4);
    int*      deg   = (int*)alloc((size_t)R_REL * N * 4);
    int*      offs  = (int*)alloc((size_t)R_REL * N * 4);
    int*      gcnt  = (int*)alloc((size_t)R_REL * NB * 4);
    int*      bbase = (int*)alloc((size_t)R_REL * NB * 4);
    unsigned* bbuf  = (unsigned*)alloc((size_t)R_REL * NB * BCAP * 4);
    uint2*    epair = (uint2*)alloc((size_t)R_REL * E * 8);
    float*    wpart = (float*)alloc((size_t)R_REL * nblk * 4);
    float*    aw    = (float*)alloc(R_REL * 4);

    hipMemsetAsync(gcnt, 0, (size_t)R_REL * NB * 4, stream);

    // weight prep
    vu_kernel<<<R_REL, 256, 0, stream>>>(W_gat, attn_r, WT_dst, bT_dst, u, cc);
    wc_kernel<<<dim3(257, R_REL), 128, 0, stream>>>(WT_src, bT_src, W_gat, Wc, bc);
    pack_kernel<<<dim3(64, R_REL), 64, 0, stream>>>(Wc, Wcp, 256 * 128, 8);
    pack_kernel<<<dim3(32, 1), 64, 0, stream>>>(W1_sem, W1p, 0, 4);

    // node projections (before fill3, which consumes el/er)
    gemm_hs<<<dim3(nblk_hs, R_REL), 512, 0, stream>>>(src_feats, Wcp, bc, attn_l, hsb, el, N);
    er_kernel<<<(N + 3) / 4, 256, 0, stream>>>(dst_feat, u, cc, er, N);

    // CSR build (bucket sort + fused hist/scan/place)
    bucket_kernel<<<dim3((E + 1023) / 1024, R_REL), 256, 0, stream>>>(src_idx, dst_idx, gcnt, bbuf, NB, E);
    bscan_kernel<<<1, 64, 0, stream>>>(gcnt, bbase, NB);
    fill3_kernel<<<dim3(NB, R_REL), 256, 0, stream>>>(bbuf, gcnt, bbase, el, er, offs, deg, epair, NB, N, E);

    // fused aggregation -> z
    gather_kernel<<<dim3((N + 15) / 16, R_REL), 256, 0, stream>>>(epair, offs, deg, hsb, b_gat, zbuf, N, E);

    // semantic attention + combine
    gemm_sem<<<dim3(nblk, R_REL), 256, 0, stream>>>(zbuf, W1p, b1_sem, w2_sem, wpart, N);
    reduce_sem<<<1, 256, 0, stream>>>(wpart, aw, nblk, N);
    combine<<<(N * 32 + 255) / 256, 256, 0, stream>>>(zbuf, aw, out, N);
}